// Round 2
// baseline (2211.243 us; speedup 1.0000x reference)
//
#include <hip/hip_runtime.h>

typedef unsigned short u16;
typedef unsigned int u32;
typedef __attribute__((ext_vector_type(8))) short bf16x8;
typedef __attribute__((ext_vector_type(4))) float f32x4;

__device__ __forceinline__ float bf2f(u16 u) { return __uint_as_float(((u32)u) << 16); }
__device__ __forceinline__ u16 f2bf(float f) {
  u32 u = __float_as_uint(f);
  return (u16)((u + 0x7fffu + ((u >> 16) & 1u)) >> 16);
}

// ---------------------------------------------------------------------------
// Embedding gather: fp32 emb row -> internal bf16 feature row. 1 thread/elem.
__global__ void gather_f2b(const float* __restrict__ emb, const int* __restrict__ ids,
                           u16* __restrict__ out, int n, int V) {
  int u = blockIdx.x * 256 + threadIdx.x;
  if (u >= n * 64) return;
  int node = u >> 6, k = u & 63;
  int r = ids[node];
  r = ((u32)r < (u32)V) ? r : 0;
  out[u] = f2bf(emb[(size_t)r * 64 + k]);
}

// ---------------------------------------------------------------------------
// Fused degree histogram over all 5 relations (one launch).
__global__ void hist5(const int* __restrict__ d0, const int* __restrict__ d1,
                      const int* __restrict__ d2, const int* __restrict__ d3,
                      const int* __restrict__ d4, int* __restrict__ cnt,
                      int E1, int E2, int E3, int E4, int E5,
                      int c1, int c2, int c3, int c4,
                      int N0, int N1, int N2, int N3, int N4) {
  int e = blockIdx.x * 256 + threadIdx.x;
  if (e >= E5) return;
  const int* dp; int cb, N, le;
  if (e < E1)      { dp = d0; cb = 0;  N = N0; le = e; }
  else if (e < E2) { dp = d1; cb = c1; N = N1; le = e - E1; }
  else if (e < E3) { dp = d2; cb = c2; N = N2; le = e - E2; }
  else if (e < E4) { dp = d3; cb = c3; N = N3; le = e - E3; }
  else             { dp = d4; cb = c4; N = N4; le = e - E4; }
  int d = dp[le];
  if ((u32)d < (u32)N) atomicAdd(&cnt[cb + d], 1);
}

// ---------------------------------------------------------------------------
// Hierarchical exclusive scan of the 5 concatenated degree arrays.
// Chunk = 2048 elems/block. scanA: per-chunk sums. scanB: per-relation scan of
// chunk sums (+ sentinel). scanC: per-chunk exclusive scan + global write.
__global__ void __launch_bounds__(256) scanA(const int* __restrict__ cnt, int* __restrict__ part,
    int n0, int n1, int n2, int n3, int n4, int s1, int s2, int s3, int s4) {
  int Ns[5] = {n0, n1, n2, n3, n4};
  int b = blockIdx.x;
  int r = (b >= s4) ? 4 : (b >= s3) ? 3 : (b >= s2) ? 2 : (b >= s1) ? 1 : 0;
  int sr = (r == 0) ? 0 : (r == 1) ? s1 : (r == 2) ? s2 : (r == 3) ? s3 : s4;
  int cOff = 0;
  for (int i = 0; i < r; i++) cOff += Ns[i];
  int lb = b - sr;
  int rem = Ns[r] - lb * 2048; if (rem > 2048) rem = 2048;
  const int* c = cnt + cOff + (size_t)lb * 2048;
  int t = threadIdx.x;
  int s = 0;
  #pragma unroll
  for (int j = 0; j < 8; j++) { int i = t + j * 256; s += (i < rem) ? c[i] : 0; }
  #pragma unroll
  for (int d = 1; d < 64; d <<= 1) s += __shfl_xor(s, d);
  __shared__ int ws[4];
  if ((t & 63) == 0) ws[t >> 6] = s;
  __syncthreads();
  if (t == 0) part[b] = ws[0] + ws[1] + ws[2] + ws[3];
}

__global__ void __launch_bounds__(64) scanB(int* __restrict__ part, int* __restrict__ off,
    int n0, int n1, int n2, int n3, int n4, int s1, int s2, int s3, int s4, int sEnd) {
  int Ns[5] = {n0, n1, n2, n3, n4};
  int Ss[6] = {0, s1, s2, s3, s4, sEnd};
  int r = blockIdx.x;
  int sr = Ss[r], er = Ss[r + 1];
  int oOff = 0;
  for (int i = 0; i < r; i++) oOff += Ns[i] + 1;
  int lane = threadIdx.x;
  int carry = 0;
  for (int base = sr; base < er; base += 64) {
    int i = base + lane;
    int v = (i < er) ? part[i] : 0;
    int s = v;
    #pragma unroll
    for (int d = 1; d < 64; d <<= 1) { int u = __shfl_up(s, d); if (lane >= d) s += u; }
    if (i < er) part[i] = carry + (s - v);
    carry += __shfl(s, 63);
  }
  if (lane == 0) off[oOff + Ns[r]] = carry;   // sentinel = relation total
}

__global__ void __launch_bounds__(256) scanC(const int* __restrict__ cnt,
    const int* __restrict__ part, int* __restrict__ off,
    int n0, int n1, int n2, int n3, int n4, int s1, int s2, int s3, int s4) {
  int Ns[5] = {n0, n1, n2, n3, n4};
  int b = blockIdx.x;
  int r = (b >= s4) ? 4 : (b >= s3) ? 3 : (b >= s2) ? 2 : (b >= s1) ? 1 : 0;
  int sr = (r == 0) ? 0 : (r == 1) ? s1 : (r == 2) ? s2 : (r == 3) ? s3 : s4;
  int cOff = 0, oOff = 0;
  for (int i = 0; i < r; i++) { cOff += Ns[i]; oOff += Ns[i] + 1; }
  int lb = b - sr;
  int rem = Ns[r] - lb * 2048; if (rem > 2048) rem = 2048;
  const int* c = cnt + cOff + (size_t)lb * 2048;
  int* of = off + oOff + (size_t)lb * 2048;
  int t = threadIdx.x, lane = t & 63, wave = t >> 6;
  int base = t * 8;
  int v[8];
  #pragma unroll
  for (int j = 0; j < 8; j++) v[j] = (base + j < rem) ? c[base + j] : 0;
  int tsum = 0;
  #pragma unroll
  for (int j = 0; j < 8; j++) tsum += v[j];
  int s = tsum;
  #pragma unroll
  for (int d = 1; d < 64; d <<= 1) { int u = __shfl_up(s, d); if (lane >= d) s += u; }
  __shared__ int ws[4];
  if (lane == 63) ws[wave] = s;
  __syncthreads();
  int wbase = 0;
  #pragma unroll
  for (int i = 0; i < 4; i++) wbase += (i < wave) ? ws[i] : 0;
  int run = part[b] + wbase + (s - tsum);
  #pragma unroll
  for (int j = 0; j < 8; j++) { if (base + j < rem) of[base + j] = run; run += v[j]; }
}

// ---------------------------------------------------------------------------
// Fused CSR fill over all 5 relations. csr global offset = segment start (e-le).
__global__ void fill5(
    const int* __restrict__ s0, const int* __restrict__ s1p, const int* __restrict__ s2p,
    const int* __restrict__ s3p, const int* __restrict__ s4p,
    const int* __restrict__ d0, const int* __restrict__ d1, const int* __restrict__ d2,
    const int* __restrict__ d3, const int* __restrict__ d4,
    const int* __restrict__ off, int* __restrict__ cur, int* __restrict__ csr,
    int E1, int E2, int E3, int E4, int E5,
    int c1, int c2, int c3, int c4,
    int o1, int o2, int o3, int o4,
    int N0, int N1, int N2, int N3, int N4) {
  int e = blockIdx.x * 256 + threadIdx.x;
  if (e >= E5) return;
  const int *sp, *dp; int cb, ob, N, le, El;
  if (e < E1)      { sp = s0;  dp = d0; cb = 0;  ob = 0;  N = N0; le = e;      El = E1; }
  else if (e < E2) { sp = s1p; dp = d1; cb = c1; ob = o1; N = N1; le = e - E1; El = E2 - E1; }
  else if (e < E3) { sp = s2p; dp = d2; cb = c2; ob = o2; N = N2; le = e - E2; El = E3 - E2; }
  else if (e < E4) { sp = s3p; dp = d3; cb = c3; ob = o3; N = N3; le = e - E3; El = E4 - E3; }
  else             { sp = s4p; dp = d4; cb = c4; ob = o4; N = N4; le = e - E4; El = E5 - E4; }
  int d = dp[le];
  if ((u32)d < (u32)N) {
    int pos = off[ob + d] + atomicAdd(&cur[cb + d], 1);
    if ((u32)pos < (u32)El) csr[(e - le) + pos] = sp[le];
  }
}

// ---------------------------------------------------------------------------
// OLD PATH (fallback if workspace too small): wave-per-node fused SAGE.
__device__ __forceinline__ float gmean(const u16* __restrict__ src, const int* __restrict__ off,
                                       const int* __restrict__ idx, u32 ns, int g, int lane) {
  int e0 = off[g], e1 = off[g + 1];
  float a0 = 0.f, a1 = 0.f, a2 = 0.f, a3 = 0.f;
  int e = e0;
  for (; e + 4 <= e1; e += 4) {
    int A = idx[e], B = idx[e + 1], C = idx[e + 2], D = idx[e + 3];
    A = ((u32)A < ns) ? A : 0;
    B = ((u32)B < ns) ? B : 0;
    C = ((u32)C < ns) ? C : 0;
    D = ((u32)D < ns) ? D : 0;
    a0 += bf2f(src[(size_t)A * 64 + lane]);
    a1 += bf2f(src[(size_t)B * 64 + lane]);
    a2 += bf2f(src[(size_t)C * 64 + lane]);
    a3 += bf2f(src[(size_t)D * 64 + lane]);
  }
  for (; e < e1; e++) {
    int A = idx[e];
    A = ((u32)A < ns) ? A : 0;
    a0 += bf2f(src[(size_t)A * 64 + lane]);
  }
  float s = (a0 + a1) + (a2 + a3);
  int d = e1 - e0;
  return (d > 0) ? s * (1.f / (float)d) : 0.f;
}

__device__ __forceinline__ void stageW(float* __restrict__ Wsh, const float* __restrict__ Wb,
                                       int t) {
  #pragma unroll
  for (int j = 0; j < 4; j++) {
    int i4 = t + j * 256;
    float4 v = ((const float4*)Wb)[i4];
    int o = (i4 * 4) >> 6, k = (i4 * 4) & 63;
    float* dst = &Wsh[o * 65 + k];
    dst[0] = v.x; dst[1] = v.y; dst[2] = v.z; dst[3] = v.w;
  }
}

__global__ void __launch_bounds__(256) sage_node(
    const u16* __restrict__ xin, u16* __restrict__ xout, int n_dst, float scale,
    const float* __restrict__ Wl, const float* __restrict__ bl, const float* __restrict__ Wr,
    int lt, int nAgg, int4 rels,
    const u16* s0, const int* of0, const int* ix0, int ns0,
    const u16* s1, const int* of1, const int* ix1, int ns1,
    const u16* s2, const int* of2, const int* ix2, int ns2) {
  __shared__ float Wsh[64 * 65];
  int t = threadIdx.x, wave = t >> 6, lane = t & 63;
  int g = blockIdx.x * 4 + wave;
  bool act = g < n_dst;

  float m0 = act ? gmean(s0, of0, ix0, (u32)ns0, g, lane) : 0.f;
  float m1 = (act && nAgg > 1) ? gmean(s1, of1, ix1, (u32)ns1, g, lane) : 0.f;
  float m2 = (act && nAgg > 2) ? gmean(s2, of2, ix2, (u32)ns2, g, lane) : 0.f;
  float xv = act ? bf2f(xin[(size_t)g * 64 + lane]) : 0.f;

  float acc = 0.f;
  for (int p = 0; p < nAgg; p++) {
    int r = (p == 0) ? rels.x : (p == 1) ? rels.y : rels.z;
    const float* Wb = Wl + ((size_t)lt * 5 + r) * 4096;
    __syncthreads();
    stageW(Wsh, Wb, t);
    __syncthreads();
    float mv = (p == 0) ? m0 : (p == 1) ? m1 : m2;
    #pragma unroll
    for (int k = 0; k < 64; k++)
      acc += __shfl(mv, k) * Wsh[lane * 65 + k];
  }
  {
    const float* w0 = Wr + ((size_t)lt * 5 + rels.x) * 4096;
    const float* w1 = Wr + ((size_t)lt * 5 + rels.y) * 4096;
    const float* w2 = Wr + ((size_t)lt * 5 + rels.z) * 4096;
    __syncthreads();
    #pragma unroll
    for (int j = 0; j < 4; j++) {
      int i4 = t + j * 256;
      float4 v = ((const float4*)w0)[i4];
      if (nAgg > 1) {
        float4 b = ((const float4*)w1)[i4];
        float4 c = ((const float4*)w2)[i4];
        v.x += b.x + c.x; v.y += b.y + c.y; v.z += b.z + c.z; v.w += b.w + c.w;
      }
      int o = (i4 * 4) >> 6, k = (i4 * 4) & 63;
      float* dst = &Wsh[o * 65 + k];
      dst[0] = v.x; dst[1] = v.y; dst[2] = v.z; dst[3] = v.w;
    }
    __syncthreads();
    #pragma unroll
    for (int k = 0; k < 64; k++)
      acc += __shfl(xv, k) * Wsh[lane * 65 + k];
  }

  float bsum = bl[((size_t)lt * 5 + rels.x) * 64 + lane];
  if (nAgg > 1) bsum += bl[((size_t)lt * 5 + rels.y) * 64 + lane] +
                        bl[((size_t)lt * 5 + rels.z) * 64 + lane];

  if (act) {
    float v = fmaxf((acc + bsum) * scale, 0.f) + xv;
    xout[(size_t)g * 64 + lane] = f2bf(v);
  }
}

// ---------------------------------------------------------------------------
// Barrier-free mean-gather, one wave per dst node, ILP-8 predicated.
__global__ void __launch_bounds__(256, 8) agg_mean(
    const u16* __restrict__ src, const int* __restrict__ off, const int* __restrict__ idx,
    u16* __restrict__ out, int n_dst, int ns) {
  int t = threadIdx.x;
  int g = blockIdx.x * 4 + (t >> 6);
  int lane = t & 63;
  if (g >= n_dst) return;
  int e0 = off[g], e1 = off[g + 1];
  int d = e1 - e0;
  float a[8] = {0.f, 0.f, 0.f, 0.f, 0.f, 0.f, 0.f, 0.f};
  int eL = e1 - 1;
  for (int base = e0; base < e1; base += 8) {
    int id[8];
    #pragma unroll
    for (int j = 0; j < 8; j++) {
      int e = base + j;
      int i = idx[e <= eL ? e : eL];
      id[j] = ((u32)i < (u32)ns) ? i : 0;
    }
    float v[8];
    #pragma unroll
    for (int j = 0; j < 8; j++)
      v[j] = bf2f(src[(size_t)id[j] * 64 + lane]);
    #pragma unroll
    for (int j = 0; j < 8; j++)
      a[j] += (base + j < e1) ? v[j] : 0.f;
  }
  float s = ((a[0] + a[1]) + (a[2] + a[3])) + ((a[4] + a[5]) + (a[6] + a[7]));
  float mean = (d > 0) ? s / (float)d : 0.f;
  out[(size_t)g * 64 + lane] = f2bf(mean);
}

// Fused 3-relation mean-gather (person side): up to 24 row loads in flight per
// round -> one latency round covers the common case (all degrees <= 8).
__global__ void __launch_bounds__(256, 4) agg_mean3(
    const u16* __restrict__ sA, const int* __restrict__ ofA, const int* __restrict__ ixA, int nsA,
    const u16* __restrict__ sB, const int* __restrict__ ofB, const int* __restrict__ ixB, int nsB,
    const u16* __restrict__ sC, const int* __restrict__ ofC, const int* __restrict__ ixC, int nsC,
    u16* __restrict__ outA, u16* __restrict__ outB, u16* __restrict__ outC, int n_dst) {
  int t = threadIdx.x;
  int g = blockIdx.x * 4 + (t >> 6);
  int lane = t & 63;
  if (g >= n_dst) return;
  int a0 = ofA[g], a1 = ofA[g + 1];
  int b0 = ofB[g], b1 = ofB[g + 1];
  int c0 = ofC[g], c1 = ofC[g + 1];
  int da = a1 - a0, db = b1 - b0, dc = c1 - c0;
  int dmax = da > db ? da : db; if (dc > dmax) dmax = dc;
  float pa[4] = {0, 0, 0, 0}, pb[4] = {0, 0, 0, 0}, pc[4] = {0, 0, 0, 0};
  for (int base = 0; base < dmax; base += 8) {
    bool doA = base < da, doB = base < db, doC = base < dc;  // wave-uniform
    int iA[8], iB[8], iC[8];
    if (doA) {
      int L = a1 - 1;
      #pragma unroll
      for (int j = 0; j < 8; j++) { int e = a0 + base + j; int x = ixA[e <= L ? e : L];
                                    iA[j] = ((u32)x < (u32)nsA) ? x : 0; }
    }
    if (doB) {
      int L = b1 - 1;
      #pragma unroll
      for (int j = 0; j < 8; j++) { int e = b0 + base + j; int x = ixB[e <= L ? e : L];
                                    iB[j] = ((u32)x < (u32)nsB) ? x : 0; }
    }
    if (doC) {
      int L = c1 - 1;
      #pragma unroll
      for (int j = 0; j < 8; j++) { int e = c0 + base + j; int x = ixC[e <= L ? e : L];
                                    iC[j] = ((u32)x < (u32)nsC) ? x : 0; }
    }
    float vA[8], vB[8], vC[8];
    if (doA) {
      #pragma unroll
      for (int j = 0; j < 8; j++) vA[j] = bf2f(sA[(size_t)iA[j] * 64 + lane]);
    } else {
      #pragma unroll
      for (int j = 0; j < 8; j++) vA[j] = 0.f;
    }
    if (doB) {
      #pragma unroll
      for (int j = 0; j < 8; j++) vB[j] = bf2f(sB[(size_t)iB[j] * 64 + lane]);
    } else {
      #pragma unroll
      for (int j = 0; j < 8; j++) vB[j] = 0.f;
    }
    if (doC) {
      #pragma unroll
      for (int j = 0; j < 8; j++) vC[j] = bf2f(sC[(size_t)iC[j] * 64 + lane]);
    } else {
      #pragma unroll
      for (int j = 0; j < 8; j++) vC[j] = 0.f;
    }
    #pragma unroll
    for (int j = 0; j < 8; j++) {
      pa[j & 3] += (base + j < da) ? vA[j] : 0.f;
      pb[j & 3] += (base + j < db) ? vB[j] : 0.f;
      pc[j & 3] += (base + j < dc) ? vC[j] : 0.f;
    }
  }
  float rA = (pa[0] + pa[1]) + (pa[2] + pa[3]);
  float rB = (pb[0] + pb[1]) + (pb[2] + pb[3]);
  float rC = (pc[0] + pc[1]) + (pc[2] + pc[3]);
  outA[(size_t)g * 64 + lane] = f2bf(da > 0 ? rA / (float)da : 0.f);
  outB[(size_t)g * 64 + lane] = f2bf(db > 0 ? rB / (float)db : 0.f);
  outC[(size_t)g * 64 + lane] = f2bf(dc > 0 ? rC / (float)dc : 0.f);
}

// ---------------------------------------------------------------------------
// MFMA GEMM. C = [A0|A1|..|X] @ Wstack^T, fused epilogue relu((C+b)*s)+x,
// bf16 IN-PLACE output. Epilogue staged through per-wave LDS [16][65] so the
// X-residual read and the store are coalesced 16B/lane full-row accesses
// (fixes the 3.8x HBM write amplification of the scalar D-layout epilogue).
template <int NM>
__global__ void __launch_bounds__(256, 2) gemm_sage(
    const u16* __restrict__ A0, const u16* __restrict__ A1, const u16* __restrict__ A2,
    const u16* X, u16* out,  // no __restrict__: out aliases X (in-place)
    const float* __restrict__ Wl, const float* __restrict__ bl,
    const float* __restrict__ Wr,
    int lt, int rx, int ry, int rz, float scale, int n) {
  constexpr int KC = 2 * (NM + 1);          // K-chunks of 32
  __shared__ float ldsAcc[4][16 * 65];
  int t = threadIdx.x, wave = t >> 6, lane = t & 63;
  int col0 = lane & 15, kb = lane >> 4;
  float* lw = ldsAcc[wave];

  // ---- build B fragments (weights -> bf16) in registers, once per wave ----
  bf16x8 B[KC][4];
  #pragma unroll
  for (int kc = 0; kc < KC; kc++) {
    int m = kc >> 1;
    int kk = (kc & 1) * 32 + kb * 8;
    int rel = (m == 0) ? rx : (m == 1) ? ry : rz;
    #pragma unroll
    for (int nt = 0; nt < 4; nt++) {
      int o = nt * 16 + col0;
      float4 u0, u1;
      if (m < NM) {
        const float* Wp = Wl + ((size_t)lt * 5 + rel) * 4096 + o * 64 + kk;
        u0 = *(const float4*)Wp;
        u1 = *(const float4*)(Wp + 4);
      } else {  // root: sum of Wr over used relations
        const float* p0 = Wr + ((size_t)lt * 5 + rx) * 4096 + o * 64 + kk;
        u0 = *(const float4*)p0;
        u1 = *(const float4*)(p0 + 4);
        if (NM == 3) {
          const float* p1 = Wr + ((size_t)lt * 5 + ry) * 4096 + o * 64 + kk;
          const float* p2 = Wr + ((size_t)lt * 5 + rz) * 4096 + o * 64 + kk;
          float4 a1 = *(const float4*)p1, b1 = *(const float4*)(p1 + 4);
          float4 a2 = *(const float4*)p2, b2 = *(const float4*)(p2 + 4);
          u0.x += a1.x + a2.x; u0.y += a1.y + a2.y; u0.z += a1.z + a2.z; u0.w += a1.w + a2.w;
          u1.x += b1.x + b2.x; u1.y += b1.y + b2.y; u1.z += b1.z + b2.z; u1.w += b1.w + b2.w;
        }
      }
      bf16x8 f;
      f[0] = (short)f2bf(u0.x); f[1] = (short)f2bf(u0.y);
      f[2] = (short)f2bf(u0.z); f[3] = (short)f2bf(u0.w);
      f[4] = (short)f2bf(u1.x); f[5] = (short)f2bf(u1.y);
      f[6] = (short)f2bf(u1.z); f[7] = (short)f2bf(u1.w);
      B[kc][nt] = f;
    }
  }

  // ---- per-lane epilogue bias: 8 consecutive cols starting at (lane&7)*8 ----
  int ccl = (lane & 7) * 8;
  float bsum8[8];
  #pragma unroll
  for (int j = 0; j < 8; j++) {
    int col = ccl + j;
    float b = bl[((size_t)lt * 5 + rx) * 64 + col];
    if (NM == 3) b += bl[((size_t)lt * 5 + ry) * 64 + col] +
                      bl[((size_t)lt * 5 + rz) * 64 + col];
    bsum8[j] = b;
  }

  // ---- M loop: 16 rows per wave-tile, grid-stride ----
  int ntiles = (n + 15) >> 4;
  for (int tile = blockIdx.x * 4 + wave; tile < ntiles; tile += gridDim.x * 4) {
    int m0 = tile << 4;
    int rowA = m0 + col0;
    rowA = (rowA < n) ? rowA : (n - 1);
    bf16x8 Af[KC];
    #pragma unroll
    for (int kc = 0; kc < KC; kc++) {
      int m = kc >> 1;
      const u16* s = (m < NM) ? ((m == 0) ? A0 : (m == 1) ? A1 : A2) : X;
      int kk = (kc & 1) * 32 + kb * 8;
      Af[kc] = *(const bf16x8*)(s + (size_t)rowA * 64 + kk);  // 16B, aligned
    }
    f32x4 acc[4] = {};
    #pragma unroll
    for (int kc = 0; kc < KC; kc++) {
      #pragma unroll
      for (int nt = 0; nt < 4; nt++)
        acc[nt] = __builtin_amdgcn_mfma_f32_16x16x32_bf16(Af[kc], B[kc][nt], acc[nt], 0, 0, 0);
    }
    // stage D tile to LDS in MFMA layout: row=kb*4+j, col=nt*16+col0 (pad 65)
    #pragma unroll
    for (int nt = 0; nt < 4; nt++)
      #pragma unroll
      for (int j = 0; j < 4; j++)
        lw[(kb * 4 + j) * 65 + nt * 16 + col0] = acc[nt][j];
    // re-read row-contiguous: lane -> row (lane>>3), 8-col chunk (lane&7)*8
    #pragma unroll
    for (int it = 0; it < 2; it++) {
      int r16 = it * 8 + (lane >> 3);
      int row = m0 + r16;
      float vv[8];
      #pragma unroll
      for (int j = 0; j < 8; j++) vv[j] = lw[r16 * 65 + ccl + j];
      if (row < n) {
        bf16x8 xv8 = *(const bf16x8*)(X + (size_t)row * 64 + ccl);
        bf16x8 o8;
        #pragma unroll
        for (int j = 0; j < 8; j++) {
          float xvf = bf2f((u16)xv8[j]);
          float v = fmaxf((vv[j] + bsum8[j]) * scale, 0.f) + xvf;
          o8[j] = (short)f2bf(v);
        }
        *(bf16x8*)(out + (size_t)row * 64 + ccl) = o8;   // 16B coalesced store
      }
    }
  }
}

// ---------------------------------------------------------------------------
// Column sums over bf16 features (graph-mean readout)
__global__ void colsum2(const u16* __restrict__ x, int n, float* __restrict__ gout) {
  __shared__ float part[64];
  int t = threadIdx.x;
  if (t < 64) part[t] = 0.f;
  __syncthreads();
  int col = t & 63, w = blockIdx.x * 4 + (t >> 6), tw = gridDim.x * 4;
  float s = 0.f;
  for (int r = w; r < n; r += tw) s += bf2f(x[(size_t)r * 64 + col]);
  atomicAdd(&part[col], s);
  __syncthreads();
  if (t < 64) atomicAdd(&gout[t], part[t]);
}

// Crime head: out[0:20) as FP32
__global__ void __launch_bounds__(256) head2(const float* __restrict__ gsum,
    const float* __restrict__ Wc1, const float* __restrict__ bc1,
    const float* __restrict__ Wc2, const float* __restrict__ bc2,
    int NP, int NO, int NL, float* __restrict__ out) {
  __shared__ float g[192];
  __shared__ float h[64];
  int t = threadIdx.x;
  if (t < 192) {
    float d = (t < 64) ? (float)NP : (t < 128) ? (float)NO : (float)NL;
    g[t] = gsum[t] / d;
  }
  __syncthreads();
  if (t < 64) {
    float a = bc1[t];
    for (int k = 0; k < 192; k++) a += g[k] * Wc1[(size_t)t * 192 + k];
    h[t] = fmaxf(a, 0.f);
  }
  __syncthreads();
  if (t < 20) {
    float a = bc2[t];
    for (int k = 0; k < 64; k++) a += h[k] * Wc2[(size_t)t * 64 + k];
    out[t] = a;
  }
}

// Suspect head: out[i] as FP32 (out passed pre-offset by +20)
__global__ void __launch_bounds__(256) suspect2(const u16* __restrict__ p,
    const float* __restrict__ Ws1, const float* __restrict__ bs1,
    const float* __restrict__ Ws2, const float* __restrict__ bs2,
    float* __restrict__ out, int NP) {
  __shared__ float W1[2048];
  __shared__ float b1[32], w2[32];
  __shared__ float b2s;
  int t = threadIdx.x;
  #pragma unroll
  for (int i = 0; i < 8; i++) {
    int d = t + i * 256;
    W1[d] = Ws1[d];
  }
  if (t < 32) { b1[t] = bs1[t]; w2[t] = Ws2[t]; }
  if (t == 0) b2s = bs2[0];
  __syncthreads();
  int i = blockIdx.x * 256 + t;
  if (i >= NP) return;
  float x[64];
  #pragma unroll
  for (int k = 0; k < 64; k++) x[k] = bf2f(p[(size_t)i * 64 + k]);
  float sc = b2s;
  for (int j = 0; j < 32; j++) {
    float a = b1[j];
    const float* wr = &W1[j * 64];
    #pragma unroll
    for (int k = 0; k < 64; k++) a += x[k] * wr[k];
    sc += fmaxf(a, 0.f) * w2[j];
  }
  out[i] = sc;
}

// ---------------------------------------------------------------------------
extern "C" void kernel_launch(void* const* d_in, const int* in_sizes, int n_in,
                              void* d_out, int out_size, void* d_ws, size_t ws_size,
                              hipStream_t stream) {
  const int NP = in_sizes[0], NO = in_sizes[1], NL = in_sizes[2];
  const int Ea = in_sizes[3], Eu = in_sizes[5], Et = in_sizes[7];
  const int VP = in_sizes[9] / 64, VO = in_sizes[10] / 64, VL = in_sizes[11] / 64;

  const int* x_person   = (const int*)d_in[0];
  const int* x_object   = (const int*)d_in[1];
  const int* x_location = (const int*)d_in[2];
  const int* acts_src = (const int*)d_in[3];
  const int* acts_dst = (const int*)d_in[4];
  const int* uses_src = (const int*)d_in[5];
  const int* uses_dst = (const int*)d_in[6];
  const int* at_src   = (const int*)d_in[7];
  const int* at_dst   = (const int*)d_in[8];
  const float* person_emb   = (const float*)d_in[9];
  const float* object_emb   = (const float*)d_in[10];
  const float* location_emb = (const float*)d_in[11];
  const float* Wl  = (const float*)d_in[12];
  const float* bl  = (const float*)d_in[13];
  const float* Wr  = (const float*)d_in[14];
  const float* Wc1 = (const float*)d_in[15];
  const float* bc1 = (const float*)d_in[16];
  const float* Wc2 = (const float*)d_in[17];
  const float* bc2 = (const float*)d_in[18];
  const float* Ws1 = (const float*)d_in[19];
  const float* bs1 = (const float*)d_in[20];
  const float* Ws2 = (const float*)d_in[21];
  const float* bs2 = (const float*)d_in[22];
  float* out = (float*)d_out;

  // ---- workspace (16B aligned) ----
  char* w = (char*)d_ws;
  auto alloc = [&](size_t bytes) { char* r = w; w += (bytes + 15) & ~(size_t)15; return r; };
  u16* pX   = (u16*)alloc((size_t)NP * 128);
  u16* pAg0 = (u16*)alloc((size_t)NP * 128);   // old path: pB
  u16* oX   = (u16*)alloc((size_t)NO * 128);
  u16* oAg  = (u16*)alloc((size_t)NO * 128);   // old path: oB
  u16* lX   = (u16*)alloc((size_t)NL * 128);
  u16* lAg  = (u16*)alloc((size_t)NL * 128);   // old path: lB
  float* gsum = (float*)alloc(192 * 4);
  const size_t CN = (size_t)3 * NP + NO + NL;
  int* cnt = (int*)alloc(CN * 4);
  int* cur = (int*)alloc(CN * 4);
  int* off = (int*)alloc((CN + 8) * 4);
  int* part = (int*)alloc(4096 * 4);           // scan chunk partials (<=1024 used)
  int* csr = (int*)alloc(((size_t)Ea + 2 * (size_t)Eu + 2 * (size_t)Et) * 4);
  size_t base_need = (size_t)(w - (char*)d_ws);
  u16* pAg1 = (u16*)alloc((size_t)NP * 128);   // new-path extras
  u16* pAg2 = (u16*)alloc((size_t)NP * 128);
  size_t full_need = (size_t)(w - (char*)d_ws);
  (void)n_in; (void)out_size;
  // ws guard: if it fires, out stays 0 -> absmax == 0.118652 exactly (signature)
  if (base_need > ws_size) return;
  bool fits = (full_need <= ws_size);

  int c1 = NP, c2 = NP + NO, c3 = 2 * NP + NO, c4 = 2 * NP + NO + NL;
  int o0 = 0, o1 = NP + 1, o2 = o1 + NO + 1, o3 = o2 + NP + 1, o4 = o3 + NL + 1;
  int* csr0 = csr;
  int* csr1 = csr0 + Ea;
  int* csr2 = csr1 + Eu;
  int* csr3 = csr2 + Eu;
  int* csr4 = csr3 + Et;

  hipMemsetAsync(cnt, 0, CN * 2 * sizeof(int), stream);  // cnt + cur adjacent
  hipMemsetAsync(gsum, 0, 192 * sizeof(float), stream);

  gather_f2b<<<(NP * 64 + 255) / 256, 256, 0, stream>>>(person_emb, x_person, pX, NP, VP);
  gather_f2b<<<(NO * 64 + 255) / 256, 256, 0, stream>>>(object_emb, x_object, oX, NO, VO);
  gather_f2b<<<(NL * 64 + 255) / 256, 256, 0, stream>>>(location_emb, x_location, lX, NL, VL);

  // ---- CSR build: fused hist, 3-phase scan, fused fill ----
  int E1 = Ea, E2 = E1 + Eu, E3 = E2 + Eu, E4 = E3 + Et, E5 = E4 + Et;
  hist5<<<(E5 + 255) / 256, 256, 0, stream>>>(acts_dst, uses_dst, uses_src, at_dst, at_src,
      cnt, E1, E2, E3, E4, E5, c1, c2, c3, c4, NP, NO, NP, NL, NP);

  int B0 = (NP + 2047) / 2048, B1 = (NO + 2047) / 2048, B3 = (NL + 2047) / 2048;
  int s1 = B0, s2 = s1 + B1, s3 = s2 + B0, s4 = s3 + B3, sEnd = s4 + B0;
  scanA<<<sEnd, 256, 0, stream>>>(cnt, part, NP, NO, NP, NL, NP, s1, s2, s3, s4);
  scanB<<<5, 64, 0, stream>>>(part, off, NP, NO, NP, NL, NP, s1, s2, s3, s4, sEnd);
  scanC<<<sEnd, 256, 0, stream>>>(cnt, part, off, NP, NO, NP, NL, NP, s1, s2, s3, s4);

  fill5<<<(E5 + 255) / 256, 256, 0, stream>>>(
      acts_src, uses_src, uses_dst, at_src, at_dst,
      acts_dst, uses_dst, uses_src, at_dst, at_src,
      off, cur, csr, E1, E2, E3, E4, E5,
      c1, c2, c3, c4, o1, o2, o3, o4, NP, NO, NP, NL, NP);

  const u16 *pF, *oF, *lF;
  if (fits) {
    // ---- NEW PATH: decoupled aggregation + MFMA GEMM, in-place features ----
    int tP = (NP + 15) >> 4, tO = (NO + 15) >> 4, tL = (NL + 15) >> 4;
    int gP = (tP + 3) / 4; if (gP > 1024) gP = 1024;
    int gO = (tO + 3) / 4; if (gO > 512)  gO = 512;
    int gL = (tL + 3) / 4; if (gL > 256)  gL = 256;
    for (int t = 0; t < 3; t++) {
      // person means (3 relations fused), then obj/loc means (read pX, so they
      // must run BEFORE the in-place person GEMM overwrites pX)
      agg_mean3<<<(NP + 3) / 4, 256, 0, stream>>>(
          pX, off + o0, csr0, NP,
          oX, off + o2, csr2, NO,
          lX, off + o4, csr4, NL,
          pAg0, pAg1, pAg2, NP);
      agg_mean<<<(NO + 3) / 4, 256, 0, stream>>>(pX, off + o1, csr1, oAg, NO, NP);
      agg_mean<<<(NL + 3) / 4, 256, 0, stream>>>(pX, off + o3, csr3, lAg, NL, NP);
      gemm_sage<3><<<gP, 256, 0, stream>>>(pAg0, pAg1, pAg2, pX, pX,
                                           Wl, bl, Wr, t, 0, 2, 4, 1.f / 3.f, NP);
      gemm_sage<1><<<gO, 256, 0, stream>>>(oAg, (const u16*)0, (const u16*)0, oX, oX,
                                           Wl, bl, Wr, t, 1, 0, 0, 1.f, NO);
      gemm_sage<1><<<gL, 256, 0, stream>>>(lAg, (const u16*)0, (const u16*)0, lX, lX,
                                           Wl, bl, Wr, t, 3, 0, 0, 1.f, NL);
    }
    pF = pX; oF = oX; lF = lX;
  } else {
    // ---- OLD PATH (fallback): fused wave-per-node SAGE with ping-pong ----
    u16* pb[2] = {pX, pAg0};
    u16* ob[2] = {oX, oAg};
    u16* lb[2] = {lX, lAg};
    int bP = (NP + 3) / 4, bO = (NO + 3) / 4, bL = (NL + 3) / 4;
    int cu = 0;
    int4 relsP = {0, 2, 4, 0}, relsO = {1, 1, 1, 0}, relsL = {3, 3, 3, 0};
    for (int t = 0; t < 3; t++) {
      u16 *pi = pb[cu], *po = pb[1 - cu];
      u16 *oi = ob[cu], *oo = ob[1 - cu];
      u16 *li = lb[cu], *lo = lb[1 - cu];
      sage_node<<<bP, 256, 0, stream>>>(pi, po, NP, 1.f / 3.f, Wl, bl, Wr, t, 3, relsP,
          pi, off + o0, csr0, NP,
          oi, off + o2, csr2, NO,
          li, off + o4, csr4, NL);
      sage_node<<<bO, 256, 0, stream>>>(oi, oo, NO, 1.f, Wl, bl, Wr, t, 1, relsO,
          pi, off + o1, csr1, NP,
          (const u16*)0, (const int*)0, (const int*)0, 0,
          (const u16*)0, (const int*)0, (const int*)0, 0);
      sage_node<<<bL, 256, 0, stream>>>(li, lo, NL, 1.f, Wl, bl, Wr, t, 1, relsL,
          pi, off + o3, csr3, NP,
          (const u16*)0, (const int*)0, (const int*)0, 0,
          (const u16*)0, (const int*)0, (const int*)0, 0);
      cu = 1 - cu;
    }
    pF = pb[cu]; oF = ob[cu]; lF = lb[cu];
  }

  // ---- readout (FP32 output) ----
  colsum2<<<512, 256, 0, stream>>>(pF, NP, gsum);
  colsum2<<<512, 256, 0, stream>>>(oF, NO, gsum + 64);
  colsum2<<<256, 256, 0, stream>>>(lF, NL, gsum + 128);
  head2<<<1, 256, 0, stream>>>(gsum, Wc1, bc1, Wc2, bc2, NP, NO, NL, out);
  suspect2<<<(NP + 255) / 256, 256, 0, stream>>>(pF, Ws1, bs1, Ws2, bs2, out + 20, NP);
}

// Round 3
// 1809.302 us; speedup vs baseline: 1.2222x; 1.2222x over previous
//
#include <hip/hip_runtime.h>

typedef unsigned short u16;
typedef unsigned int u32;
typedef __attribute__((ext_vector_type(8))) short bf16x8;
typedef __attribute__((ext_vector_type(4))) float f32x4;

__device__ __forceinline__ float bf2f(u16 u) { return __uint_as_float(((u32)u) << 16); }
__device__ __forceinline__ u16 f2bf(float f) {
  u32 u = __float_as_uint(f);
  return (u16)((u + 0x7fffu + ((u >> 16) & 1u)) >> 16);
}

// ---------------------------------------------------------------------------
// Embedding gather: fp32 emb row -> internal bf16 feature row. 1 thread/elem.
__global__ void gather_f2b(const float* __restrict__ emb, const int* __restrict__ ids,
                           u16* __restrict__ out, int n, int V) {
  int u = blockIdx.x * 256 + threadIdx.x;
  if (u >= n * 64) return;
  int node = u >> 6, k = u & 63;
  int r = ids[node];
  r = ((u32)r < (u32)V) ? r : 0;
  out[u] = f2bf(emb[(size_t)r * 64 + k]);
}

// ---------------------------------------------------------------------------
// Weight prep (once per launch): bf16 lin weights, bf16 root-sum weights,
// fp32 bias-sums. Kills per-wave fp32->bf16 conversion in the GEMM hot loop.
// WBlin: [3][5][4096] bf16 (same flat layout as Wl)
// WBroot: [3][3][4096] bf16; c: 0=person sum(Wr[0,2,4]), 1=object Wr[1], 2=loc Wr[3]
// bsums: [3][3][64] fp32;    same c mapping over bl
__global__ void prep_w(const float* __restrict__ Wl, const float* __restrict__ Wr,
                       const float* __restrict__ bl,
                       u16* __restrict__ WBlin, u16* __restrict__ WBroot,
                       float* __restrict__ bsums) {
  int i = blockIdx.x * 256 + threadIdx.x;
  const int TL = 3 * 5 * 4096;
  if (i < TL) { WBlin[i] = f2bf(Wl[i]); return; }
  int j = i - TL;
  if (j < 3 * 3 * 4096) {
    int lt = j / (3 * 4096), rem = j % (3 * 4096), c = rem / 4096, e = rem % 4096;
    int r0 = (c == 0) ? 0 : (c == 1) ? 1 : 3;
    float v = Wr[((size_t)lt * 5 + r0) * 4096 + e];
    if (c == 0) v += Wr[((size_t)lt * 5 + 2) * 4096 + e] +
                     Wr[((size_t)lt * 5 + 4) * 4096 + e];
    WBroot[j] = f2bf(v);
    return;
  }
  int k2 = j - 3 * 3 * 4096;
  if (k2 < 3 * 3 * 64) {
    int lt = k2 / 192, rem = k2 % 192, c = rem / 64, e = rem % 64;
    int r0 = (c == 0) ? 0 : (c == 1) ? 1 : 3;
    float v = bl[((size_t)lt * 5 + r0) * 64 + e];
    if (c == 0) v += bl[((size_t)lt * 5 + 2) * 64 + e] +
                     bl[((size_t)lt * 5 + 4) * 64 + e];
    bsums[k2] = v;
  }
}

// ---------------------------------------------------------------------------
// Fused degree histogram over all 5 relations (one launch).
__global__ void hist5(const int* __restrict__ d0, const int* __restrict__ d1,
                      const int* __restrict__ d2, const int* __restrict__ d3,
                      const int* __restrict__ d4, int* __restrict__ cnt,
                      int E1, int E2, int E3, int E4, int E5,
                      int c1, int c2, int c3, int c4,
                      int N0, int N1, int N2, int N3, int N4) {
  int e = blockIdx.x * 256 + threadIdx.x;
  if (e >= E5) return;
  const int* dp; int cb, N, le;
  if (e < E1)      { dp = d0; cb = 0;  N = N0; le = e; }
  else if (e < E2) { dp = d1; cb = c1; N = N1; le = e - E1; }
  else if (e < E3) { dp = d2; cb = c2; N = N2; le = e - E2; }
  else if (e < E4) { dp = d3; cb = c3; N = N3; le = e - E3; }
  else             { dp = d4; cb = c4; N = N4; le = e - E4; }
  int d = dp[le];
  if ((u32)d < (u32)N) atomicAdd(&cnt[cb + d], 1);
}

// ---------------------------------------------------------------------------
// Hierarchical exclusive scan of the 5 concatenated degree arrays.
__global__ void __launch_bounds__(256) scanA(const int* __restrict__ cnt, int* __restrict__ part,
    int n0, int n1, int n2, int n3, int n4, int s1, int s2, int s3, int s4) {
  int Ns[5] = {n0, n1, n2, n3, n4};
  int b = blockIdx.x;
  int r = (b >= s4) ? 4 : (b >= s3) ? 3 : (b >= s2) ? 2 : (b >= s1) ? 1 : 0;
  int sr = (r == 0) ? 0 : (r == 1) ? s1 : (r == 2) ? s2 : (r == 3) ? s3 : s4;
  int cOff = 0;
  for (int i = 0; i < r; i++) cOff += Ns[i];
  int lb = b - sr;
  int rem = Ns[r] - lb * 2048; if (rem > 2048) rem = 2048;
  const int* c = cnt + cOff + (size_t)lb * 2048;
  int t = threadIdx.x;
  int s = 0;
  #pragma unroll
  for (int j = 0; j < 8; j++) { int i = t + j * 256; s += (i < rem) ? c[i] : 0; }
  #pragma unroll
  for (int d = 1; d < 64; d <<= 1) s += __shfl_xor(s, d);
  __shared__ int ws[4];
  if ((t & 63) == 0) ws[t >> 6] = s;
  __syncthreads();
  if (t == 0) part[b] = ws[0] + ws[1] + ws[2] + ws[3];
}

__global__ void __launch_bounds__(64) scanB(int* __restrict__ part, int* __restrict__ off,
    int n0, int n1, int n2, int n3, int n4, int s1, int s2, int s3, int s4, int sEnd) {
  int Ns[5] = {n0, n1, n2, n3, n4};
  int Ss[6] = {0, s1, s2, s3, s4, sEnd};
  int r = blockIdx.x;
  int sr = Ss[r], er = Ss[r + 1];
  int oOff = 0;
  for (int i = 0; i < r; i++) oOff += Ns[i] + 1;
  int lane = threadIdx.x;
  int carry = 0;
  for (int base = sr; base < er; base += 64) {
    int i = base + lane;
    int v = (i < er) ? part[i] : 0;
    int s = v;
    #pragma unroll
    for (int d = 1; d < 64; d <<= 1) { int u = __shfl_up(s, d); if (lane >= d) s += u; }
    if (i < er) part[i] = carry + (s - v);
    carry += __shfl(s, 63);
  }
  if (lane == 0) off[oOff + Ns[r]] = carry;   // sentinel = relation total
}

__global__ void __launch_bounds__(256) scanC(const int* __restrict__ cnt,
    const int* __restrict__ part, int* __restrict__ off,
    int n0, int n1, int n2, int n3, int n4, int s1, int s2, int s3, int s4) {
  int Ns[5] = {n0, n1, n2, n3, n4};
  int b = blockIdx.x;
  int r = (b >= s4) ? 4 : (b >= s3) ? 3 : (b >= s2) ? 2 : (b >= s1) ? 1 : 0;
  int sr = (r == 0) ? 0 : (r == 1) ? s1 : (r == 2) ? s2 : (r == 3) ? s3 : s4;
  int cOff = 0, oOff = 0;
  for (int i = 0; i < r; i++) { cOff += Ns[i]; oOff += Ns[i] + 1; }
  int lb = b - sr;
  int rem = Ns[r] - lb * 2048; if (rem > 2048) rem = 2048;
  const int* c = cnt + cOff + (size_t)lb * 2048;
  int* of = off + oOff + (size_t)lb * 2048;
  int t = threadIdx.x, lane = t & 63, wave = t >> 6;
  int base = t * 8;
  int v[8];
  #pragma unroll
  for (int j = 0; j < 8; j++) v[j] = (base + j < rem) ? c[base + j] : 0;
  int tsum = 0;
  #pragma unroll
  for (int j = 0; j < 8; j++) tsum += v[j];
  int s = tsum;
  #pragma unroll
  for (int d = 1; d < 64; d <<= 1) { int u = __shfl_up(s, d); if (lane >= d) s += u; }
  __shared__ int ws[4];
  if (lane == 63) ws[wave] = s;
  __syncthreads();
  int wbase = 0;
  #pragma unroll
  for (int i = 0; i < 4; i++) wbase += (i < wave) ? ws[i] : 0;
  int run = part[b] + wbase + (s - tsum);
  #pragma unroll
  for (int j = 0; j < 8; j++) { if (base + j < rem) of[base + j] = run; run += v[j]; }
}

// ---------------------------------------------------------------------------
// Fused CSR fill over all 5 relations. csr global offset = segment start (e-le).
__global__ void fill5(
    const int* __restrict__ s0, const int* __restrict__ s1p, const int* __restrict__ s2p,
    const int* __restrict__ s3p, const int* __restrict__ s4p,
    const int* __restrict__ d0, const int* __restrict__ d1, const int* __restrict__ d2,
    const int* __restrict__ d3, const int* __restrict__ d4,
    const int* __restrict__ off, int* __restrict__ cur, int* __restrict__ csr,
    int E1, int E2, int E3, int E4, int E5,
    int c1, int c2, int c3, int c4,
    int o1, int o2, int o3, int o4,
    int N0, int N1, int N2, int N3, int N4) {
  int e = blockIdx.x * 256 + threadIdx.x;
  if (e >= E5) return;
  const int *sp, *dp; int cb, ob, N, le, El;
  if (e < E1)      { sp = s0;  dp = d0; cb = 0;  ob = 0;  N = N0; le = e;      El = E1; }
  else if (e < E2) { sp = s1p; dp = d1; cb = c1; ob = o1; N = N1; le = e - E1; El = E2 - E1; }
  else if (e < E3) { sp = s2p; dp = d2; cb = c2; ob = o2; N = N2; le = e - E2; El = E3 - E2; }
  else if (e < E4) { sp = s3p; dp = d3; cb = c3; ob = o3; N = N3; le = e - E3; El = E4 - E3; }
  else             { sp = s4p; dp = d4; cb = c4; ob = o4; N = N4; le = e - E4; El = E5 - E4; }
  int d = dp[le];
  if ((u32)d < (u32)N) {
    int pos = off[ob + d] + atomicAdd(&cur[cb + d], 1);
    if ((u32)pos < (u32)El) csr[(e - le) + pos] = sp[le];
  }
}

// ---------------------------------------------------------------------------
// OLD PATH (fallback if workspace too small): wave-per-node fused SAGE.
__device__ __forceinline__ float gmean(const u16* __restrict__ src, const int* __restrict__ off,
                                       const int* __restrict__ idx, u32 ns, int g, int lane) {
  int e0 = off[g], e1 = off[g + 1];
  float a0 = 0.f, a1 = 0.f, a2 = 0.f, a3 = 0.f;
  int e = e0;
  for (; e + 4 <= e1; e += 4) {
    int A = idx[e], B = idx[e + 1], C = idx[e + 2], D = idx[e + 3];
    A = ((u32)A < ns) ? A : 0;
    B = ((u32)B < ns) ? B : 0;
    C = ((u32)C < ns) ? C : 0;
    D = ((u32)D < ns) ? D : 0;
    a0 += bf2f(src[(size_t)A * 64 + lane]);
    a1 += bf2f(src[(size_t)B * 64 + lane]);
    a2 += bf2f(src[(size_t)C * 64 + lane]);
    a3 += bf2f(src[(size_t)D * 64 + lane]);
  }
  for (; e < e1; e++) {
    int A = idx[e];
    A = ((u32)A < ns) ? A : 0;
    a0 += bf2f(src[(size_t)A * 64 + lane]);
  }
  float s = (a0 + a1) + (a2 + a3);
  int d = e1 - e0;
  return (d > 0) ? s * (1.f / (float)d) : 0.f;
}

__device__ __forceinline__ void stageW(float* __restrict__ Wsh, const float* __restrict__ Wb,
                                       int t) {
  #pragma unroll
  for (int j = 0; j < 4; j++) {
    int i4 = t + j * 256;
    float4 v = ((const float4*)Wb)[i4];
    int o = (i4 * 4) >> 6, k = (i4 * 4) & 63;
    float* dst = &Wsh[o * 65 + k];
    dst[0] = v.x; dst[1] = v.y; dst[2] = v.z; dst[3] = v.w;
  }
}

__global__ void __launch_bounds__(256) sage_node(
    const u16* __restrict__ xin, u16* __restrict__ xout, int n_dst, float scale,
    const float* __restrict__ Wl, const float* __restrict__ bl, const float* __restrict__ Wr,
    int lt, int nAgg, int4 rels,
    const u16* s0, const int* of0, const int* ix0, int ns0,
    const u16* s1, const int* of1, const int* ix1, int ns1,
    const u16* s2, const int* of2, const int* ix2, int ns2) {
  __shared__ float Wsh[64 * 65];
  int t = threadIdx.x, wave = t >> 6, lane = t & 63;
  int g = blockIdx.x * 4 + wave;
  bool act = g < n_dst;

  float m0 = act ? gmean(s0, of0, ix0, (u32)ns0, g, lane) : 0.f;
  float m1 = (act && nAgg > 1) ? gmean(s1, of1, ix1, (u32)ns1, g, lane) : 0.f;
  float m2 = (act && nAgg > 2) ? gmean(s2, of2, ix2, (u32)ns2, g, lane) : 0.f;
  float xv = act ? bf2f(xin[(size_t)g * 64 + lane]) : 0.f;

  float acc = 0.f;
  for (int p = 0; p < nAgg; p++) {
    int r = (p == 0) ? rels.x : (p == 1) ? rels.y : rels.z;
    const float* Wb = Wl + ((size_t)lt * 5 + r) * 4096;
    __syncthreads();
    stageW(Wsh, Wb, t);
    __syncthreads();
    float mv = (p == 0) ? m0 : (p == 1) ? m1 : m2;
    #pragma unroll
    for (int k = 0; k < 64; k++)
      acc += __shfl(mv, k) * Wsh[lane * 65 + k];
  }
  {
    const float* w0 = Wr + ((size_t)lt * 5 + rels.x) * 4096;
    const float* w1 = Wr + ((size_t)lt * 5 + rels.y) * 4096;
    const float* w2 = Wr + ((size_t)lt * 5 + rels.z) * 4096;
    __syncthreads();
    #pragma unroll
    for (int j = 0; j < 4; j++) {
      int i4 = t + j * 256;
      float4 v = ((const float4*)w0)[i4];
      if (nAgg > 1) {
        float4 b = ((const float4*)w1)[i4];
        float4 c = ((const float4*)w2)[i4];
        v.x += b.x + c.x; v.y += b.y + c.y; v.z += b.z + c.z; v.w += b.w + c.w;
      }
      int o = (i4 * 4) >> 6, k = (i4 * 4) & 63;
      float* dst = &Wsh[o * 65 + k];
      dst[0] = v.x; dst[1] = v.y; dst[2] = v.z; dst[3] = v.w;
    }
    __syncthreads();
    #pragma unroll
    for (int k = 0; k < 64; k++)
      acc += __shfl(xv, k) * Wsh[lane * 65 + k];
  }

  float bsum = bl[((size_t)lt * 5 + rels.x) * 64 + lane];
  if (nAgg > 1) bsum += bl[((size_t)lt * 5 + rels.y) * 64 + lane] +
                        bl[((size_t)lt * 5 + rels.z) * 64 + lane];

  if (act) {
    float v = fmaxf((acc + bsum) * scale, 0.f) + xv;
    xout[(size_t)g * 64 + lane] = f2bf(v);
  }
}

// ---------------------------------------------------------------------------
// Barrier-free mean-gather, one wave per dst node, ILP-8 predicated
// (one L2/L3 latency round covers deg<=8, ~92% of Poisson(5) nodes).
// Low-VGPR on purpose: runs at 8 blocks/CU.
__global__ void __launch_bounds__(256, 8) agg_mean(
    const u16* __restrict__ src, const int* __restrict__ off, const int* __restrict__ idx,
    u16* __restrict__ out, int n_dst, int ns) {
  int t = threadIdx.x;
  int g = blockIdx.x * 4 + (t >> 6);
  int lane = t & 63;
  if (g >= n_dst) return;
  int e0 = off[g], e1 = off[g + 1];
  int d = e1 - e0;
  float a[8] = {0.f, 0.f, 0.f, 0.f, 0.f, 0.f, 0.f, 0.f};
  int eL = e1 - 1;
  for (int base = e0; base < e1; base += 8) {
    int id[8];
    #pragma unroll
    for (int j = 0; j < 8; j++) {
      int e = base + j;
      int i = idx[e <= eL ? e : eL];       // clamped: always a valid address
      id[j] = ((u32)i < (u32)ns) ? i : 0;
    }
    float v[8];
    #pragma unroll
    for (int j = 0; j < 8; j++)            // 8 independent row loads in flight
      v[j] = bf2f(src[(size_t)id[j] * 64 + lane]);
    #pragma unroll
    for (int j = 0; j < 8; j++)
      a[j] += (base + j < e1) ? v[j] : 0.f;
  }
  float s = ((a[0] + a[1]) + (a[2] + a[3])) + ((a[4] + a[5]) + (a[6] + a[7]));
  float mean = (d > 0) ? s / (float)d : 0.f;
  out[(size_t)g * 64 + lane] = f2bf(mean);
}

// ---------------------------------------------------------------------------
// MFMA GEMM. C = [A0|A1|..|X] @ Wstack^T, fused epilogue relu((C+b)*s)+x,
// bf16 IN-PLACE output (safe: each wave reads its 16 rows before storing).
// Weights are PRE-CONVERTED bf16 (prep_w); B fragments are reloaded from the
// 32KB L2-hot weight set inside the kc-loop, so only 4-8 B-frags are live
// -> ~90 VGPRs, no scratch spill (round-1/2 version held 128 VGPRs of B under
// a 128-VGPR launch_bounds cap = spill = 200us at 0.2% VALUBusy).
// Epilogue staged through per-wave LDS [16][65] for coalesced 16B/lane stores.
template <int NM>
__global__ void __launch_bounds__(256, 4) gemm_sage(
    const u16* __restrict__ A0, const u16* __restrict__ A1, const u16* __restrict__ A2,
    const u16* X, u16* out,  // no __restrict__: out aliases X (in-place)
    const u16* __restrict__ lin0, const u16* __restrict__ lin1, const u16* __restrict__ lin2,
    const u16* __restrict__ root, const float* __restrict__ bsum,
    float scale, int n) {
  constexpr int KC = 2 * (NM + 1);          // K-chunks of 32
  __shared__ float ldsAcc[4][16 * 65];
  int t = threadIdx.x, wave = t >> 6, lane = t & 63;
  int col0 = lane & 15, kb = lane >> 4;
  float* lw = ldsAcc[wave];

  // per-kc weight base (lane-dependent k offset folded in)
  const u16* Wbase[KC];
  #pragma unroll
  for (int kc = 0; kc < KC; kc++) {
    int m = kc >> 1;
    const u16* basep = (m < NM) ? ((m == 0) ? lin0 : (m == 1) ? lin1 : lin2) : root;
    Wbase[kc] = basep + (kc & 1) * 32 + kb * 8;
  }

  // per-lane epilogue bias: 8 consecutive cols starting at (lane&7)*8
  int ccl = (lane & 7) * 8;
  float4 blo = *(const float4*)(bsum + ccl);
  float4 bhi = *(const float4*)(bsum + ccl + 4);
  float bsum8[8] = {blo.x, blo.y, blo.z, blo.w, bhi.x, bhi.y, bhi.z, bhi.w};

  // ---- M loop: 16 rows per wave-tile, grid-stride ----
  int ntiles = (n + 15) >> 4;
  for (int tile = blockIdx.x * 4 + wave; tile < ntiles; tile += gridDim.x * 4) {
    int m0 = tile << 4;
    int rowA = m0 + col0;
    rowA = (rowA < n) ? rowA : (n - 1);
    bf16x8 Af[KC];
    #pragma unroll
    for (int kc = 0; kc < KC; kc++) {       // issue all A loads first (MLP)
      int m = kc >> 1;
      const u16* s = (m < NM) ? ((m == 0) ? A0 : (m == 1) ? A1 : A2) : X;
      int kk = (kc & 1) * 32 + kb * 8;
      Af[kc] = *(const bf16x8*)(s + (size_t)rowA * 64 + kk);  // 16B, aligned
    }
    f32x4 acc[4] = {};
    #pragma unroll
    for (int kc = 0; kc < KC; kc++) {
      #pragma unroll
      for (int nt = 0; nt < 4; nt++) {
        bf16x8 B = *(const bf16x8*)(Wbase[kc] + (nt * 16 + col0) * 64);  // L1/L2 hot
        acc[nt] = __builtin_amdgcn_mfma_f32_16x16x32_bf16(Af[kc], B, acc[nt], 0, 0, 0);
      }
    }
    // stage D tile to LDS in MFMA layout: row=kb*4+j, col=nt*16+col0 (pad 65)
    #pragma unroll
    for (int nt = 0; nt < 4; nt++)
      #pragma unroll
      for (int j = 0; j < 4; j++)
        lw[(kb * 4 + j) * 65 + nt * 16 + col0] = acc[nt][j];
    // re-read row-contiguous: lane -> row (lane>>3), 8-col chunk (lane&7)*8
    #pragma unroll
    for (int it = 0; it < 2; it++) {
      int r16 = it * 8 + (lane >> 3);
      int row = m0 + r16;
      float vv[8];
      #pragma unroll
      for (int j = 0; j < 8; j++) vv[j] = lw[r16 * 65 + ccl + j];
      if (row < n) {
        bf16x8 xv8 = *(const bf16x8*)(X + (size_t)row * 64 + ccl);
        bf16x8 o8;
        #pragma unroll
        for (int j = 0; j < 8; j++) {
          float xvf = bf2f((u16)xv8[j]);
          float v = fmaxf((vv[j] + bsum8[j]) * scale, 0.f) + xvf;
          o8[j] = (short)f2bf(v);
        }
        *(bf16x8*)(out + (size_t)row * 64 + ccl) = o8;   // 16B coalesced store
      }
    }
  }
}

// ---------------------------------------------------------------------------
// Column sums over bf16 features (graph-mean readout)
__global__ void colsum2(const u16* __restrict__ x, int n, float* __restrict__ gout) {
  __shared__ float part[64];
  int t = threadIdx.x;
  if (t < 64) part[t] = 0.f;
  __syncthreads();
  int col = t & 63, w = blockIdx.x * 4 + (t >> 6), tw = gridDim.x * 4;
  float s = 0.f;
  for (int r = w; r < n; r += tw) s += bf2f(x[(size_t)r * 64 + col]);
  atomicAdd(&part[col], s);
  __syncthreads();
  if (t < 64) atomicAdd(&gout[t], part[t]);
}

// Crime head: out[0:20) as FP32
__global__ void __launch_bounds__(256) head2(const float* __restrict__ gsum,
    const float* __restrict__ Wc1, const float* __restrict__ bc1,
    const float* __restrict__ Wc2, const float* __restrict__ bc2,
    int NP, int NO, int NL, float* __restrict__ out) {
  __shared__ float g[192];
  __shared__ float h[64];
  int t = threadIdx.x;
  if (t < 192) {
    float d = (t < 64) ? (float)NP : (t < 128) ? (float)NO : (float)NL;
    g[t] = gsum[t] / d;
  }
  __syncthreads();
  if (t < 64) {
    float a = bc1[t];
    for (int k = 0; k < 192; k++) a += g[k] * Wc1[(size_t)t * 192 + k];
    h[t] = fmaxf(a, 0.f);
  }
  __syncthreads();
  if (t < 20) {
    float a = bc2[t];
    for (int k = 0; k < 64; k++) a += h[k] * Wc2[(size_t)t * 64 + k];
    out[t] = a;
  }
}

// Suspect head: out[i] as FP32 (out passed pre-offset by +20)
__global__ void __launch_bounds__(256) suspect2(const u16* __restrict__ p,
    const float* __restrict__ Ws1, const float* __restrict__ bs1,
    const float* __restrict__ Ws2, const float* __restrict__ bs2,
    float* __restrict__ out, int NP) {
  __shared__ float W1[2048];
  __shared__ float b1[32], w2[32];
  __shared__ float b2s;
  int t = threadIdx.x;
  #pragma unroll
  for (int i = 0; i < 8; i++) {
    int d = t + i * 256;
    W1[d] = Ws1[d];
  }
  if (t < 32) { b1[t] = bs1[t]; w2[t] = Ws2[t]; }
  if (t == 0) b2s = bs2[0];
  __syncthreads();
  int i = blockIdx.x * 256 + t;
  if (i >= NP) return;
  float x[64];
  #pragma unroll
  for (int k = 0; k < 64; k++) x[k] = bf2f(p[(size_t)i * 64 + k]);
  float sc = b2s;
  for (int j = 0; j < 32; j++) {
    float a = b1[j];
    const float* wr = &W1[j * 64];
    #pragma unroll
    for (int k = 0; k < 64; k++) a += x[k] * wr[k];
    sc += fmaxf(a, 0.f) * w2[j];
  }
  out[i] = sc;
}

// ---------------------------------------------------------------------------
extern "C" void kernel_launch(void* const* d_in, const int* in_sizes, int n_in,
                              void* d_out, int out_size, void* d_ws, size_t ws_size,
                              hipStream_t stream) {
  const int NP = in_sizes[0], NO = in_sizes[1], NL = in_sizes[2];
  const int Ea = in_sizes[3], Eu = in_sizes[5], Et = in_sizes[7];
  const int VP = in_sizes[9] / 64, VO = in_sizes[10] / 64, VL = in_sizes[11] / 64;

  const int* x_person   = (const int*)d_in[0];
  const int* x_object   = (const int*)d_in[1];
  const int* x_location = (const int*)d_in[2];
  const int* acts_src = (const int*)d_in[3];
  const int* acts_dst = (const int*)d_in[4];
  const int* uses_src = (const int*)d_in[5];
  const int* uses_dst = (const int*)d_in[6];
  const int* at_src   = (const int*)d_in[7];
  const int* at_dst   = (const int*)d_in[8];
  const float* person_emb   = (const float*)d_in[9];
  const float* object_emb   = (const float*)d_in[10];
  const float* location_emb = (const float*)d_in[11];
  const float* Wl  = (const float*)d_in[12];
  const float* bl  = (const float*)d_in[13];
  const float* Wr  = (const float*)d_in[14];
  const float* Wc1 = (const float*)d_in[15];
  const float* bc1 = (const float*)d_in[16];
  const float* Wc2 = (const float*)d_in[17];
  const float* bc2 = (const float*)d_in[18];
  const float* Ws1 = (const float*)d_in[19];
  const float* bs1 = (const float*)d_in[20];
  const float* Ws2 = (const float*)d_in[21];
  const float* bs2 = (const float*)d_in[22];
  float* out = (float*)d_out;

  // ---- workspace (16B aligned) ----
  char* w = (char*)d_ws;
  auto alloc = [&](size_t bytes) { char* r = w; w += (bytes + 15) & ~(size_t)15; return r; };
  u16* pX   = (u16*)alloc((size_t)NP * 128);
  u16* pAg0 = (u16*)alloc((size_t)NP * 128);   // old path: pB
  u16* oX   = (u16*)alloc((size_t)NO * 128);
  u16* oAg  = (u16*)alloc((size_t)NO * 128);   // old path: oB
  u16* lX   = (u16*)alloc((size_t)NL * 128);
  u16* lAg  = (u16*)alloc((size_t)NL * 128);   // old path: lB
  float* gsum = (float*)alloc(192 * 4);
  const size_t CN = (size_t)3 * NP + NO + NL;
  int* cnt = (int*)alloc(CN * 4);
  int* cur = (int*)alloc(CN * 4);
  int* off = (int*)alloc((CN + 8) * 4);
  int* part = (int*)alloc(4096 * 4);           // scan chunk partials (<=1024 used)
  u16* WBlin  = (u16*)alloc((size_t)3 * 5 * 4096 * 2);
  u16* WBroot = (u16*)alloc((size_t)3 * 3 * 4096 * 2);
  float* bsums = (float*)alloc((size_t)3 * 3 * 64 * 4);
  int* csr = (int*)alloc(((size_t)Ea + 2 * (size_t)Eu + 2 * (size_t)Et) * 4);
  size_t base_need = (size_t)(w - (char*)d_ws);
  u16* pAg1 = (u16*)alloc((size_t)NP * 128);   // new-path extras
  u16* pAg2 = (u16*)alloc((size_t)NP * 128);
  size_t full_need = (size_t)(w - (char*)d_ws);
  (void)n_in; (void)out_size;
  // ws guard: if it fires, out stays 0 -> absmax == 0.118652 exactly (signature)
  if (base_need > ws_size) return;
  bool fits = (full_need <= ws_size);

  int c1 = NP, c2 = NP + NO, c3 = 2 * NP + NO, c4 = 2 * NP + NO + NL;
  int o0 = 0, o1 = NP + 1, o2 = o1 + NO + 1, o3 = o2 + NP + 1, o4 = o3 + NL + 1;
  int* csr0 = csr;
  int* csr1 = csr0 + Ea;
  int* csr2 = csr1 + Eu;
  int* csr3 = csr2 + Eu;
  int* csr4 = csr3 + Et;

  hipMemsetAsync(cnt, 0, CN * 2 * sizeof(int), stream);  // cnt + cur adjacent
  hipMemsetAsync(gsum, 0, 192 * sizeof(float), stream);

  prep_w<<<387, 256, 0, stream>>>(Wl, Wr, bl, WBlin, WBroot, bsums);

  gather_f2b<<<(NP * 64 + 255) / 256, 256, 0, stream>>>(person_emb, x_person, pX, NP, VP);
  gather_f2b<<<(NO * 64 + 255) / 256, 256, 0, stream>>>(object_emb, x_object, oX, NO, VO);
  gather_f2b<<<(NL * 64 + 255) / 256, 256, 0, stream>>>(location_emb, x_location, lX, NL, VL);

  // ---- CSR build: fused hist, 3-phase scan, fused fill ----
  int E1 = Ea, E2 = E1 + Eu, E3 = E2 + Eu, E4 = E3 + Et, E5 = E4 + Et;
  hist5<<<(E5 + 255) / 256, 256, 0, stream>>>(acts_dst, uses_dst, uses_src, at_dst, at_src,
      cnt, E1, E2, E3, E4, E5, c1, c2, c3, c4, NP, NO, NP, NL, NP);

  int B0 = (NP + 2047) / 2048, B1 = (NO + 2047) / 2048, B3 = (NL + 2047) / 2048;
  int s1 = B0, s2 = s1 + B1, s3 = s2 + B0, s4 = s3 + B3, sEnd = s4 + B0;
  scanA<<<sEnd, 256, 0, stream>>>(cnt, part, NP, NO, NP, NL, NP, s1, s2, s3, s4);
  scanB<<<5, 64, 0, stream>>>(part, off, NP, NO, NP, NL, NP, s1, s2, s3, s4, sEnd);
  scanC<<<sEnd, 256, 0, stream>>>(cnt, part, off, NP, NO, NP, NL, NP, s1, s2, s3, s4);

  fill5<<<(E5 + 255) / 256, 256, 0, stream>>>(
      acts_src, uses_src, uses_dst, at_src, at_dst,
      acts_dst, uses_dst, uses_src, at_dst, at_src,
      off, cur, csr, E1, E2, E3, E4, E5,
      c1, c2, c3, c4, o1, o2, o3, o4, NP, NO, NP, NL, NP);

  const u16 *pF, *oF, *lF;
  if (fits) {
    // ---- NEW PATH: decoupled aggregation + MFMA GEMM, in-place features ----
    int tP = (NP + 15) >> 4, tO = (NO + 15) >> 4, tL = (NL + 15) >> 4;
    int gP = (tP + 3) / 4; if (gP > 1024) gP = 1024;
    int gO = (tO + 3) / 4; if (gO > 512)  gO = 512;
    int gL = (tL + 3) / 4; if (gL > 256)  gL = 256;
    for (int t = 0; t < 3; t++) {
      // person means (3 relations), then obj/loc means (these read pX, so they
      // must run BEFORE the in-place person GEMM overwrites pX)
      agg_mean<<<(NP + 3) / 4, 256, 0, stream>>>(pX, off + o0, csr0, pAg0, NP, NP);
      agg_mean<<<(NP + 3) / 4, 256, 0, stream>>>(oX, off + o2, csr2, pAg1, NP, NO);
      agg_mean<<<(NP + 3) / 4, 256, 0, stream>>>(lX, off + o4, csr4, pAg2, NP, NL);
      agg_mean<<<(NO + 3) / 4, 256, 0, stream>>>(pX, off + o1, csr1, oAg, NO, NP);
      agg_mean<<<(NL + 3) / 4, 256, 0, stream>>>(pX, off + o3, csr3, lAg, NL, NP);
      gemm_sage<3><<<gP, 256, 0, stream>>>(pAg0, pAg1, pAg2, pX, pX,
          WBlin + ((size_t)t * 5 + 0) * 4096,
          WBlin + ((size_t)t * 5 + 2) * 4096,
          WBlin + ((size_t)t * 5 + 4) * 4096,
          WBroot + ((size_t)t * 3 + 0) * 4096,
          bsums + ((size_t)t * 3 + 0) * 64, 1.f / 3.f, NP);
      gemm_sage<1><<<gO, 256, 0, stream>>>(oAg, (const u16*)0, (const u16*)0, oX, oX,
          WBlin + ((size_t)t * 5 + 1) * 4096, (const u16*)0, (const u16*)0,
          WBroot + ((size_t)t * 3 + 1) * 4096,
          bsums + ((size_t)t * 3 + 1) * 64, 1.f, NO);
      gemm_sage<1><<<gL, 256, 0, stream>>>(lAg, (const u16*)0, (const u16*)0, lX, lX,
          WBlin + ((size_t)t * 5 + 3) * 4096, (const u16*)0, (const u16*)0,
          WBroot + ((size_t)t * 3 + 2) * 4096,
          bsums + ((size_t)t * 3 + 2) * 64, 1.f, NL);
    }
    pF = pX; oF = oX; lF = lX;
  } else {
    // ---- OLD PATH (fallback): fused wave-per-node SAGE with ping-pong ----
    u16* pb[2] = {pX, pAg0};
    u16* ob[2] = {oX, oAg};
    u16* lb[2] = {lX, lAg};
    int bP = (NP + 3) / 4, bO = (NO + 3) / 4, bL = (NL + 3) / 4;
    int cu = 0;
    int4 relsP = {0, 2, 4, 0}, relsO = {1, 1, 1, 0}, relsL = {3, 3, 3, 0};
    for (int t = 0; t < 3; t++) {
      u16 *pi = pb[cu], *po = pb[1 - cu];
      u16 *oi = ob[cu], *oo = ob[1 - cu];
      u16 *li = lb[cu], *lo = lb[1 - cu];
      sage_node<<<bP, 256, 0, stream>>>(pi, po, NP, 1.f / 3.f, Wl, bl, Wr, t, 3, relsP,
          pi, off + o0, csr0, NP,
          oi, off + o2, csr2, NO,
          li, off + o4, csr4, NL);
      sage_node<<<bO, 256, 0, stream>>>(oi, oo, NO, 1.f, Wl, bl, Wr, t, 1, relsO,
          pi, off + o1, csr1, NP,
          (const u16*)0, (const int*)0, (const int*)0, 0,
          (const u16*)0, (const int*)0, (const int*)0, 0);
      sage_node<<<bL, 256, 0, stream>>>(li, lo, NL, 1.f, Wl, bl, Wr, t, 1, relsL,
          pi, off + o3, csr3, NP,
          (const u16*)0, (const int*)0, (const int*)0, 0,
          (const u16*)0, (const int*)0, (const int*)0, 0);
      cu = 1 - cu;
    }
    pF = pb[cu]; oF = ob[cu]; lF = lb[cu];
  }

  // ---- readout (FP32 output) ----
  colsum2<<<512, 256, 0, stream>>>(pF, NP, gsum);
  colsum2<<<512, 256, 0, stream>>>(oF, NO, gsum + 64);
  colsum2<<<256, 256, 0, stream>>>(lF, NL, gsum + 128);
  head2<<<1, 256, 0, stream>>>(gsum, Wc1, bc1, Wc2, bc2, NP, NO, NL, out);
  suspect2<<<(NP + 255) / 256, 256, 0, stream>>>(pF, Ws1, bs1, Ws2, bs2, out + 20, NP);
}

// Round 4
// 1687.297 us; speedup vs baseline: 1.3105x; 1.0723x over previous
//
#include <hip/hip_runtime.h>

typedef unsigned short u16;
typedef unsigned int u32;
typedef __attribute__((ext_vector_type(8))) short bf16x8;
typedef __attribute__((ext_vector_type(4))) float f32x4;

#define BKW 2048           // bucket width (nodes); BKSH = log2(BKW)
#define BKSH 11
#define MAXBK 512          // max total buckets (bench: 368)

__device__ __forceinline__ float bf2f(u16 u) { return __uint_as_float(((u32)u) << 16); }
__device__ __forceinline__ u16 f2bf(float f) {
  u32 u = __float_as_uint(f);
  return (u16)((u + 0x7fffu + ((u >> 16) & 1u)) >> 16);
}

// ---------------------------------------------------------------------------
// Embedding gather: fp32 emb row -> internal bf16 feature row. 1 thread/elem.
__global__ void gather_f2b(const float* __restrict__ emb, const int* __restrict__ ids,
                           u16* __restrict__ out, int n, int V) {
  int u = blockIdx.x * 256 + threadIdx.x;
  if (u >= n * 64) return;
  int node = u >> 6, k = u & 63;
  int r = ids[node];
  r = ((u32)r < (u32)V) ? r : 0;
  out[u] = f2bf(emb[(size_t)r * 64 + k]);
}

// ---------------------------------------------------------------------------
// Weight prep (once per launch): bf16 lin weights, bf16 root-sum weights,
// fp32 bias-sums.
__global__ void prep_w(const float* __restrict__ Wl, const float* __restrict__ Wr,
                       const float* __restrict__ bl,
                       u16* __restrict__ WBlin, u16* __restrict__ WBroot,
                       float* __restrict__ bsums) {
  int i = blockIdx.x * 256 + threadIdx.x;
  const int TL = 3 * 5 * 4096;
  if (i < TL) { WBlin[i] = f2bf(Wl[i]); return; }
  int j = i - TL;
  if (j < 3 * 3 * 4096) {
    int lt = j / (3 * 4096), rem = j % (3 * 4096), c = rem / 4096, e = rem % 4096;
    int r0 = (c == 0) ? 0 : (c == 1) ? 1 : 3;
    float v = Wr[((size_t)lt * 5 + r0) * 4096 + e];
    if (c == 0) v += Wr[((size_t)lt * 5 + 2) * 4096 + e] +
                     Wr[((size_t)lt * 5 + 4) * 4096 + e];
    WBroot[j] = f2bf(v);
    return;
  }
  int k2 = j - 3 * 3 * 4096;
  if (k2 < 3 * 3 * 64) {
    int lt = k2 / 192, rem = k2 % 192, c = rem / 64, e = rem % 64;
    int r0 = (c == 0) ? 0 : (c == 1) ? 1 : 3;
    float v = bl[((size_t)lt * 5 + r0) * 64 + e];
    if (c == 0) v += bl[((size_t)lt * 5 + 2) * 64 + e] +
                     bl[((size_t)lt * 5 + 4) * 64 + e];
    bsums[k2] = v;
  }
}

// ---------------------------------------------------------------------------
// CSR build, bucket-sort formulation (dense writes, no 17x write-amp):
//   bkt_count  : per-bucket edge counts (LDS-aggregated histogram)
//   bkt_scan   : exclusive scan of bucket counts -> bases/cursors + sentinels
//   bkt_scatter: append packed records (src<<11 | local_dst) to bucket frontiers
//   bkt_sort   : per-bucket LDS counting sort -> off[] + csr[]
// ---------------------------------------------------------------------------
__global__ void __launch_bounds__(256) bkt_count(
    const int* __restrict__ D0, const int* __restrict__ D1, const int* __restrict__ D2,
    const int* __restrict__ D3, const int* __restrict__ D4,
    int* __restrict__ bcnt,
    int E1, int E2, int E3, int E4, int E5,
    int s1, int s2, int s3, int s4,
    int N0, int N1, int N2, int N3, int N4, int NBK) {
  __shared__ int c[MAXBK];
  int t = threadIdx.x;
  for (int i = t; i < NBK; i += 256) c[i] = 0;
  __syncthreads();
  int chunk0 = blockIdx.x * 8192;
  for (int j = 0; j < 32; j++) {
    int e = chunk0 + j * 256 + t;
    if (e >= E5) break;
    const int* dp; int sb, N, le;
    if (e < E1)      { dp = D0; sb = 0;  N = N0; le = e; }
    else if (e < E2) { dp = D1; sb = s1; N = N1; le = e - E1; }
    else if (e < E3) { dp = D2; sb = s2; N = N2; le = e - E2; }
    else if (e < E4) { dp = D3; sb = s3; N = N3; le = e - E3; }
    else             { dp = D4; sb = s4; N = N4; le = e - E4; }
    int d = dp[le];
    if ((u32)d < (u32)N) atomicAdd(&c[sb + (d >> BKSH)], 1);
  }
  __syncthreads();
  for (int i = t; i < NBK; i += 256) if (c[i]) atomicAdd(&bcnt[i], c[i]);
}

__global__ void __launch_bounds__(512) bkt_scan(
    const int* __restrict__ bcnt, int* __restrict__ bbase, int* __restrict__ bcur,
    int* __restrict__ off,
    int s1, int s2, int s3, int s4, int NBK,
    int q0, int q1, int q2, int q3, int q4) {   // absolute off-sentinel indices
  __shared__ int sb[MAXBK + 1];
  __shared__ int ws[8];
  int t = threadIdx.x, lane = t & 63, wv = t >> 6;
  int v = (t < NBK) ? bcnt[t] : 0;
  int s = v;
  #pragma unroll
  for (int d = 1; d < 64; d <<= 1) { int u = __shfl_up(s, d); if (lane >= d) s += u; }
  if (lane == 63) ws[wv] = s;
  __syncthreads();
  int wbase = 0;
  for (int i = 0; i < wv; i++) wbase += ws[i];
  int excl = wbase + (s - v);
  if (t < NBK) { bbase[t] = excl; bcur[t] = excl; sb[t] = excl; }
  if (t == 0) {
    int tot = 0;
    #pragma unroll
    for (int i = 0; i < 8; i++) tot += ws[i];
    bbase[NBK] = tot; sb[NBK] = tot;
  }
  __syncthreads();
  if (t == 0) off[q0] = sb[s1];
  else if (t == 1) off[q1] = sb[s2] - sb[s1];
  else if (t == 2) off[q2] = sb[s3] - sb[s2];
  else if (t == 3) off[q3] = sb[s4] - sb[s3];
  else if (t == 4) off[q4] = sb[NBK] - sb[s4];
}

__global__ void __launch_bounds__(256) bkt_scatter(
    const int* __restrict__ S0, const int* __restrict__ S1, const int* __restrict__ S2,
    const int* __restrict__ S3, const int* __restrict__ S4,
    const int* __restrict__ D0, const int* __restrict__ D1, const int* __restrict__ D2,
    const int* __restrict__ D3, const int* __restrict__ D4,
    int* __restrict__ bcur, u32* __restrict__ bdata,
    int E1, int E2, int E3, int E4, int E5,
    int s1, int s2, int s3, int s4,
    int N0, int N1, int N2, int N3, int N4, int NBK) {
  __shared__ int c[MAXBK];
  __shared__ int base[MAXBK];
  int t = threadIdx.x;
  for (int i = t; i < NBK; i += 256) c[i] = 0;
  __syncthreads();
  int chunk0 = blockIdx.x * 4096;
  int lb[16]; u32 rec[16];
  #pragma unroll
  for (int j = 0; j < 16; j++) {
    int e = chunk0 + j * 256 + t;
    lb[j] = -1;
    if (e < E5) {
      const int *sp, *dp; int sb, N, le;
      if (e < E1)      { sp = S0; dp = D0; sb = 0;  N = N0; le = e; }
      else if (e < E2) { sp = S1; dp = D1; sb = s1; N = N1; le = e - E1; }
      else if (e < E3) { sp = S2; dp = D2; sb = s2; N = N2; le = e - E2; }
      else if (e < E4) { sp = S3; dp = D3; sb = s3; N = N3; le = e - E3; }
      else             { sp = S4; dp = D4; sb = s4; N = N4; le = e - E4; }
      int d = dp[le];
      if ((u32)d < (u32)N) {
        lb[j] = sb + (d >> BKSH);
        rec[j] = ((u32)sp[le] << BKSH) | (u32)(d & (BKW - 1));
        atomicAdd(&c[lb[j]], 1);
      }
    }
  }
  __syncthreads();
  for (int i = t; i < NBK; i += 256) {
    int cc = c[i];
    base[i] = cc ? atomicAdd(&bcur[i], cc) : 0;
    c[i] = 0;
  }
  __syncthreads();
  #pragma unroll
  for (int j = 0; j < 16; j++) {
    if (lb[j] >= 0) {
      int r = atomicAdd(&c[lb[j]], 1);
      int pos = base[lb[j]] + r;
      if ((u32)pos < (u32)E5) bdata[pos] = rec[j];   // dense bucket frontier write
    }
  }
}

__global__ void __launch_bounds__(256) bkt_sort(
    const int* __restrict__ bbase, const u32* __restrict__ bdata,
    int* __restrict__ off, int* __restrict__ csr,
    int s1, int s2, int s3, int s4, int NBK,
    int N0, int N1, int N2, int N3, int N4,
    int o1, int o2, int o3, int o4,
    int g1, int g2, int g3, int g4,
    int La, int Lu, int Lt) {
  __shared__ int cnt[BKW];
  __shared__ int pre[BKW];
  __shared__ int wsum[4];
  int b = blockIdx.x, t = threadIdx.x, lane = t & 63, wv = t >> 6;
  int r = (b >= s4) ? 4 : (b >= s3) ? 3 : (b >= s2) ? 2 : (b >= s1) ? 1 : 0;
  int sr = (r == 0) ? 0 : (r == 1) ? s1 : (r == 2) ? s2 : (r == 3) ? s3 : s4;
  int Nr = (r == 0) ? N0 : (r == 1) ? N1 : (r == 2) ? N2 : (r == 3) ? N3 : N4;
  int oR = (r == 0) ? 0 : (r == 1) ? o1 : (r == 2) ? o2 : (r == 3) ? o3 : o4;
  int gR = (r == 0) ? 0 : (r == 1) ? g1 : (r == 2) ? g2 : (r == 3) ? g3 : g4;
  int Lr = (r == 0) ? La : (r == 1 || r == 2) ? Lu : Lt;
  int relRecBase = bbase[sr];
  int bstart = bbase[b], bend = bbase[b + 1];
  int node0 = (b - sr) << BKSH;
  int W = Nr - node0; if (W > BKW) W = BKW;
  int csrB = bstart - relRecBase;              // base within relation csr segment
  for (int i = t; i < BKW; i += 256) cnt[i] = 0;
  __syncthreads();
  for (int i = bstart + t; i < bend; i += 256)
    atomicAdd(&cnt[bdata[i] & (BKW - 1)], 1);
  __syncthreads();
  // block exclusive scan over 2048 counts (8/thread)
  int basei = t * 8;
  int v[8]; int tsum = 0;
  #pragma unroll
  for (int j = 0; j < 8; j++) { v[j] = cnt[basei + j]; tsum += v[j]; }
  int s = tsum;
  #pragma unroll
  for (int d = 1; d < 64; d <<= 1) { int u = __shfl_up(s, d); if (lane >= d) s += u; }
  if (lane == 63) wsum[wv] = s;
  __syncthreads();
  int wbase = 0;
  #pragma unroll
  for (int i = 0; i < 4; i++) wbase += (i < wv) ? wsum[i] : 0;
  int run = wbase + (s - tsum);
  #pragma unroll
  for (int j = 0; j < 8; j++) {
    pre[basei + j] = run;
    if (basei + j < W) off[oR + node0 + basei + j] = csrB + run;
    run += v[j];
  }
  #pragma unroll
  for (int j = 0; j < 8; j++) cnt[basei + j] = 0;   // reuse as rank cursor
  __syncthreads();
  for (int i = bstart + t; i < bend; i += 256) {
    u32 rc = bdata[i];
    int ld = rc & (BKW - 1);
    int src = (int)(rc >> BKSH);
    int rank = atomicAdd(&cnt[ld], 1);
    int pos = csrB + pre[ld] + rank;
    if ((u32)pos < (u32)Lr) csr[gR + pos] = src;    // L2-resident bucket region
  }
}

// ---------------------------------------------------------------------------
// OLD PATH (fallback if workspace too small): wave-per-node fused SAGE.
__device__ __forceinline__ float gmean(const u16* __restrict__ src, const int* __restrict__ off,
                                       const int* __restrict__ idx, u32 ns, int g, int lane) {
  int e0 = off[g], e1 = off[g + 1];
  float a0 = 0.f, a1 = 0.f, a2 = 0.f, a3 = 0.f;
  int e = e0;
  for (; e + 4 <= e1; e += 4) {
    int A = idx[e], B = idx[e + 1], C = idx[e + 2], D = idx[e + 3];
    A = ((u32)A < ns) ? A : 0;
    B = ((u32)B < ns) ? B : 0;
    C = ((u32)C < ns) ? C : 0;
    D = ((u32)D < ns) ? D : 0;
    a0 += bf2f(src[(size_t)A * 64 + lane]);
    a1 += bf2f(src[(size_t)B * 64 + lane]);
    a2 += bf2f(src[(size_t)C * 64 + lane]);
    a3 += bf2f(src[(size_t)D * 64 + lane]);
  }
  for (; e < e1; e++) {
    int A = idx[e];
    A = ((u32)A < ns) ? A : 0;
    a0 += bf2f(src[(size_t)A * 64 + lane]);
  }
  float s = (a0 + a1) + (a2 + a3);
  int d = e1 - e0;
  return (d > 0) ? s * (1.f / (float)d) : 0.f;
}

__device__ __forceinline__ void stageW(float* __restrict__ Wsh, const float* __restrict__ Wb,
                                       int t) {
  #pragma unroll
  for (int j = 0; j < 4; j++) {
    int i4 = t + j * 256;
    float4 v = ((const float4*)Wb)[i4];
    int o = (i4 * 4) >> 6, k = (i4 * 4) & 63;
    float* dst = &Wsh[o * 65 + k];
    dst[0] = v.x; dst[1] = v.y; dst[2] = v.z; dst[3] = v.w;
  }
}

__global__ void __launch_bounds__(256) sage_node(
    const u16* __restrict__ xin, u16* __restrict__ xout, int n_dst, float scale,
    const float* __restrict__ Wl, const float* __restrict__ bl, const float* __restrict__ Wr,
    int lt, int nAgg, int4 rels,
    const u16* s0, const int* of0, const int* ix0, int ns0,
    const u16* s1, const int* of1, const int* ix1, int ns1,
    const u16* s2, const int* of2, const int* ix2, int ns2) {
  __shared__ float Wsh[64 * 65];
  int t = threadIdx.x, wave = t >> 6, lane = t & 63;
  int g = blockIdx.x * 4 + wave;
  bool act = g < n_dst;

  float m0 = act ? gmean(s0, of0, ix0, (u32)ns0, g, lane) : 0.f;
  float m1 = (act && nAgg > 1) ? gmean(s1, of1, ix1, (u32)ns1, g, lane) : 0.f;
  float m2 = (act && nAgg > 2) ? gmean(s2, of2, ix2, (u32)ns2, g, lane) : 0.f;
  float xv = act ? bf2f(xin[(size_t)g * 64 + lane]) : 0.f;

  float acc = 0.f;
  for (int p = 0; p < nAgg; p++) {
    int r = (p == 0) ? rels.x : (p == 1) ? rels.y : rels.z;
    const float* Wb = Wl + ((size_t)lt * 5 + r) * 4096;
    __syncthreads();
    stageW(Wsh, Wb, t);
    __syncthreads();
    float mv = (p == 0) ? m0 : (p == 1) ? m1 : m2;
    #pragma unroll
    for (int k = 0; k < 64; k++)
      acc += __shfl(mv, k) * Wsh[lane * 65 + k];
  }
  {
    const float* w0 = Wr + ((size_t)lt * 5 + rels.x) * 4096;
    const float* w1 = Wr + ((size_t)lt * 5 + rels.y) * 4096;
    const float* w2 = Wr + ((size_t)lt * 5 + rels.z) * 4096;
    __syncthreads();
    #pragma unroll
    for (int j = 0; j < 4; j++) {
      int i4 = t + j * 256;
      float4 v = ((const float4*)w0)[i4];
      if (nAgg > 1) {
        float4 b = ((const float4*)w1)[i4];
        float4 c = ((const float4*)w2)[i4];
        v.x += b.x + c.x; v.y += b.y + c.y; v.z += b.z + c.z; v.w += b.w + c.w;
      }
      int o = (i4 * 4) >> 6, k = (i4 * 4) & 63;
      float* dst = &Wsh[o * 65 + k];
      dst[0] = v.x; dst[1] = v.y; dst[2] = v.z; dst[3] = v.w;
    }
    __syncthreads();
    #pragma unroll
    for (int k = 0; k < 64; k++)
      acc += __shfl(xv, k) * Wsh[lane * 65 + k];
  }

  float bsum = bl[((size_t)lt * 5 + rels.x) * 64 + lane];
  if (nAgg > 1) bsum += bl[((size_t)lt * 5 + rels.y) * 64 + lane] +
                        bl[((size_t)lt * 5 + rels.z) * 64 + lane];

  if (act) {
    float v = fmaxf((acc + bsum) * scale, 0.f) + xv;
    xout[(size_t)g * 64 + lane] = f2bf(v);
  }
}

// ---------------------------------------------------------------------------
// Barrier-free mean-gather, one wave per dst node, ILP-8 predicated.
__global__ void __launch_bounds__(256, 8) agg_mean(
    const u16* __restrict__ src, const int* __restrict__ off, const int* __restrict__ idx,
    u16* __restrict__ out, int n_dst, int ns) {
  int t = threadIdx.x;
  int g = blockIdx.x * 4 + (t >> 6);
  int lane = t & 63;
  if (g >= n_dst) return;
  int e0 = off[g], e1 = off[g + 1];
  int d = e1 - e0;
  float a[8] = {0.f, 0.f, 0.f, 0.f, 0.f, 0.f, 0.f, 0.f};
  int eL = e1 - 1;
  for (int base = e0; base < e1; base += 8) {
    int id[8];
    #pragma unroll
    for (int j = 0; j < 8; j++) {
      int e = base + j;
      int i = idx[e <= eL ? e : eL];       // clamped: always a valid address
      id[j] = ((u32)i < (u32)ns) ? i : 0;
    }
    float v[8];
    #pragma unroll
    for (int j = 0; j < 8; j++)            // 8 independent row loads in flight
      v[j] = bf2f(src[(size_t)id[j] * 64 + lane]);
    #pragma unroll
    for (int j = 0; j < 8; j++)
      a[j] += (base + j < e1) ? v[j] : 0.f;
  }
  float s = ((a[0] + a[1]) + (a[2] + a[3])) + ((a[4] + a[5]) + (a[6] + a[7]));
  float mean = (d > 0) ? s / (float)d : 0.f;
  out[(size_t)g * 64 + lane] = f2bf(mean);
}

// ---------------------------------------------------------------------------
// MFMA GEMM. C = [A0|A1|..|X] @ Wstack^T, fused epilogue relu((C+b)*s)+x,
// bf16 IN-PLACE output. Weights pre-converted bf16 (prep_w); B fragments
// reloaded from the L1-hot 32KB weight set inside the kc-loop (no spill).
// Epilogue staged through per-wave LDS [16][65] for coalesced 16B/lane stores.
template <int NM>
__global__ void __launch_bounds__(256, 4) gemm_sage(
    const u16* __restrict__ A0, const u16* __restrict__ A1, const u16* __restrict__ A2,
    const u16* X, u16* out,  // no __restrict__: out aliases X (in-place)
    const u16* __restrict__ lin0, const u16* __restrict__ lin1, const u16* __restrict__ lin2,
    const u16* __restrict__ root, const float* __restrict__ bsum,
    float scale, int n) {
  constexpr int KC = 2 * (NM + 1);          // K-chunks of 32
  __shared__ float ldsAcc[4][16 * 65];
  int t = threadIdx.x, wave = t >> 6, lane = t & 63;
  int col0 = lane & 15, kb = lane >> 4;
  float* lw = ldsAcc[wave];

  const u16* Wbase[KC];
  #pragma unroll
  for (int kc = 0; kc < KC; kc++) {
    int m = kc >> 1;
    const u16* basep = (m < NM) ? ((m == 0) ? lin0 : (m == 1) ? lin1 : lin2) : root;
    Wbase[kc] = basep + (kc & 1) * 32 + kb * 8;
  }

  int ccl = (lane & 7) * 8;
  float4 blo = *(const float4*)(bsum + ccl);
  float4 bhi = *(const float4*)(bsum + ccl + 4);
  float bsum8[8] = {blo.x, blo.y, blo.z, blo.w, bhi.x, bhi.y, bhi.z, bhi.w};

  int ntiles = (n + 15) >> 4;
  for (int tile = blockIdx.x * 4 + wave; tile < ntiles; tile += gridDim.x * 4) {
    int m0 = tile << 4;
    int rowA = m0 + col0;
    rowA = (rowA < n) ? rowA : (n - 1);
    bf16x8 Af[KC];
    #pragma unroll
    for (int kc = 0; kc < KC; kc++) {
      int m = kc >> 1;
      const u16* s = (m < NM) ? ((m == 0) ? A0 : (m == 1) ? A1 : A2) : X;
      int kk = (kc & 1) * 32 + kb * 8;
      Af[kc] = *(const bf16x8*)(s + (size_t)rowA * 64 + kk);  // 16B, aligned
    }
    f32x4 acc[4] = {};
    #pragma unroll
    for (int kc = 0; kc < KC; kc++) {
      #pragma unroll
      for (int nt = 0; nt < 4; nt++) {
        bf16x8 B = *(const bf16x8*)(Wbase[kc] + (nt * 16 + col0) * 64);  // L1 hot
        acc[nt] = __builtin_amdgcn_mfma_f32_16x16x32_bf16(Af[kc], B, acc[nt], 0, 0, 0);
      }
    }
    #pragma unroll
    for (int nt = 0; nt < 4; nt++)
      #pragma unroll
      for (int j = 0; j < 4; j++)
        lw[(kb * 4 + j) * 65 + nt * 16 + col0] = acc[nt][j];
    #pragma unroll
    for (int it = 0; it < 2; it++) {
      int r16 = it * 8 + (lane >> 3);
      int row = m0 + r16;
      float vv[8];
      #pragma unroll
      for (int j = 0; j < 8; j++) vv[j] = lw[r16 * 65 + ccl + j];
      if (row < n) {
        bf16x8 xv8 = *(const bf16x8*)(X + (size_t)row * 64 + ccl);
        bf16x8 o8;
        #pragma unroll
        for (int j = 0; j < 8; j++) {
          float xvf = bf2f((u16)xv8[j]);
          float v = fmaxf((vv[j] + bsum8[j]) * scale, 0.f) + xvf;
          o8[j] = (short)f2bf(v);
        }
        *(bf16x8*)(out + (size_t)row * 64 + ccl) = o8;   // 16B coalesced store
      }
    }
  }
}

// ---------------------------------------------------------------------------
// Column sums over bf16 features (graph-mean readout)
__global__ void colsum2(const u16* __restrict__ x, int n, float* __restrict__ gout) {
  __shared__ float part[64];
  int t = threadIdx.x;
  if (t < 64) part[t] = 0.f;
  __syncthreads();
  int col = t & 63, w = blockIdx.x * 4 + (t >> 6), tw = gridDim.x * 4;
  float s = 0.f;
  for (int r = w; r < n; r += tw) s += bf2f(x[(size_t)r * 64 + col]);
  atomicAdd(&part[col], s);
  __syncthreads();
  if (t < 64) atomicAdd(&gout[t], part[t]);
}

// Crime head: out[0:20) as FP32
__global__ void __launch_bounds__(256) head2(const float* __restrict__ gsum,
    const float* __restrict__ Wc1, const float* __restrict__ bc1,
    const float* __restrict__ Wc2, const float* __restrict__ bc2,
    int NP, int NO, int NL, float* __restrict__ out) {
  __shared__ float g[192];
  __shared__ float h[64];
  int t = threadIdx.x;
  if (t < 192) {
    float d = (t < 64) ? (float)NP : (t < 128) ? (float)NO : (float)NL;
    g[t] = gsum[t] / d;
  }
  __syncthreads();
  if (t < 64) {
    float a = bc1[t];
    for (int k = 0; k < 192; k++) a += g[k] * Wc1[(size_t)t * 192 + k];
    h[t] = fmaxf(a, 0.f);
  }
  __syncthreads();
  if (t < 20) {
    float a = bc2[t];
    for (int k = 0; k < 64; k++) a += h[k] * Wc2[(size_t)t * 64 + k];
    out[t] = a;
  }
}

// Suspect head: out[i] as FP32 (out passed pre-offset by +20)
__global__ void __launch_bounds__(256) suspect2(const u16* __restrict__ p,
    const float* __restrict__ Ws1, const float* __restrict__ bs1,
    const float* __restrict__ Ws2, const float* __restrict__ bs2,
    float* __restrict__ out, int NP) {
  __shared__ float W1[2048];
  __shared__ float b1[32], w2[32];
  __shared__ float b2s;
  int t = threadIdx.x;
  #pragma unroll
  for (int i = 0; i < 8; i++) {
    int d = t + i * 256;
    W1[d] = Ws1[d];
  }
  if (t < 32) { b1[t] = bs1[t]; w2[t] = Ws2[t]; }
  if (t == 0) b2s = bs2[0];
  __syncthreads();
  int i = blockIdx.x * 256 + t;
  if (i >= NP) return;
  float x[64];
  #pragma unroll
  for (int k = 0; k < 64; k++) x[k] = bf2f(p[(size_t)i * 64 + k]);
  float sc = b2s;
  for (int j = 0; j < 32; j++) {
    float a = b1[j];
    const float* wr = &W1[j * 64];
    #pragma unroll
    for (int k = 0; k < 64; k++) a += x[k] * wr[k];
    sc += fmaxf(a, 0.f) * w2[j];
  }
  out[i] = sc;
}

// ---------------------------------------------------------------------------
extern "C" void kernel_launch(void* const* d_in, const int* in_sizes, int n_in,
                              void* d_out, int out_size, void* d_ws, size_t ws_size,
                              hipStream_t stream) {
  const int NP = in_sizes[0], NO = in_sizes[1], NL = in_sizes[2];
  const int Ea = in_sizes[3], Eu = in_sizes[5], Et = in_sizes[7];
  const int VP = in_sizes[9] / 64, VO = in_sizes[10] / 64, VL = in_sizes[11] / 64;

  const int* x_person   = (const int*)d_in[0];
  const int* x_object   = (const int*)d_in[1];
  const int* x_location = (const int*)d_in[2];
  const int* acts_src = (const int*)d_in[3];
  const int* acts_dst = (const int*)d_in[4];
  const int* uses_src = (const int*)d_in[5];
  const int* uses_dst = (const int*)d_in[6];
  const int* at_src   = (const int*)d_in[7];
  const int* at_dst   = (const int*)d_in[8];
  const float* person_emb   = (const float*)d_in[9];
  const float* object_emb   = (const float*)d_in[10];
  const float* location_emb = (const float*)d_in[11];
  const float* Wl  = (const float*)d_in[12];
  const float* bl  = (const float*)d_in[13];
  const float* Wr  = (const float*)d_in[14];
  const float* Wc1 = (const float*)d_in[15];
  const float* bc1 = (const float*)d_in[16];
  const float* Wc2 = (const float*)d_in[17];
  const float* bc2 = (const float*)d_in[18];
  const float* Ws1 = (const float*)d_in[19];
  const float* bs1 = (const float*)d_in[20];
  const float* Ws2 = (const float*)d_in[21];
  const float* bs2 = (const float*)d_in[22];
  float* out = (float*)d_out;

  // ---- bucket geometry (MAXBK guard: bench is 368) ----
  int B0 = (NP + BKW - 1) >> BKSH;
  int B1 = (NO + BKW - 1) >> BKSH;
  int B3 = (NL + BKW - 1) >> BKSH;
  int s1 = B0, s2 = s1 + B1, s3 = s2 + B0, s4 = s3 + B3, NBK = s4 + B0;
  if (NBK > MAXBK) return;   // out stays 0 -> visible failure signature

  // ---- workspace (16B aligned) ----
  char* w = (char*)d_ws;
  auto alloc = [&](size_t bytes) { char* r = w; w += (bytes + 15) & ~(size_t)15; return r; };
  u16* pX   = (u16*)alloc((size_t)NP * 128);
  u16* pAg0 = (u16*)alloc((size_t)NP * 128);   // old path: pB
  u16* oX   = (u16*)alloc((size_t)NO * 128);
  u16* oAg  = (u16*)alloc((size_t)NO * 128);   // old path: oB
  u16* lX   = (u16*)alloc((size_t)NL * 128);
  u16* lAg  = (u16*)alloc((size_t)NL * 128);   // old path: lB
  float* gsum = (float*)alloc(192 * 4);
  const size_t CN = (size_t)3 * NP + NO + NL;
  int* off = (int*)alloc((CN + 8) * 4);
  int* bcnt  = (int*)alloc((MAXBK) * 4);
  int* bbase = (int*)alloc((MAXBK + 1) * 4);
  int* bcur  = (int*)alloc((MAXBK) * 4);
  const int E1 = Ea, E2 = E1 + Eu, E3 = E2 + Eu, E4 = E3 + Et, E5 = E4 + Et;
  u32* bdata = (u32*)alloc((size_t)E5 * 4);
  u16* WBlin  = (u16*)alloc((size_t)3 * 5 * 4096 * 2);
  u16* WBroot = (u16*)alloc((size_t)3 * 3 * 4096 * 2);
  float* bsums = (float*)alloc((size_t)3 * 3 * 64 * 4);
  int* csr = (int*)alloc((size_t)E5 * 4);
  size_t base_need = (size_t)(w - (char*)d_ws);
  u16* pAg1 = (u16*)alloc((size_t)NP * 128);   // new-path extras
  u16* pAg2 = (u16*)alloc((size_t)NP * 128);
  size_t full_need = (size_t)(w - (char*)d_ws);
  (void)n_in; (void)out_size;
  // ws guard: if it fires, out stays 0 -> absmax == 0.118652 exactly (signature)
  if (base_need > ws_size) return;
  bool fits = (full_need <= ws_size);

  int o0 = 0, o1 = NP + 1, o2 = o1 + NO + 1, o3 = o2 + NP + 1, o4 = o3 + NL + 1;
  int g1 = Ea, g2 = Ea + Eu, g3 = Ea + 2 * Eu, g4 = Ea + 2 * Eu + Et;
  int* csr0 = csr;
  int* csr1 = csr + g1;
  int* csr2 = csr + g2;
  int* csr3 = csr + g3;
  int* csr4 = csr + g4;

  hipMemsetAsync(bcnt, 0, MAXBK * sizeof(int), stream);
  hipMemsetAsync(gsum, 0, 192 * sizeof(float), stream);

  prep_w<<<387, 256, 0, stream>>>(Wl, Wr, bl, WBlin, WBroot, bsums);

  gather_f2b<<<(NP * 64 + 255) / 256, 256, 0, stream>>>(person_emb, x_person, pX, NP, VP);
  gather_f2b<<<(NO * 64 + 255) / 256, 256, 0, stream>>>(object_emb, x_object, oX, NO, VO);
  gather_f2b<<<(NL * 64 + 255) / 256, 256, 0, stream>>>(location_emb, x_location, lX, NL, VL);

  // ---- CSR build: bucket-sort (dense writes) ----
  bkt_count<<<(E5 + 8191) / 8192, 256, 0, stream>>>(
      acts_dst, uses_dst, uses_src, at_dst, at_src, bcnt,
      E1, E2, E3, E4, E5, s1, s2, s3, s4, NP, NO, NP, NL, NP, NBK);
  bkt_scan<<<1, 512, 0, stream>>>(bcnt, bbase, bcur, off,
      s1, s2, s3, s4, NBK,
      o0 + NP, o1 + NO, o2 + NP, o3 + NL, o4 + NP);
  bkt_scatter<<<(E5 + 4095) / 4096, 256, 0, stream>>>(
      acts_src, uses_src, uses_dst, at_src, at_dst,
      acts_dst, uses_dst, uses_src, at_dst, at_src,
      bcur, bdata, E1, E2, E3, E4, E5, s1, s2, s3, s4, NP, NO, NP, NL, NP, NBK);
  bkt_sort<<<NBK, 256, 0, stream>>>(bbase, bdata, off, csr,
      s1, s2, s3, s4, NBK, NP, NO, NP, NL, NP,
      o1, o2, o3, o4, g1, g2, g3, g4, Ea, Eu, Et);

  const u16 *pF, *oF, *lF;
  if (fits) {
    // ---- decoupled aggregation + MFMA GEMM, in-place features ----
    int tP = (NP + 15) >> 4, tO = (NO + 15) >> 4, tL = (NL + 15) >> 4;
    int gP = (tP + 3) / 4; if (gP > 1024) gP = 1024;
    int gO = (tO + 3) / 4; if (gO > 512)  gO = 512;
    int gL = (tL + 3) / 4; if (gL > 256)  gL = 256;
    for (int t = 0; t < 3; t++) {
      agg_mean<<<(NP + 3) / 4, 256, 0, stream>>>(pX, off + o0, csr0, pAg0, NP, NP);
      agg_mean<<<(NP + 3) / 4, 256, 0, stream>>>(oX, off + o2, csr2, pAg1, NP, NO);
      agg_mean<<<(NP + 3) / 4, 256, 0, stream>>>(lX, off + o4, csr4, pAg2, NP, NL);
      agg_mean<<<(NO + 3) / 4, 256, 0, stream>>>(pX, off + o1, csr1, oAg, NO, NP);
      agg_mean<<<(NL + 3) / 4, 256, 0, stream>>>(pX, off + o3, csr3, lAg, NL, NP);
      gemm_sage<3><<<gP, 256, 0, stream>>>(pAg0, pAg1, pAg2, pX, pX,
          WBlin + ((size_t)t * 5 + 0) * 4096,
          WBlin + ((size_t)t * 5 + 2) * 4096,
          WBlin + ((size_t)t * 5 + 4) * 4096,
          WBroot + ((size_t)t * 3 + 0) * 4096,
          bsums + ((size_t)t * 3 + 0) * 64, 1.f / 3.f, NP);
      gemm_sage<1><<<gO, 256, 0, stream>>>(oAg, (const u16*)0, (const u16*)0, oX, oX,
          WBlin + ((size_t)t * 5 + 1) * 4096, (const u16*)0, (const u16*)0,
          WBroot + ((size_t)t * 3 + 1) * 4096,
          bsums + ((size_t)t * 3 + 1) * 64, 1.f, NO);
      gemm_sage<1><<<gL, 256, 0, stream>>>(lAg, (const u16*)0, (const u16*)0, lX, lX,
          WBlin + ((size_t)t * 5 + 3) * 4096, (const u16*)0, (const u16*)0,
          WBroot + ((size_t)t * 3 + 2) * 4096,
          bsums + ((size_t)t * 3 + 2) * 64, 1.f, NL);
    }
    pF = pX; oF = oX; lF = lX;
  } else {
    // ---- OLD PATH (fallback): fused wave-per-node SAGE with ping-pong ----
    u16* pb[2] = {pX, pAg0};
    u16* ob[2] = {oX, oAg};
    u16* lb[2] = {lX, lAg};
    int bP = (NP + 3) / 4, bO = (NO + 3) / 4, bL = (NL + 3) / 4;
    int cu = 0;
    int4 relsP = {0, 2, 4, 0}, relsO = {1, 1, 1, 0}, relsL = {3, 3, 3, 0};
    for (int t = 0; t < 3; t++) {
      u16 *pi = pb[cu], *po = pb[1 - cu];
      u16 *oi = ob[cu], *oo = ob[1 - cu];
      u16 *li = lb[cu], *lo = lb[1 - cu];
      sage_node<<<bP, 256, 0, stream>>>(pi, po, NP, 1.f / 3.f, Wl, bl, Wr, t, 3, relsP,
          pi, off + o0, csr0, NP,
          oi, off + o2, csr2, NO,
          li, off + o4, csr4, NL);
      sage_node<<<bO, 256, 0, stream>>>(oi, oo, NO, 1.f, Wl, bl, Wr, t, 1, relsO,
          pi, off + o1, csr1, NP,
          (const u16*)0, (const int*)0, (const int*)0, 0,
          (const u16*)0, (const int*)0, (const int*)0, 0);
      sage_node<<<bL, 256, 0, stream>>>(li, lo, NL, 1.f, Wl, bl, Wr, t, 1, relsL,
          pi, off + o3, csr3, NP,
          (const u16*)0, (const int*)0, (const int*)0, 0,
          (const u16*)0, (const int*)0, (const int*)0, 0);
      cu = 1 - cu;
    }
    pF = pb[cu]; oF = ob[cu]; lF = lb[cu];
  }

  // ---- readout (FP32 output) ----
  colsum2<<<128, 256, 0, stream>>>(pF, NP, gsum);
  colsum2<<<64, 256, 0, stream>>>(oF, NO, gsum + 64);
  colsum2<<<32, 256, 0, stream>>>(lF, NL, gsum + 128);
  head2<<<1, 256, 0, stream>>>(gsum, Wc1, bc1, Wc2, bc2, NP, NO, NL, out);
  suspect2<<<(NP + 255) / 256, 256, 0, stream>>>(pF, Ws1, bs1, Ws2, bs2, out + 20, NP);
}

// Round 5
// 1496.579 us; speedup vs baseline: 1.4775x; 1.1274x over previous
//
#include <hip/hip_runtime.h>

typedef unsigned short u16;
typedef unsigned int u32;
typedef __attribute__((ext_vector_type(8))) short bf16x8;
typedef __attribute__((ext_vector_type(4))) float f32x4;

#define BKW 2048           // bucket width (nodes); BKSH = log2(BKW)
#define BKSH 11
#define MAXBK 512          // max total buckets (bench: 368)

__device__ __forceinline__ float bf2f(u16 u) { return __uint_as_float(((u32)u) << 16); }
__device__ __forceinline__ u16 f2bf(float f) {
  u32 u = __float_as_uint(f);
  return (u16)((u + 0x7fffu + ((u >> 16) & 1u)) >> 16);
}

// ---------------------------------------------------------------------------
// Embedding gather: fp32 emb row -> internal bf16 feature row. 1 thread/elem.
__global__ void gather_f2b(const float* __restrict__ emb, const int* __restrict__ ids,
                           u16* __restrict__ out, int n, int V) {
  int u = blockIdx.x * 256 + threadIdx.x;
  if (u >= n * 64) return;
  int node = u >> 6, k = u & 63;
  int r = ids[node];
  r = ((u32)r < (u32)V) ? r : 0;
  out[u] = f2bf(emb[(size_t)r * 64 + k]);
}

// ---------------------------------------------------------------------------
// Weight prep (once per launch): bf16 lin weights, bf16 root-sum weights,
// fp32 bias-sums.
__global__ void prep_w(const float* __restrict__ Wl, const float* __restrict__ Wr,
                       const float* __restrict__ bl,
                       u16* __restrict__ WBlin, u16* __restrict__ WBroot,
                       float* __restrict__ bsums) {
  int i = blockIdx.x * 256 + threadIdx.x;
  const int TL = 3 * 5 * 4096;
  if (i < TL) { WBlin[i] = f2bf(Wl[i]); return; }
  int j = i - TL;
  if (j < 3 * 3 * 4096) {
    int lt = j / (3 * 4096), rem = j % (3 * 4096), c = rem / 4096, e = rem % 4096;
    int r0 = (c == 0) ? 0 : (c == 1) ? 1 : 3;
    float v = Wr[((size_t)lt * 5 + r0) * 4096 + e];
    if (c == 0) v += Wr[((size_t)lt * 5 + 2) * 4096 + e] +
                     Wr[((size_t)lt * 5 + 4) * 4096 + e];
    WBroot[j] = f2bf(v);
    return;
  }
  int k2 = j - 3 * 3 * 4096;
  if (k2 < 3 * 3 * 64) {
    int lt = k2 / 192, rem = k2 % 192, c = rem / 64, e = rem % 64;
    int r0 = (c == 0) ? 0 : (c == 1) ? 1 : 3;
    float v = bl[((size_t)lt * 5 + r0) * 64 + e];
    if (c == 0) v += bl[((size_t)lt * 5 + 2) * 64 + e] +
                     bl[((size_t)lt * 5 + 4) * 64 + e];
    bsums[k2] = v;
  }
}

// ---------------------------------------------------------------------------
// CSR build, bucket-sort formulation (dense writes).
// ---------------------------------------------------------------------------
__global__ void __launch_bounds__(256) bkt_count(
    const int* __restrict__ D0, const int* __restrict__ D1, const int* __restrict__ D2,
    const int* __restrict__ D3, const int* __restrict__ D4,
    int* __restrict__ bcnt,
    int E1, int E2, int E3, int E4, int E5,
    int s1, int s2, int s3, int s4,
    int N0, int N1, int N2, int N3, int N4, int NBK) {
  __shared__ int c[MAXBK];
  int t = threadIdx.x;
  for (int i = t; i < NBK; i += 256) c[i] = 0;
  __syncthreads();
  int chunk0 = blockIdx.x * 8192;
  for (int j = 0; j < 32; j++) {
    int e = chunk0 + j * 256 + t;
    if (e >= E5) break;
    const int* dp; int sb, N, le;
    if (e < E1)      { dp = D0; sb = 0;  N = N0; le = e; }
    else if (e < E2) { dp = D1; sb = s1; N = N1; le = e - E1; }
    else if (e < E3) { dp = D2; sb = s2; N = N2; le = e - E2; }
    else if (e < E4) { dp = D3; sb = s3; N = N3; le = e - E3; }
    else             { dp = D4; sb = s4; N = N4; le = e - E4; }
    int d = dp[le];
    if ((u32)d < (u32)N) atomicAdd(&c[sb + (d >> BKSH)], 1);
  }
  __syncthreads();
  for (int i = t; i < NBK; i += 256) if (c[i]) atomicAdd(&bcnt[i], c[i]);
}

__global__ void __launch_bounds__(512) bkt_scan(
    const int* __restrict__ bcnt, int* __restrict__ bbase, int* __restrict__ bcur,
    int* __restrict__ off,
    int s1, int s2, int s3, int s4, int NBK,
    int q0, int q1, int q2, int q3, int q4) {   // absolute off-sentinel indices
  __shared__ int sb[MAXBK + 1];
  __shared__ int ws[8];
  int t = threadIdx.x, lane = t & 63, wv = t >> 6;
  int v = (t < NBK) ? bcnt[t] : 0;
  int s = v;
  #pragma unroll
  for (int d = 1; d < 64; d <<= 1) { int u = __shfl_up(s, d); if (lane >= d) s += u; }
  if (lane == 63) ws[wv] = s;
  __syncthreads();
  int wbase = 0;
  for (int i = 0; i < wv; i++) wbase += ws[i];
  int excl = wbase + (s - v);
  if (t < NBK) { bbase[t] = excl; bcur[t] = excl; sb[t] = excl; }
  if (t == 0) {
    int tot = 0;
    #pragma unroll
    for (int i = 0; i < 8; i++) tot += ws[i];
    bbase[NBK] = tot; sb[NBK] = tot;
  }
  __syncthreads();
  if (t == 0) off[q0] = sb[s1];
  else if (t == 1) off[q1] = sb[s2] - sb[s1];
  else if (t == 2) off[q2] = sb[s3] - sb[s2];
  else if (t == 3) off[q3] = sb[s4] - sb[s3];
  else if (t == 4) off[q4] = sb[NBK] - sb[s4];
}

__global__ void __launch_bounds__(256) bkt_scatter(
    const int* __restrict__ S0, const int* __restrict__ S1, const int* __restrict__ S2,
    const int* __restrict__ S3, const int* __restrict__ S4,
    const int* __restrict__ D0, const int* __restrict__ D1, const int* __restrict__ D2,
    const int* __restrict__ D3, const int* __restrict__ D4,
    int* __restrict__ bcur, u32* __restrict__ bdata,
    int E1, int E2, int E3, int E4, int E5,
    int s1, int s2, int s3, int s4,
    int N0, int N1, int N2, int N3, int N4, int NBK) {
  __shared__ int c[MAXBK];
  __shared__ int base[MAXBK];
  int t = threadIdx.x;
  for (int i = t; i < NBK; i += 256) c[i] = 0;
  __syncthreads();
  int chunk0 = blockIdx.x * 4096;
  int lb[16]; u32 rec[16];
  #pragma unroll
  for (int j = 0; j < 16; j++) {
    int e = chunk0 + j * 256 + t;
    lb[j] = -1;
    if (e < E5) {
      const int *sp, *dp; int sb, N, le;
      if (e < E1)      { sp = S0; dp = D0; sb = 0;  N = N0; le = e; }
      else if (e < E2) { sp = S1; dp = D1; sb = s1; N = N1; le = e - E1; }
      else if (e < E3) { sp = S2; dp = D2; sb = s2; N = N2; le = e - E2; }
      else if (e < E4) { sp = S3; dp = D3; sb = s3; N = N3; le = e - E3; }
      else             { sp = S4; dp = D4; sb = s4; N = N4; le = e - E4; }
      int d = dp[le];
      if ((u32)d < (u32)N) {
        lb[j] = sb + (d >> BKSH);
        rec[j] = ((u32)sp[le] << BKSH) | (u32)(d & (BKW - 1));
        atomicAdd(&c[lb[j]], 1);
      }
    }
  }
  __syncthreads();
  for (int i = t; i < NBK; i += 256) {
    int cc = c[i];
    base[i] = cc ? atomicAdd(&bcur[i], cc) : 0;
    c[i] = 0;
  }
  __syncthreads();
  #pragma unroll
  for (int j = 0; j < 16; j++) {
    if (lb[j] >= 0) {
      int r = atomicAdd(&c[lb[j]], 1);
      int pos = base[lb[j]] + r;
      if ((u32)pos < (u32)E5) bdata[pos] = rec[j];   // dense bucket frontier write
    }
  }
}

// 1024 threads/block: 368 blocks x 16 waves ~= 23 waves/CU (was 5.9% occupancy)
__global__ void __launch_bounds__(1024) bkt_sort(
    const int* __restrict__ bbase, const u32* __restrict__ bdata,
    int* __restrict__ off, int* __restrict__ csr,
    int s1, int s2, int s3, int s4, int NBK,
    int N0, int N1, int N2, int N3, int N4,
    int o1, int o2, int o3, int o4,
    int g1, int g2, int g3, int g4,
    int La, int Lu, int Lt) {
  __shared__ int cnt[BKW];
  __shared__ int pre[BKW];
  __shared__ int wsum[16];
  int b = blockIdx.x, t = threadIdx.x, lane = t & 63, wv = t >> 6;
  int r = (b >= s4) ? 4 : (b >= s3) ? 3 : (b >= s2) ? 2 : (b >= s1) ? 1 : 0;
  int sr = (r == 0) ? 0 : (r == 1) ? s1 : (r == 2) ? s2 : (r == 3) ? s3 : s4;
  int Nr = (r == 0) ? N0 : (r == 1) ? N1 : (r == 2) ? N2 : (r == 3) ? N3 : N4;
  int oR = (r == 0) ? 0 : (r == 1) ? o1 : (r == 2) ? o2 : (r == 3) ? o3 : o4;
  int gR = (r == 0) ? 0 : (r == 1) ? g1 : (r == 2) ? g2 : (r == 3) ? g3 : g4;
  int Lr = (r == 0) ? La : (r == 1 || r == 2) ? Lu : Lt;
  int relRecBase = bbase[sr];
  int bstart = bbase[b], bend = bbase[b + 1];
  int node0 = (b - sr) << BKSH;
  int W = Nr - node0; if (W > BKW) W = BKW;
  int csrB = bstart - relRecBase;              // base within relation csr segment
  for (int i = t; i < BKW; i += 1024) cnt[i] = 0;
  __syncthreads();
  for (int i = bstart + t; i < bend; i += 1024)
    atomicAdd(&cnt[bdata[i] & (BKW - 1)], 1);
  __syncthreads();
  // block exclusive scan over 2048 counts (2/thread)
  int basei = t * 2;
  int v0 = cnt[basei], v1 = cnt[basei + 1];
  int tsum = v0 + v1;
  int s = tsum;
  #pragma unroll
  for (int d = 1; d < 64; d <<= 1) { int u = __shfl_up(s, d); if (lane >= d) s += u; }
  if (lane == 63) wsum[wv] = s;
  __syncthreads();
  int wbase = 0;
  #pragma unroll
  for (int i = 0; i < 16; i++) wbase += (i < wv) ? wsum[i] : 0;
  int run = wbase + (s - tsum);
  pre[basei] = run;
  if (basei < W) off[oR + node0 + basei] = csrB + run;
  run += v0;
  pre[basei + 1] = run;
  if (basei + 1 < W) off[oR + node0 + basei + 1] = csrB + run;
  cnt[basei] = 0; cnt[basei + 1] = 0;          // reuse as rank cursor
  __syncthreads();
  for (int i = bstart + t; i < bend; i += 1024) {
    u32 rc = bdata[i];
    int ld = rc & (BKW - 1);
    int src = (int)(rc >> BKSH);
    int rank = atomicAdd(&cnt[ld], 1);
    int pos = csrB + pre[ld] + rank;
    if ((u32)pos < (u32)Lr) csr[gR + pos] = src;    // L2-resident bucket region
  }
}

// ---------------------------------------------------------------------------
// ILP-8 mean-gather of one node's neighborhood (lane = feature column).
__device__ __forceinline__ float gmean8(const u16* __restrict__ src, const int* __restrict__ off,
                                        const int* __restrict__ idx, u32 ns, int g, int lane) {
  int e0 = off[g], e1 = off[g + 1];
  int d = e1 - e0;
  float a[8] = {0.f, 0.f, 0.f, 0.f, 0.f, 0.f, 0.f, 0.f};
  int eL = e1 - 1;
  for (int base = e0; base < e1; base += 8) {
    int id[8];
    #pragma unroll
    for (int j = 0; j < 8; j++) {
      int e = base + j;
      int i = idx[e <= eL ? e : eL];       // clamped: always a valid address
      id[j] = ((u32)i < ns) ? i : 0;
    }
    float v[8];
    #pragma unroll
    for (int j = 0; j < 8; j++)            // 8 independent row loads in flight
      v[j] = bf2f(src[(size_t)id[j] * 64 + lane]);
    #pragma unroll
    for (int j = 0; j < 8; j++)
      a[j] += (base + j < e1) ? v[j] : 0.f;
  }
  float s = ((a[0] + a[1]) + (a[2] + a[3])) + ((a[4] + a[5]) + (a[6] + a[7]));
  return (d > 0) ? s / (float)d : 0.f;
}

// ---------------------------------------------------------------------------
// FUSED SAGE layer: gather-mean + MFMA GEMM + epilogue, ping-pong output.
// Block = 16 dst rows, 4 waves. Wave w gathers rows w*4..w*4+3 (NM relations
// + root X) into LDS A-tile [16][(NM+1)*64+8]; barrier; wave w then computes
// output cols w*16..w*16+15 with KC=2*(NM+1) MFMAs (A from LDS, B from the
// L1-hot prepped bf16 weights); epilogue reads X-residual from the same LDS
// tile, stages D through LDS, stores coalesced 16B/lane.
// Means never touch HBM: kills the pAg materialization round-trip
// (~150 MB/layer) of the decoupled agg_mean+gemm_sage pipeline.
template <int NM>
__global__ void __launch_bounds__(256, 4) sage_fused(
    const u16* __restrict__ X, u16* __restrict__ out,   // out != X (ping-pong)
    const u16* __restrict__ S0, const int* __restrict__ of0, const int* __restrict__ ix0, int ns0,
    const u16* __restrict__ S1, const int* __restrict__ of1, const int* __restrict__ ix1, int ns1,
    const u16* __restrict__ S2, const int* __restrict__ of2, const int* __restrict__ ix2, int ns2,
    const u16* __restrict__ lin0, const u16* __restrict__ lin1, const u16* __restrict__ lin2,
    const u16* __restrict__ root, const float* __restrict__ bsum,
    float scale, int n) {
  constexpr int KC = 2 * (NM + 1);            // K-chunks of 32
  constexpr int AP = (NM + 1) * 64 + 8;       // padded A row pitch (u16)
  __shared__ u16 A_lds[16 * AP];
  __shared__ u16 D_lds[16 * 72];
  int t = threadIdx.x, wave = t >> 6, lane = t & 63;
  int col0 = lane & 15, kb = lane >> 4;
  int m0 = blockIdx.x << 4;

  // ---- gather phase: wave w fills rows w*4..w*4+3 of the A tile ----
  #pragma unroll
  for (int j = 0; j < 4; j++) {
    int rr = wave * 4 + j;
    int g = m0 + rr;
    int gc = (g < n) ? g : (n - 1);
    float m0v = gmean8(S0, of0, ix0, (u32)ns0, gc, lane);
    A_lds[rr * AP + lane] = f2bf(m0v);
    if (NM == 3) {
      float m1v = gmean8(S1, of1, ix1, (u32)ns1, gc, lane);
      A_lds[rr * AP + 64 + lane] = f2bf(m1v);
      float m2v = gmean8(S2, of2, ix2, (u32)ns2, gc, lane);
      A_lds[rr * AP + 128 + lane] = f2bf(m2v);
    }
    A_lds[rr * AP + NM * 64 + lane] = X[(size_t)gc * 64 + lane];  // root row
  }
  __syncthreads();

  // ---- MFMA phase: wave w computes output cols w*16..w*16+15 ----
  const u16* Wbase[KC];
  #pragma unroll
  for (int kc = 0; kc < KC; kc++) {
    int m = kc >> 1;
    const u16* basep = (m < NM) ? ((m == 0) ? lin0 : (m == 1) ? lin1 : lin2) : root;
    Wbase[kc] = basep + (kc & 1) * 32 + kb * 8;
  }
  int oc = wave * 16 + col0;                   // this thread's output column
  f32x4 acc = {};
  #pragma unroll
  for (int kc = 0; kc < KC; kc++) {
    // A cols for chunk kc: (kc>>1)*64 + (kc&1)*32 + kb*8 == kc*32 + kb*8
    bf16x8 Af = *(const bf16x8*)&A_lds[col0 * AP + kc * 32 + kb * 8];
    bf16x8 B  = *(const bf16x8*)(Wbase[kc] + oc * 64);   // L1-hot weights
    acc = __builtin_amdgcn_mfma_f32_16x16x32_bf16(Af, B, acc, 0, 0, 0);
  }

  // ---- epilogue: v = relu((acc+b)*s) + x, staged via LDS for coalesced IO ----
  float b0 = bsum[oc];
  #pragma unroll
  for (int j = 0; j < 4; j++) {
    int rr = kb * 4 + j;                       // D row within tile
    float xv = bf2f(A_lds[rr * AP + NM * 64 + oc]);
    float v = fmaxf((acc[j] + b0) * scale, 0.f) + xv;
    D_lds[rr * 72 + oc] = f2bf(v);
  }
  __syncthreads();
  int ccl = (lane & 7) * 8;
  #pragma unroll
  for (int it = 0; it < 2; it++) {
    int rr = it * 8 + (lane >> 3);
    int row = m0 + rr;
    if (row < n) {
      bf16x8 o8;
      #pragma unroll
      for (int j = 0; j < 8; j++) o8[j] = (short)D_lds[rr * 72 + ccl + j];
      *(bf16x8*)(out + (size_t)row * 64 + ccl) = o8;     // 16B coalesced store
    }
  }
}

// ---------------------------------------------------------------------------
// Column sums over bf16 features (graph-mean readout)
__global__ void colsum2(const u16* __restrict__ x, int n, float* __restrict__ gout) {
  __shared__ float part[64];
  int t = threadIdx.x;
  if (t < 64) part[t] = 0.f;
  __syncthreads();
  int col = t & 63, w = blockIdx.x * 4 + (t >> 6), tw = gridDim.x * 4;
  float s = 0.f;
  for (int r = w; r < n; r += tw) s += bf2f(x[(size_t)r * 64 + col]);
  atomicAdd(&part[col], s);
  __syncthreads();
  if (t < 64) atomicAdd(&gout[t], part[t]);
}

// Crime head: out[0:20) as FP32
__global__ void __launch_bounds__(256) head2(const float* __restrict__ gsum,
    const float* __restrict__ Wc1, const float* __restrict__ bc1,
    const float* __restrict__ Wc2, const float* __restrict__ bc2,
    int NP, int NO, int NL, float* __restrict__ out) {
  __shared__ float g[192];
  __shared__ float h[64];
  int t = threadIdx.x;
  if (t < 192) {
    float d = (t < 64) ? (float)NP : (t < 128) ? (float)NO : (float)NL;
    g[t] = gsum[t] / d;
  }
  __syncthreads();
  if (t < 64) {
    float a = bc1[t];
    for (int k = 0; k < 192; k++) a += g[k] * Wc1[(size_t)t * 192 + k];
    h[t] = fmaxf(a, 0.f);
  }
  __syncthreads();
  if (t < 20) {
    float a = bc2[t];
    for (int k = 0; k < 64; k++) a += h[k] * Wc2[(size_t)t * 64 + k];
    out[t] = a;
  }
}

// Suspect head: out[i] as FP32 (out passed pre-offset by +20)
__global__ void __launch_bounds__(256) suspect2(const u16* __restrict__ p,
    const float* __restrict__ Ws1, const float* __restrict__ bs1,
    const float* __restrict__ Ws2, const float* __restrict__ bs2,
    float* __restrict__ out, int NP) {
  __shared__ float W1[2048];
  __shared__ float b1[32], w2[32];
  __shared__ float b2s;
  int t = threadIdx.x;
  #pragma unroll
  for (int i = 0; i < 8; i++) {
    int d = t + i * 256;
    W1[d] = Ws1[d];
  }
  if (t < 32) { b1[t] = bs1[t]; w2[t] = Ws2[t]; }
  if (t == 0) b2s = bs2[0];
  __syncthreads();
  int i = blockIdx.x * 256 + t;
  if (i >= NP) return;
  float x[64];
  #pragma unroll
  for (int k = 0; k < 64; k++) x[k] = bf2f(p[(size_t)i * 64 + k]);
  float sc = b2s;
  for (int j = 0; j < 32; j++) {
    float a = b1[j];
    const float* wr = &W1[j * 64];
    #pragma unroll
    for (int k = 0; k < 64; k++) a += x[k] * wr[k];
    sc += fmaxf(a, 0.f) * w2[j];
  }
  out[i] = sc;
}

// ---------------------------------------------------------------------------
extern "C" void kernel_launch(void* const* d_in, const int* in_sizes, int n_in,
                              void* d_out, int out_size, void* d_ws, size_t ws_size,
                              hipStream_t stream) {
  const int NP = in_sizes[0], NO = in_sizes[1], NL = in_sizes[2];
  const int Ea = in_sizes[3], Eu = in_sizes[5], Et = in_sizes[7];
  const int VP = in_sizes[9] / 64, VO = in_sizes[10] / 64, VL = in_sizes[11] / 64;

  const int* x_person   = (const int*)d_in[0];
  const int* x_object   = (const int*)d_in[1];
  const int* x_location = (const int*)d_in[2];
  const int* acts_src = (const int*)d_in[3];
  const int* acts_dst = (const int*)d_in[4];
  const int* uses_src = (const int*)d_in[5];
  const int* uses_dst = (const int*)d_in[6];
  const int* at_src   = (const int*)d_in[7];
  const int* at_dst   = (const int*)d_in[8];
  const float* person_emb   = (const float*)d_in[9];
  const float* object_emb   = (const float*)d_in[10];
  const float* location_emb = (const float*)d_in[11];
  const float* Wl  = (const float*)d_in[12];
  const float* bl  = (const float*)d_in[13];
  const float* Wr  = (const float*)d_in[14];
  const float* Wc1 = (const float*)d_in[15];
  const float* bc1 = (const float*)d_in[16];
  const float* Wc2 = (const float*)d_in[17];
  const float* bc2 = (const float*)d_in[18];
  const float* Ws1 = (const float*)d_in[19];
  const float* bs1 = (const float*)d_in[20];
  const float* Ws2 = (const float*)d_in[21];
  const float* bs2 = (const float*)d_in[22];
  float* out = (float*)d_out;

  // ---- bucket geometry (MAXBK guard: bench is 368) ----
  int B0 = (NP + BKW - 1) >> BKSH;
  int B1 = (NO + BKW - 1) >> BKSH;
  int B3 = (NL + BKW - 1) >> BKSH;
  int s1 = B0, s2 = s1 + B1, s3 = s2 + B0, s4 = s3 + B3, NBK = s4 + B0;
  if (NBK > MAXBK) return;   // out stays 0 -> visible failure signature

  // ---- workspace (16B aligned) ----
  char* w = (char*)d_ws;
  auto alloc = [&](size_t bytes) { char* r = w; w += (bytes + 15) & ~(size_t)15; return r; };
  u16* pA = (u16*)alloc((size_t)NP * 128);
  u16* pB = (u16*)alloc((size_t)NP * 128);
  u16* oA = (u16*)alloc((size_t)NO * 128);
  u16* oB = (u16*)alloc((size_t)NO * 128);
  u16* lA = (u16*)alloc((size_t)NL * 128);
  u16* lB = (u16*)alloc((size_t)NL * 128);
  float* gsum = (float*)alloc(192 * 4);
  const size_t CN = (size_t)3 * NP + NO + NL;
  int* off = (int*)alloc((CN + 8) * 4);
  int* bcnt  = (int*)alloc((MAXBK) * 4);
  int* bbase = (int*)alloc((MAXBK + 1) * 4);
  int* bcur  = (int*)alloc((MAXBK) * 4);
  const int E1 = Ea, E2 = E1 + Eu, E3 = E2 + Eu, E4 = E3 + Et, E5 = E4 + Et;
  u32* bdata = (u32*)alloc((size_t)E5 * 4);
  u16* WBlin  = (u16*)alloc((size_t)3 * 5 * 4096 * 2);
  u16* WBroot = (u16*)alloc((size_t)3 * 3 * 4096 * 2);
  float* bsums = (float*)alloc((size_t)3 * 3 * 64 * 4);
  int* csr = (int*)alloc((size_t)E5 * 4);
  size_t base_need = (size_t)(w - (char*)d_ws);
  (void)n_in; (void)out_size;
  // ws guard: if it fires, out stays 0 -> absmax == 0.118652 exactly (signature)
  if (base_need > ws_size) return;

  int o0 = 0, o1 = NP + 1, o2 = o1 + NO + 1, o3 = o2 + NP + 1, o4 = o3 + NL + 1;
  int g1 = Ea, g2 = Ea + Eu, g3 = Ea + 2 * Eu, g4 = Ea + 2 * Eu + Et;
  int* csr0 = csr;
  int* csr1 = csr + g1;
  int* csr2 = csr + g2;
  int* csr3 = csr + g3;
  int* csr4 = csr + g4;

  hipMemsetAsync(bcnt, 0, MAXBK * sizeof(int), stream);
  hipMemsetAsync(gsum, 0, 192 * sizeof(float), stream);

  prep_w<<<387, 256, 0, stream>>>(Wl, Wr, bl, WBlin, WBroot, bsums);

  gather_f2b<<<(NP * 64 + 255) / 256, 256, 0, stream>>>(person_emb, x_person, pA, NP, VP);
  gather_f2b<<<(NO * 64 + 255) / 256, 256, 0, stream>>>(object_emb, x_object, oA, NO, VO);
  gather_f2b<<<(NL * 64 + 255) / 256, 256, 0, stream>>>(location_emb, x_location, lA, NL, VL);

  // ---- CSR build: bucket-sort (dense writes) ----
  bkt_count<<<(E5 + 8191) / 8192, 256, 0, stream>>>(
      acts_dst, uses_dst, uses_src, at_dst, at_src, bcnt,
      E1, E2, E3, E4, E5, s1, s2, s3, s4, NP, NO, NP, NL, NP, NBK);
  bkt_scan<<<1, 512, 0, stream>>>(bcnt, bbase, bcur, off,
      s1, s2, s3, s4, NBK,
      o0 + NP, o1 + NO, o2 + NP, o3 + NL, o4 + NP);
  bkt_scatter<<<(E5 + 4095) / 4096, 256, 0, stream>>>(
      acts_src, uses_src, uses_dst, at_src, at_dst,
      acts_dst, uses_dst, uses_src, at_dst, at_src,
      bcur, bdata, E1, E2, E3, E4, E5, s1, s2, s3, s4, NP, NO, NP, NL, NP, NBK);
  bkt_sort<<<NBK, 1024, 0, stream>>>(bbase, bdata, off, csr,
      s1, s2, s3, s4, NBK, NP, NO, NP, NL, NP,
      o1, o2, o3, o4, g1, g2, g3, g4, Ea, Eu, Et);

  // ---- 3 layers: fused gather+GEMM, ping-pong buffers ----
  u16* pb[2] = {pA, pB};
  u16* ob[2] = {oA, oB};
  u16* lb[2] = {lA, lB};
  int cu = 0;
  for (int t = 0; t < 3; t++) {
    u16 *pi = pb[cu], *po = pb[1 - cu];
    u16 *oi = ob[cu], *oo = ob[1 - cu];
    u16 *li = lb[cu], *lo = lb[1 - cu];
    sage_fused<3><<<(NP + 15) / 16, 256, 0, stream>>>(pi, po,
        pi, off + o0, csr0, NP,
        oi, off + o2, csr2, NO,
        li, off + o4, csr4, NL,
        WBlin + ((size_t)t * 5 + 0) * 4096,
        WBlin + ((size_t)t * 5 + 2) * 4096,
        WBlin + ((size_t)t * 5 + 4) * 4096,
        WBroot + ((size_t)t * 3 + 0) * 4096,
        bsums + ((size_t)t * 3 + 0) * 64, 1.f / 3.f, NP);
    sage_fused<1><<<(NO + 15) / 16, 256, 0, stream>>>(oi, oo,
        pi, off + o1, csr1, NP,
        (const u16*)0, (const int*)0, (const int*)0, 0,
        (const u16*)0, (const int*)0, (const int*)0, 0,
        WBlin + ((size_t)t * 5 + 1) * 4096, (const u16*)0, (const u16*)0,
        WBroot + ((size_t)t * 3 + 1) * 4096,
        bsums + ((size_t)t * 3 + 1) * 64, 1.f, NO);
    sage_fused<1><<<(NL + 15) / 16, 256, 0, stream>>>(li, lo,
        pi, off + o3, csr3, NP,
        (const u16*)0, (const int*)0, (const int*)0, 0,
        (const u16*)0, (const int*)0, (const int*)0, 0,
        WBlin + ((size_t)t * 5 + 3) * 4096, (const u16*)0, (const u16*)0,
        WBroot + ((size_t)t * 3 + 2) * 4096,
        bsums + ((size_t)t * 3 + 2) * 64, 1.f, NL);
    cu = 1 - cu;
  }
  const u16* pF = pb[cu];
  const u16* oF = ob[cu];
  const u16* lF = lb[cu];

  // ---- readout (FP32 output) ----
  colsum2<<<128, 256, 0, stream>>>(pF, NP, gsum);
  colsum2<<<64, 256, 0, stream>>>(oF, NO, gsum + 64);
  colsum2<<<32, 256, 0, stream>>>(lF, NL, gsum + 128);
  head2<<<1, 256, 0, stream>>>(gsum, Wc1, bc1, Wc2, bc2, NP, NO, NL, out);
  suspect2<<<(NP + 255) / 256, 256, 0, stream>>>(pF, Ws1, bs1, Ws2, bs2, out + 20, NP);
}

// Round 6
// 1121.770 us; speedup vs baseline: 1.9712x; 1.3341x over previous
//
#include <hip/hip_runtime.h>

typedef unsigned short u16;
typedef unsigned int u32;
typedef __attribute__((ext_vector_type(8))) short bf16x8;
typedef __attribute__((ext_vector_type(4))) float f32x4;

#define BKW 2048           // bucket width (nodes); BKSH = log2(BKW)
#define BKSH 11
#define MAXBK 512          // max total buckets (bench: 368)

__device__ __forceinline__ float bf2f(u16 u) { return __uint_as_float(((u32)u) << 16); }
__device__ __forceinline__ u16 f2bf(float f) {
  u32 u = __float_as_uint(f);
  return (u16)((u + 0x7fffu + ((u >> 16) & 1u)) >> 16);
}

// ---------------------------------------------------------------------------
// Embedding gather: fp32 emb row -> internal bf16 feature row. 1 thread/elem.
__global__ void gather_f2b(const float* __restrict__ emb, const int* __restrict__ ids,
                           u16* __restrict__ out, int n, int V) {
  int u = blockIdx.x * 256 + threadIdx.x;
  if (u >= n * 64) return;
  int node = u >> 6, k = u & 63;
  int r = ids[node];
  r = ((u32)r < (u32)V) ? r : 0;
  out[u] = f2bf(emb[(size_t)r * 64 + k]);
}

// ---------------------------------------------------------------------------
// Weight prep (once per launch): bf16 lin weights, bf16 root-sum weights,
// fp32 bias-sums.
__global__ void prep_w(const float* __restrict__ Wl, const float* __restrict__ Wr,
                       const float* __restrict__ bl,
                       u16* __restrict__ WBlin, u16* __restrict__ WBroot,
                       float* __restrict__ bsums) {
  int i = blockIdx.x * 256 + threadIdx.x;
  const int TL = 3 * 5 * 4096;
  if (i < TL) { WBlin[i] = f2bf(Wl[i]); return; }
  int j = i - TL;
  if (j < 3 * 3 * 4096) {
    int lt = j / (3 * 4096), rem = j % (3 * 4096), c = rem / 4096, e = rem % 4096;
    int r0 = (c == 0) ? 0 : (c == 1) ? 1 : 3;
    float v = Wr[((size_t)lt * 5 + r0) * 4096 + e];
    if (c == 0) v += Wr[((size_t)lt * 5 + 2) * 4096 + e] +
                     Wr[((size_t)lt * 5 + 4) * 4096 + e];
    WBroot[j] = f2bf(v);
    return;
  }
  int k2 = j - 3 * 3 * 4096;
  if (k2 < 3 * 3 * 64) {
    int lt = k2 / 192, rem = k2 % 192, c = rem / 64, e = rem % 64;
    int r0 = (c == 0) ? 0 : (c == 1) ? 1 : 3;
    float v = bl[((size_t)lt * 5 + r0) * 64 + e];
    if (c == 0) v += bl[((size_t)lt * 5 + 2) * 64 + e] +
                     bl[((size_t)lt * 5 + 4) * 64 + e];
    bsums[k2] = v;
  }
}

// ---------------------------------------------------------------------------
// CSR build, bucket-sort formulation (dense writes).
// ---------------------------------------------------------------------------
__global__ void __launch_bounds__(256) bkt_count(
    const int* __restrict__ D0, const int* __restrict__ D1, const int* __restrict__ D2,
    const int* __restrict__ D3, const int* __restrict__ D4,
    int* __restrict__ bcnt,
    int E1, int E2, int E3, int E4, int E5,
    int s1, int s2, int s3, int s4,
    int N0, int N1, int N2, int N3, int N4, int NBK) {
  __shared__ int c[MAXBK];
  int t = threadIdx.x;
  for (int i = t; i < NBK; i += 256) c[i] = 0;
  __syncthreads();
  int chunk0 = blockIdx.x * 8192;
  for (int j = 0; j < 32; j++) {
    int e = chunk0 + j * 256 + t;
    if (e >= E5) break;
    const int* dp; int sb, N, le;
    if (e < E1)      { dp = D0; sb = 0;  N = N0; le = e; }
    else if (e < E2) { dp = D1; sb = s1; N = N1; le = e - E1; }
    else if (e < E3) { dp = D2; sb = s2; N = N2; le = e - E2; }
    else if (e < E4) { dp = D3; sb = s3; N = N3; le = e - E3; }
    else             { dp = D4; sb = s4; N = N4; le = e - E4; }
    int d = dp[le];
    if ((u32)d < (u32)N) atomicAdd(&c[sb + (d >> BKSH)], 1);
  }
  __syncthreads();
  for (int i = t; i < NBK; i += 256) if (c[i]) atomicAdd(&bcnt[i], c[i]);
}

__global__ void __launch_bounds__(512) bkt_scan(
    const int* __restrict__ bcnt, int* __restrict__ bbase, int* __restrict__ bcur,
    int* __restrict__ off,
    int s1, int s2, int s3, int s4, int NBK,
    int q0, int q1, int q2, int q3, int q4) {   // absolute off-sentinel indices
  __shared__ int sb[MAXBK + 1];
  __shared__ int ws[8];
  int t = threadIdx.x, lane = t & 63, wv = t >> 6;
  int v = (t < NBK) ? bcnt[t] : 0;
  int s = v;
  #pragma unroll
  for (int d = 1; d < 64; d <<= 1) { int u = __shfl_up(s, d); if (lane >= d) s += u; }
  if (lane == 63) ws[wv] = s;
  __syncthreads();
  int wbase = 0;
  for (int i = 0; i < wv; i++) wbase += ws[i];
  int excl = wbase + (s - v);
  if (t < NBK) { bbase[t] = excl; bcur[t] = excl; sb[t] = excl; }
  if (t == 0) {
    int tot = 0;
    #pragma unroll
    for (int i = 0; i < 8; i++) tot += ws[i];
    bbase[NBK] = tot; sb[NBK] = tot;
  }
  __syncthreads();
  if (t == 0) off[q0] = sb[s1];
  else if (t == 1) off[q1] = sb[s2] - sb[s1];
  else if (t == 2) off[q2] = sb[s3] - sb[s2];
  else if (t == 3) off[q3] = sb[s4] - sb[s3];
  else if (t == 4) off[q4] = sb[NBK] - sb[s4];
}

__global__ void __launch_bounds__(256) bkt_scatter(
    const int* __restrict__ S0, const int* __restrict__ S1, const int* __restrict__ S2,
    const int* __restrict__ S3, const int* __restrict__ S4,
    const int* __restrict__ D0, const int* __restrict__ D1, const int* __restrict__ D2,
    const int* __restrict__ D3, const int* __restrict__ D4,
    int* __restrict__ bcur, u32* __restrict__ bdata,
    int E1, int E2, int E3, int E4, int E5,
    int s1, int s2, int s3, int s4,
    int N0, int N1, int N2, int N3, int N4, int NBK) {
  __shared__ int c[MAXBK];
  __shared__ int base[MAXBK];
  int t = threadIdx.x;
  for (int i = t; i < NBK; i += 256) c[i] = 0;
  __syncthreads();
  int chunk0 = blockIdx.x * 4096;
  int lb[16]; u32 rec[16];
  #pragma unroll
  for (int j = 0; j < 16; j++) {
    int e = chunk0 + j * 256 + t;
    lb[j] = -1;
    if (e < E5) {
      const int *sp, *dp; int sb, N, le;
      if (e < E1)      { sp = S0; dp = D0; sb = 0;  N = N0; le = e; }
      else if (e < E2) { sp = S1; dp = D1; sb = s1; N = N1; le = e - E1; }
      else if (e < E3) { sp = S2; dp = D2; sb = s2; N = N2; le = e - E2; }
      else if (e < E4) { sp = S3; dp = D3; sb = s3; N = N3; le = e - E3; }
      else             { sp = S4; dp = D4; sb = s4; N = N4; le = e - E4; }
      int d = dp[le];
      if ((u32)d < (u32)N) {
        lb[j] = sb + (d >> BKSH);
        rec[j] = ((u32)sp[le] << BKSH) | (u32)(d & (BKW - 1));
        atomicAdd(&c[lb[j]], 1);
      }
    }
  }
  __syncthreads();
  for (int i = t; i < NBK; i += 256) {
    int cc = c[i];
    base[i] = cc ? atomicAdd(&bcur[i], cc) : 0;
    c[i] = 0;
  }
  __syncthreads();
  #pragma unroll
  for (int j = 0; j < 16; j++) {
    if (lb[j] >= 0) {
      int r = atomicAdd(&c[lb[j]], 1);
      int pos = base[lb[j]] + r;
      if ((u32)pos < (u32)E5) bdata[pos] = rec[j];   // dense bucket frontier write
    }
  }
}

// 1024 threads/block: 368 blocks x 16 waves.
__global__ void __launch_bounds__(1024) bkt_sort(
    const int* __restrict__ bbase, const u32* __restrict__ bdata,
    int* __restrict__ off, int* __restrict__ csr,
    int s1, int s2, int s3, int s4, int NBK,
    int N0, int N1, int N2, int N3, int N4,
    int o1, int o2, int o3, int o4,
    int g1, int g2, int g3, int g4,
    int La, int Lu, int Lt) {
  __shared__ int cnt[BKW];
  __shared__ int pre[BKW];
  __shared__ int wsum[16];
  int b = blockIdx.x, t = threadIdx.x, lane = t & 63, wv = t >> 6;
  int r = (b >= s4) ? 4 : (b >= s3) ? 3 : (b >= s2) ? 2 : (b >= s1) ? 1 : 0;
  int sr = (r == 0) ? 0 : (r == 1) ? s1 : (r == 2) ? s2 : (r == 3) ? s3 : s4;
  int Nr = (r == 0) ? N0 : (r == 1) ? N1 : (r == 2) ? N2 : (r == 3) ? N3 : N4;
  int oR = (r == 0) ? 0 : (r == 1) ? o1 : (r == 2) ? o2 : (r == 3) ? o3 : o4;
  int gR = (r == 0) ? 0 : (r == 1) ? g1 : (r == 2) ? g2 : (r == 3) ? g3 : g4;
  int Lr = (r == 0) ? La : (r == 1 || r == 2) ? Lu : Lt;
  int relRecBase = bbase[sr];
  int bstart = bbase[b], bend = bbase[b + 1];
  int node0 = (b - sr) << BKSH;
  int W = Nr - node0; if (W > BKW) W = BKW;
  int csrB = bstart - relRecBase;              // base within relation csr segment
  for (int i = t; i < BKW; i += 1024) cnt[i] = 0;
  __syncthreads();
  for (int i = bstart + t; i < bend; i += 1024)
    atomicAdd(&cnt[bdata[i] & (BKW - 1)], 1);
  __syncthreads();
  // block exclusive scan over 2048 counts (2/thread)
  int basei = t * 2;
  int v0 = cnt[basei], v1 = cnt[basei + 1];
  int tsum = v0 + v1;
  int s = tsum;
  #pragma unroll
  for (int d = 1; d < 64; d <<= 1) { int u = __shfl_up(s, d); if (lane >= d) s += u; }
  if (lane == 63) wsum[wv] = s;
  __syncthreads();
  int wbase = 0;
  #pragma unroll
  for (int i = 0; i < 16; i++) wbase += (i < wv) ? wsum[i] : 0;
  int run = wbase + (s - tsum);
  pre[basei] = run;
  if (basei < W) off[oR + node0 + basei] = csrB + run;
  run += v0;
  pre[basei + 1] = run;
  if (basei + 1 < W) off[oR + node0 + basei + 1] = csrB + run;
  cnt[basei] = 0; cnt[basei + 1] = 0;          // reuse as rank cursor
  __syncthreads();
  for (int i = bstart + t; i < bend; i += 1024) {
    u32 rc = bdata[i];
    int ld = rc & (BKW - 1);
    int src = (int)(rc >> BKSH);
    int rank = atomicAdd(&cnt[ld], 1);
    int pos = csrB + pre[ld] + rank;
    if ((u32)pos < (u32)Lr) csr[gR + pos] = src;    // L2-resident bucket region
  }
}

// ---------------------------------------------------------------------------
// FUSED SAGE layer v2: vectorized gather + MFMA GEMM + epilogue, ping-pong.
// Block = 32 dst rows, 4 waves.
// GATHER: wave w owns rows w*8..w*8+7. Lane = (s,c): row-slot s=lane>>3,
// col-chunk c=lane&7. Per 8-edge round each lane does ONE bf16x8 (16B) load
// -> a wave-instruction moves 1KB (8 rows) instead of 128B (1 row): 8x fewer
// VMEM+VALU per byte than the scalar-per-column gmean (v1 was 85% VALUBusy).
// ids burst-loaded 8 ahead (2 dependent latencies per round); 8 lanes of a
// row-slot share the idx address (HW broadcast). No cross-lane reduction:
// each lane owns its 8 columns, writes bf16x8 straight to the LDS A-tile.
// MFMA: wave w computes rows (w&1)*16..+16, cols (w>>1)*32..+32.
template <int NM>
__global__ void __launch_bounds__(256, 4) sage_fused(
    const u16* __restrict__ X, u16* __restrict__ out,   // out != X (ping-pong)
    const u16* __restrict__ S0, const int* __restrict__ of0, const int* __restrict__ ix0, int ns0,
    const u16* __restrict__ S1, const int* __restrict__ of1, const int* __restrict__ ix1, int ns1,
    const u16* __restrict__ S2, const int* __restrict__ of2, const int* __restrict__ ix2, int ns2,
    const u16* __restrict__ lin0, const u16* __restrict__ lin1, const u16* __restrict__ lin2,
    const u16* __restrict__ root, const float* __restrict__ bsum,
    float scale, int n) {
  constexpr int KC = 2 * (NM + 1);            // K-chunks of 32
  constexpr int AP = (NM + 1) * 64 + 8;       // padded A row pitch (u16)
  __shared__ __align__(16) u16 A_lds[32 * AP];
  __shared__ __align__(16) u16 D_lds[32 * 72];
  int t = threadIdx.x, wave = t >> 6, lane = t & 63;
  int m0 = blockIdx.x << 5;

  // ---- gather phase: lane (s,c); wave w fills rows w*8..w*8+7 ----
  {
    int s = lane >> 3, c = lane & 7;
    int rr = wave * 8 + s;
    int g = m0 + rr;
    int gc = (g < n) ? g : (n - 1);
    #pragma unroll
    for (int rel = 0; rel < NM; rel++) {
      const u16* S  = (rel == 0) ? S0 : (rel == 1) ? S1 : S2;
      const int* of = (rel == 0) ? of0 : (rel == 1) ? of1 : of2;
      const int* ix = (rel == 0) ? ix0 : (rel == 1) ? ix1 : ix2;
      u32 ns = (u32)((rel == 0) ? ns0 : (rel == 1) ? ns1 : ns2);
      int e0 = of[gc], e1 = of[gc + 1];
      int deg = e1 - e0;
      float a[8] = {0.f, 0.f, 0.f, 0.f, 0.f, 0.f, 0.f, 0.f};
      for (int base = e0; __any(base < e1); base += 8) {
        int id[8];
        #pragma unroll
        for (int j = 0; j < 8; j++) {        // 8 independent 4B id loads
          int e = base + j;
          id[j] = (e < e1) ? ix[e] : -1;     // exec-masked load
        }
        #pragma unroll
        for (int j = 0; j < 8; j++) {        // 8 independent 16B row loads
          bf16x8 v = {};
          if ((u32)id[j] < ns)               // exec-masked: no fetch if inactive
            v = *(const bf16x8*)(S + (size_t)(u32)id[j] * 64 + c * 8);
          #pragma unroll
          for (int k = 0; k < 8; k++) a[k] += bf2f((u16)v[k]);
        }
      }
      float inv = (deg > 0) ? 1.f / (float)deg : 0.f;
      bf16x8 m8;
      #pragma unroll
      for (int k = 0; k < 8; k++) m8[k] = (short)f2bf(a[k] * inv);
      *(bf16x8*)&A_lds[rr * AP + rel * 64 + c * 8] = m8;
    }
    // root X row (16B vector copy)
    bf16x8 xv = *(const bf16x8*)(X + (size_t)gc * 64 + c * 8);
    *(bf16x8*)&A_lds[rr * AP + NM * 64 + c * 8] = xv;
  }
  __syncthreads();

  // ---- MFMA phase: wave w -> rows (w&1)*16..+16, cols (w>>1)*32..+32 ----
  int col0 = lane & 15, kb = lane >> 4;
  int rt = (wave & 1) * 16;
  int ct = (wave >> 1) * 32;
  const u16* Wbase[KC];
  #pragma unroll
  for (int kc = 0; kc < KC; kc++) {
    int m = kc >> 1;
    const u16* basep = (m < NM) ? ((m == 0) ? lin0 : (m == 1) ? lin1 : lin2) : root;
    Wbase[kc] = basep + (kc & 1) * 32 + kb * 8;
  }
  f32x4 acc0 = {}, acc1 = {};
  #pragma unroll
  for (int kc = 0; kc < KC; kc++) {
    bf16x8 Af = *(const bf16x8*)&A_lds[(rt + col0) * AP + kc * 32 + kb * 8];
    bf16x8 B0 = *(const bf16x8*)(Wbase[kc] + (ct + col0) * 64);        // L1 hot
    acc0 = __builtin_amdgcn_mfma_f32_16x16x32_bf16(Af, B0, acc0, 0, 0, 0);
    bf16x8 B1 = *(const bf16x8*)(Wbase[kc] + (ct + 16 + col0) * 64);
    acc1 = __builtin_amdgcn_mfma_f32_16x16x32_bf16(Af, B1, acc1, 0, 0, 0);
  }

  // ---- epilogue: v = relu((acc+b)*s) + x, staged via LDS for coalesced IO ----
  float b0 = bsum[ct + col0];
  float b1 = bsum[ct + 16 + col0];
  #pragma unroll
  for (int j = 0; j < 4; j++) {
    int dr = rt + kb * 4 + j;                // D row within 32-row tile
    float xv0 = bf2f(A_lds[dr * AP + NM * 64 + ct + col0]);
    D_lds[dr * 72 + ct + col0] = f2bf(fmaxf((acc0[j] + b0) * scale, 0.f) + xv0);
    float xv1 = bf2f(A_lds[dr * AP + NM * 64 + ct + 16 + col0]);
    D_lds[dr * 72 + ct + 16 + col0] = f2bf(fmaxf((acc1[j] + b1) * scale, 0.f) + xv1);
  }
  __syncthreads();
  int row32 = t >> 3, cc = (t & 7) * 8;      // 256 threads = 32 rows x 8 chunks
  int row = m0 + row32;
  if (row < n) {
    bf16x8 o8;
    #pragma unroll
    for (int j = 0; j < 8; j++) o8[j] = (short)D_lds[row32 * 72 + cc + j];
    *(bf16x8*)(out + (size_t)row * 64 + cc) = o8;       // 16B coalesced store
  }
}

// ---------------------------------------------------------------------------
// Column sums over bf16 features (graph-mean readout)
__global__ void colsum2(const u16* __restrict__ x, int n, float* __restrict__ gout) {
  __shared__ float part[64];
  int t = threadIdx.x;
  if (t < 64) part[t] = 0.f;
  __syncthreads();
  int col = t & 63, w = blockIdx.x * 4 + (t >> 6), tw = gridDim.x * 4;
  float s = 0.f;
  for (int r = w; r < n; r += tw) s += bf2f(x[(size_t)r * 64 + col]);
  atomicAdd(&part[col], s);
  __syncthreads();
  if (t < 64) atomicAdd(&gout[t], part[t]);
}

// Crime head: out[0:20) as FP32
__global__ void __launch_bounds__(256) head2(const float* __restrict__ gsum,
    const float* __restrict__ Wc1, const float* __restrict__ bc1,
    const float* __restrict__ Wc2, const float* __restrict__ bc2,
    int NP, int NO, int NL, float* __restrict__ out) {
  __shared__ float g[192];
  __shared__ float h[64];
  int t = threadIdx.x;
  if (t < 192) {
    float d = (t < 64) ? (float)NP : (t < 128) ? (float)NO : (float)NL;
    g[t] = gsum[t] / d;
  }
  __syncthreads();
  if (t < 64) {
    float a = bc1[t];
    for (int k = 0; k < 192; k++) a += g[k] * Wc1[(size_t)t * 192 + k];
    h[t] = fmaxf(a, 0.f);
  }
  __syncthreads();
  if (t < 20) {
    float a = bc2[t];
    for (int k = 0; k < 64; k++) a += h[k] * Wc2[(size_t)t * 64 + k];
    out[t] = a;
  }
}

// Suspect head: out[i] as FP32 (out passed pre-offset by +20)
__global__ void __launch_bounds__(256) suspect2(const u16* __restrict__ p,
    const float* __restrict__ Ws1, const float* __restrict__ bs1,
    const float* __restrict__ Ws2, const float* __restrict__ bs2,
    float* __restrict__ out, int NP) {
  __shared__ float W1[2048];
  __shared__ float b1[32], w2[32];
  __shared__ float b2s;
  int t = threadIdx.x;
  #pragma unroll
  for (int i = 0; i < 8; i++) {
    int d = t + i * 256;
    W1[d] = Ws1[d];
  }
  if (t < 32) { b1[t] = bs1[t]; w2[t] = Ws2[t]; }
  if (t == 0) b2s = bs2[0];
  __syncthreads();
  int i = blockIdx.x * 256 + t;
  if (i >= NP) return;
  float x[64];
  #pragma unroll
  for (int k = 0; k < 64; k++) x[k] = bf2f(p[(size_t)i * 64 + k]);
  float sc = b2s;
  for (int j = 0; j < 32; j++) {
    float a = b1[j];
    const float* wr = &W1[j * 64];
    #pragma unroll
    for (int k = 0; k < 64; k++) a += x[k] * wr[k];
    sc += fmaxf(a, 0.f) * w2[j];
  }
  out[i] = sc;
}

// ---------------------------------------------------------------------------
extern "C" void kernel_launch(void* const* d_in, const int* in_sizes, int n_in,
                              void* d_out, int out_size, void* d_ws, size_t ws_size,
                              hipStream_t stream) {
  const int NP = in_sizes[0], NO = in_sizes[1], NL = in_sizes[2];
  const int Ea = in_sizes[3], Eu = in_sizes[5], Et = in_sizes[7];
  const int VP = in_sizes[9] / 64, VO = in_sizes[10] / 64, VL = in_sizes[11] / 64;

  const int* x_person   = (const int*)d_in[0];
  const int* x_object   = (const int*)d_in[1];
  const int* x_location = (const int*)d_in[2];
  const int* acts_src = (const int*)d_in[3];
  const int* acts_dst = (const int*)d_in[4];
  const int* uses_src = (const int*)d_in[5];
  const int* uses_dst = (const int*)d_in[6];
  const int* at_src   = (const int*)d_in[7];
  const int* at_dst   = (const int*)d_in[8];
  const float* person_emb   = (const float*)d_in[9];
  const float* object_emb   = (const float*)d_in[10];
  const float* location_emb = (const float*)d_in[11];
  const float* Wl  = (const float*)d_in[12];
  const float* bl  = (const float*)d_in[13];
  const float* Wr  = (const float*)d_in[14];
  const float* Wc1 = (const float*)d_in[15];
  const float* bc1 = (const float*)d_in[16];
  const float* Wc2 = (const float*)d_in[17];
  const float* bc2 = (const float*)d_in[18];
  const float* Ws1 = (const float*)d_in[19];
  const float* bs1 = (const float*)d_in[20];
  const float* Ws2 = (const float*)d_in[21];
  const float* bs2 = (const float*)d_in[22];
  float* out = (float*)d_out;

  // ---- bucket geometry (MAXBK guard: bench is 368) ----
  int B0 = (NP + BKW - 1) >> BKSH;
  int B1 = (NO + BKW - 1) >> BKSH;
  int B3 = (NL + BKW - 1) >> BKSH;
  int s1 = B0, s2 = s1 + B1, s3 = s2 + B0, s4 = s3 + B3, NBK = s4 + B0;
  if (NBK > MAXBK) return;   // out stays 0 -> visible failure signature

  // ---- workspace (16B aligned) ----
  char* w = (char*)d_ws;
  auto alloc = [&](size_t bytes) { char* r = w; w += (bytes + 15) & ~(size_t)15; return r; };
  u16* pA = (u16*)alloc((size_t)NP * 128);
  u16* pB = (u16*)alloc((size_t)NP * 128);
  u16* oA = (u16*)alloc((size_t)NO * 128);
  u16* oB = (u16*)alloc((size_t)NO * 128);
  u16* lA = (u16*)alloc((size_t)NL * 128);
  u16* lB = (u16*)alloc((size_t)NL * 128);
  float* gsum = (float*)alloc(192 * 4);
  const size_t CN = (size_t)3 * NP + NO + NL;
  int* off = (int*)alloc((CN + 8) * 4);
  int* bcnt  = (int*)alloc((MAXBK) * 4);
  int* bbase = (int*)alloc((MAXBK + 1) * 4);
  int* bcur  = (int*)alloc((MAXBK) * 4);
  const int E1 = Ea, E2 = E1 + Eu, E3 = E2 + Eu, E4 = E3 + Et, E5 = E4 + Et;
  u32* bdata = (u32*)alloc((size_t)E5 * 4);
  u16* WBlin  = (u16*)alloc((size_t)3 * 5 * 4096 * 2);
  u16* WBroot = (u16*)alloc((size_t)3 * 3 * 4096 * 2);
  float* bsums = (float*)alloc((size_t)3 * 3 * 64 * 4);
  int* csr = (int*)alloc((size_t)E5 * 4);
  size_t base_need = (size_t)(w - (char*)d_ws);
  (void)n_in; (void)out_size;
  // ws guard: if it fires, out stays 0 -> absmax == 0.118652 exactly (signature)
  if (base_need > ws_size) return;

  int o0 = 0, o1 = NP + 1, o2 = o1 + NO + 1, o3 = o2 + NP + 1, o4 = o3 + NL + 1;
  int g1 = Ea, g2 = Ea + Eu, g3 = Ea + 2 * Eu, g4 = Ea + 2 * Eu + Et;
  int* csr0 = csr;
  int* csr1 = csr + g1;
  int* csr2 = csr + g2;
  int* csr3 = csr + g3;
  int* csr4 = csr + g4;

  hipMemsetAsync(bcnt, 0, MAXBK * sizeof(int), stream);
  hipMemsetAsync(gsum, 0, 192 * sizeof(float), stream);

  prep_w<<<387, 256, 0, stream>>>(Wl, Wr, bl, WBlin, WBroot, bsums);

  gather_f2b<<<(NP * 64 + 255) / 256, 256, 0, stream>>>(person_emb, x_person, pA, NP, VP);
  gather_f2b<<<(NO * 64 + 255) / 256, 256, 0, stream>>>(object_emb, x_object, oA, NO, VO);
  gather_f2b<<<(NL * 64 + 255) / 256, 256, 0, stream>>>(location_emb, x_location, lA, NL, VL);

  // ---- CSR build: bucket-sort (dense writes) ----
  bkt_count<<<(E5 + 8191) / 8192, 256, 0, stream>>>(
      acts_dst, uses_dst, uses_src, at_dst, at_src, bcnt,
      E1, E2, E3, E4, E5, s1, s2, s3, s4, NP, NO, NP, NL, NP, NBK);
  bkt_scan<<<1, 512, 0, stream>>>(bcnt, bbase, bcur, off,
      s1, s2, s3, s4, NBK,
      o0 + NP, o1 + NO, o2 + NP, o3 + NL, o4 + NP);
  bkt_scatter<<<(E5 + 4095) / 4096, 256, 0, stream>>>(
      acts_src, uses_src, uses_dst, at_src, at_dst,
      acts_dst, uses_dst, uses_src, at_dst, at_src,
      bcur, bdata, E1, E2, E3, E4, E5, s1, s2, s3, s4, NP, NO, NP, NL, NP, NBK);
  bkt_sort<<<NBK, 1024, 0, stream>>>(bbase, bdata, off, csr,
      s1, s2, s3, s4, NBK, NP, NO, NP, NL, NP,
      o1, o2, o3, o4, g1, g2, g3, g4, Ea, Eu, Et);

  // ---- 3 layers: fused gather+GEMM, ping-pong buffers ----
  u16* pb[2] = {pA, pB};
  u16* ob[2] = {oA, oB};
  u16* lb[2] = {lA, lB};
  int cu = 0;
  for (int t = 0; t < 3; t++) {
    u16 *pi = pb[cu], *po = pb[1 - cu];
    u16 *oi = ob[cu], *oo = ob[1 - cu];
    u16 *li = lb[cu], *lo = lb[1 - cu];
    sage_fused<3><<<(NP + 31) / 32, 256, 0, stream>>>(pi, po,
        pi, off + o0, csr0, NP,
        oi, off + o2, csr2, NO,
        li, off + o4, csr4, NL,
        WBlin + ((size_t)t * 5 + 0) * 4096,
        WBlin + ((size_t)t * 5 + 2) * 4096,
        WBlin + ((size_t)t * 5 + 4) * 4096,
        WBroot + ((size_t)t * 3 + 0) * 4096,
        bsums + ((size_t)t * 3 + 0) * 64, 1.f / 3.f, NP);
    sage_fused<1><<<(NO + 31) / 32, 256, 0, stream>>>(oi, oo,
        pi, off + o1, csr1, NP,
        (const u16*)0, (const int*)0, (const int*)0, 0,
        (const u16*)0, (const int*)0, (const int*)0, 0,
        WBlin + ((size_t)t * 5 + 1) * 4096, (const u16*)0, (const u16*)0,
        WBroot + ((size_t)t * 3 + 1) * 4096,
        bsums + ((size_t)t * 3 + 1) * 64, 1.f, NO);
    sage_fused<1><<<(NL + 31) / 32, 256, 0, stream>>>(li, lo,
        pi, off + o3, csr3, NP,
        (const u16*)0, (const int*)0, (const int*)0, 0,
        (const u16*)0, (const int*)0, (const int*)0, 0,
        WBlin + ((size_t)t * 5 + 3) * 4096, (const u16*)0, (const u16*)0,
        WBroot + ((size_t)t * 3 + 2) * 4096,
        bsums + ((size_t)t * 3 + 2) * 64, 1.f, NL);
    cu = 1 - cu;
  }
  const u16* pF = pb[cu];
  const u16* oF = ob[cu];
  const u16* lF = lb[cu];

  // ---- readout (FP32 output) ----
  colsum2<<<128, 256, 0, stream>>>(pF, NP, gsum);
  colsum2<<<64, 256, 0, stream>>>(oF, NO, gsum + 64);
  colsum2<<<32, 256, 0, stream>>>(lF, NL, gsum + 128);
  head2<<<1, 256, 0, stream>>>(gsum, Wc1, bc1, Wc2, bc2, NP, NO, NL, out);
  suspect2<<<(NP + 255) / 256, 256, 0, stream>>>(pF, Ws1, bs1, Ws2, bs2, out + 20, NP);
}

// Round 8
// 826.641 us; speedup vs baseline: 2.6750x; 1.3570x over previous
//
#include <hip/hip_runtime.h>

typedef unsigned short u16;
typedef unsigned int u32;
typedef __attribute__((ext_vector_type(8))) short bf16x8;
typedef __attribute__((ext_vector_type(4))) float f32x4;

#define BKW 2048           // bucket width (nodes); BKSH = log2(BKW)
#define BKSH 11
#define MAXBK 512          // max total buckets (bench: 368)

__device__ __forceinline__ float bf2f(u16 u) { return __uint_as_float(((u32)u) << 16); }
__device__ __forceinline__ u16 f2bf(float f) {
  u32 u = __float_as_uint(f);
  return (u16)((u + 0x7fffu + ((u >> 16) & 1u)) >> 16);
}

// ---------------------------------------------------------------------------
// Embedding gather: fp32 emb row -> internal bf16 feature row.
// Vectorized: 4 elems/thread (float4 load, ushort4 store); 16 threads/row
// share the id load (HW broadcast).
__global__ void gather_f2b(const float* __restrict__ emb, const int* __restrict__ ids,
                           u16* __restrict__ out, int n, int V) {
  int u = blockIdx.x * 256 + threadIdx.x;
  if (u >= n * 16) return;
  int node = u >> 4, q = u & 15;
  int r = ids[node];
  r = ((u32)r < (u32)V) ? r : 0;
  float4 v = *(const float4*)(emb + (size_t)r * 64 + q * 4);
  ushort4 o;
  o.x = f2bf(v.x); o.y = f2bf(v.y); o.z = f2bf(v.z); o.w = f2bf(v.w);
  *(ushort4*)(out + (size_t)node * 64 + q * 4) = o;
}

// ---------------------------------------------------------------------------
// Weight prep (once per launch): bf16 lin weights, bf16 root-sum weights,
// fp32 bias-sums.
__global__ void prep_w(const float* __restrict__ Wl, const float* __restrict__ Wr,
                       const float* __restrict__ bl,
                       u16* __restrict__ WBlin, u16* __restrict__ WBroot,
                       float* __restrict__ bsums) {
  int i = blockIdx.x * 256 + threadIdx.x;
  const int TL = 3 * 5 * 4096;
  if (i < TL) { WBlin[i] = f2bf(Wl[i]); return; }
  int j = i - TL;
  if (j < 3 * 3 * 4096) {
    int lt = j / (3 * 4096), rem = j % (3 * 4096), c = rem / 4096, e = rem % 4096;
    int r0 = (c == 0) ? 0 : (c == 1) ? 1 : 3;
    float v = Wr[((size_t)lt * 5 + r0) * 4096 + e];
    if (c == 0) v += Wr[((size_t)lt * 5 + 2) * 4096 + e] +
                     Wr[((size_t)lt * 5 + 4) * 4096 + e];
    WBroot[j] = f2bf(v);
    return;
  }
  int k2 = j - 3 * 3 * 4096;
  if (k2 < 3 * 3 * 64) {
    int lt = k2 / 192, rem = k2 % 192, c = rem / 64, e = rem % 64;
    int r0 = (c == 0) ? 0 : (c == 1) ? 1 : 3;
    float v = bl[((size_t)lt * 5 + r0) * 64 + e];
    if (c == 0) v += bl[((size_t)lt * 5 + 2) * 64 + e] +
                     bl[((size_t)lt * 5 + 4) * 64 + e];
    bsums[k2] = v;
  }
}

// ---------------------------------------------------------------------------
// CSR build, bucket-sort formulation (dense writes).
// ---------------------------------------------------------------------------
__global__ void __launch_bounds__(256) bkt_count(
    const int* __restrict__ D0, const int* __restrict__ D1, const int* __restrict__ D2,
    const int* __restrict__ D3, const int* __restrict__ D4,
    int* __restrict__ bcnt,
    int E1, int E2, int E3, int E4, int E5,
    int s1, int s2, int s3, int s4,
    int N0, int N1, int N2, int N3, int N4, int NBK) {
  __shared__ int c[MAXBK];
  int t = threadIdx.x;
  for (int i = t; i < NBK; i += 256) c[i] = 0;
  __syncthreads();
  int chunk0 = blockIdx.x * 8192;
  for (int j = 0; j < 32; j++) {
    int e = chunk0 + j * 256 + t;
    if (e >= E5) break;
    const int* dp; int sb, N, le;
    if (e < E1)      { dp = D0; sb = 0;  N = N0; le = e; }
    else if (e < E2) { dp = D1; sb = s1; N = N1; le = e - E1; }
    else if (e < E3) { dp = D2; sb = s2; N = N2; le = e - E2; }
    else if (e < E4) { dp = D3; sb = s3; N = N3; le = e - E3; }
    else             { dp = D4; sb = s4; N = N4; le = e - E4; }
    int d = dp[le];
    if ((u32)d < (u32)N) atomicAdd(&c[sb + (d >> BKSH)], 1);
  }
  __syncthreads();
  for (int i = t; i < NBK; i += 256) if (c[i]) atomicAdd(&bcnt[i], c[i]);
}

__global__ void __launch_bounds__(512) bkt_scan(
    const int* __restrict__ bcnt, int* __restrict__ bbase, int* __restrict__ bcur,
    int* __restrict__ off,
    int s1, int s2, int s3, int s4, int NBK,
    int q0, int q1, int q2, int q3, int q4) {   // absolute off-sentinel indices
  __shared__ int sb[MAXBK + 1];
  __shared__ int ws[8];
  int t = threadIdx.x, lane = t & 63, wv = t >> 6;
  int v = (t < NBK) ? bcnt[t] : 0;
  int s = v;
  #pragma unroll
  for (int d = 1; d < 64; d <<= 1) { int u = __shfl_up(s, d); if (lane >= d) s += u; }
  if (lane == 63) ws[wv] = s;
  __syncthreads();
  int wbase = 0;
  for (int i = 0; i < wv; i++) wbase += ws[i];
  int excl = wbase + (s - v);
  if (t < NBK) { bbase[t] = excl; bcur[t] = excl; sb[t] = excl; }
  if (t == 0) {
    int tot = 0;
    #pragma unroll
    for (int i = 0; i < 8; i++) tot += ws[i];
    bbase[NBK] = tot; sb[NBK] = tot;
  }
  __syncthreads();
  if (t == 0) off[q0] = sb[s1];
  else if (t == 1) off[q1] = sb[s2] - sb[s1];
  else if (t == 2) off[q2] = sb[s3] - sb[s2];
  else if (t == 3) off[q3] = sb[s4] - sb[s3];
  else if (t == 4) off[q4] = sb[NBK] - sb[s4];
}

__global__ void __launch_bounds__(256) bkt_scatter(
    const int* __restrict__ S0, const int* __restrict__ S1, const int* __restrict__ S2,
    const int* __restrict__ S3, const int* __restrict__ S4,
    const int* __restrict__ D0, const int* __restrict__ D1, const int* __restrict__ D2,
    const int* __restrict__ D3, const int* __restrict__ D4,
    int* __restrict__ bcur, u32* __restrict__ bdata,
    int E1, int E2, int E3, int E4, int E5,
    int s1, int s2, int s3, int s4,
    int N0, int N1, int N2, int N3, int N4, int NBK) {
  __shared__ int c[MAXBK];
  __shared__ int base[MAXBK];
  int t = threadIdx.x;
  for (int i = t; i < NBK; i += 256) c[i] = 0;
  __syncthreads();
  int chunk0 = blockIdx.x * 4096;
  int lb[16]; u32 rec[16];
  #pragma unroll
  for (int j = 0; j < 16; j++) {
    int e = chunk0 + j * 256 + t;
    lb[j] = -1;
    if (e < E5) {
      const int *sp, *dp; int sb, N, le;
      if (e < E1)      { sp = S0; dp = D0; sb = 0;  N = N0; le = e; }
      else if (e < E2) { sp = S1; dp = D1; sb = s1; N = N1; le = e - E1; }
      else if (e < E3) { sp = S2; dp = D2; sb = s2; N = N2; le = e - E2; }
      else if (e < E4) { sp = S3; dp = D3; sb = s3; N = N3; le = e - E3; }
      else             { sp = S4; dp = D4; sb = s4; N = N4; le = e - E4; }
      int d = dp[le];
      if ((u32)d < (u32)N) {
        lb[j] = sb + (d >> BKSH);
        rec[j] = ((u32)sp[le] << BKSH) | (u32)(d & (BKW - 1));
        atomicAdd(&c[lb[j]], 1);
      }
    }
  }
  __syncthreads();
  for (int i = t; i < NBK; i += 256) {
    int cc = c[i];
    base[i] = cc ? atomicAdd(&bcur[i], cc) : 0;
    c[i] = 0;
  }
  __syncthreads();
  #pragma unroll
  for (int j = 0; j < 16; j++) {
    if (lb[j] >= 0) {
      int r = atomicAdd(&c[lb[j]], 1);
      int pos = base[lb[j]] + r;
      if ((u32)pos < (u32)E5) bdata[pos] = rec[j];   // dense bucket frontier write
    }
  }
}

// 1024 threads/block: 368 blocks x 16 waves.
__global__ void __launch_bounds__(1024) bkt_sort(
    const int* __restrict__ bbase, const u32* __restrict__ bdata,
    int* __restrict__ off, int* __restrict__ csr,
    int s1, int s2, int s3, int s4, int NBK,
    int N0, int N1, int N2, int N3, int N4,
    int o1, int o2, int o3, int o4,
    int g1, int g2, int g3, int g4,
    int La, int Lu, int Lt) {
  __shared__ int cnt[BKW];
  __shared__ int pre[BKW];
  __shared__ int wsum[16];
  int b = blockIdx.x, t = threadIdx.x, lane = t & 63, wv = t >> 6;
  int r = (b >= s4) ? 4 : (b >= s3) ? 3 : (b >= s2) ? 2 : (b >= s1) ? 1 : 0;
  int sr = (r == 0) ? 0 : (r == 1) ? s1 : (r == 2) ? s2 : (r == 3) ? s3 : s4;
  int Nr = (r == 0) ? N0 : (r == 1) ? N1 : (r == 2) ? N2 : (r == 3) ? N3 : N4;
  int oR = (r == 0) ? 0 : (r == 1) ? o1 : (r == 2) ? o2 : (r == 3) ? o3 : o4;
  int gR = (r == 0) ? 0 : (r == 1) ? g1 : (r == 2) ? g2 : (r == 3) ? g3 : g4;
  int Lr = (r == 0) ? La : (r == 1 || r == 2) ? Lu : Lt;
  int relRecBase = bbase[sr];
  int bstart = bbase[b], bend = bbase[b + 1];
  int node0 = (b - sr) << BKSH;
  int W = Nr - node0; if (W > BKW) W = BKW;
  int csrB = bstart - relRecBase;              // base within relation csr segment
  for (int i = t; i < BKW; i += 1024) cnt[i] = 0;
  __syncthreads();
  for (int i = bstart + t; i < bend; i += 1024)
    atomicAdd(&cnt[bdata[i] & (BKW - 1)], 1);
  __syncthreads();
  // block exclusive scan over 2048 counts (2/thread)
  int basei = t * 2;
  int v0 = cnt[basei], v1 = cnt[basei + 1];
  int tsum = v0 + v1;
  int s = tsum;
  #pragma unroll
  for (int d = 1; d < 64; d <<= 1) { int u = __shfl_up(s, d); if (lane >= d) s += u; }
  if (lane == 63) wsum[wv] = s;
  __syncthreads();
  int wbase = 0;
  #pragma unroll
  for (int i = 0; i < 16; i++) wbase += (i < wv) ? wsum[i] : 0;
  int run = wbase + (s - tsum);
  pre[basei] = run;
  if (basei < W) off[oR + node0 + basei] = csrB + run;
  run += v0;
  pre[basei + 1] = run;
  if (basei + 1 < W) off[oR + node0 + basei + 1] = csrB + run;
  cnt[basei] = 0; cnt[basei + 1] = 0;          // reuse as rank cursor
  __syncthreads();
  for (int i = bstart + t; i < bend; i += 1024) {
    u32 rc = bdata[i];
    int ld = rc & (BKW - 1);
    int src = (int)(rc >> BKSH);
    int rank = atomicAdd(&cnt[ld], 1);
    int pos = csrB + pre[ld] + rank;
    if ((u32)pos < (u32)Lr) csr[gR + pos] = src;    // L2-resident bucket region
  }
}

// ---------------------------------------------------------------------------
// FUSED SAGE layer v2: vectorized gather + MFMA GEMM + epilogue, ping-pong.
// Block = 32 dst rows, 4 waves. One bf16x8 (16B) load per lane per edge-round;
// ids burst-loaded; lanes of a row-slot share idx addr (HW broadcast).
template <int NM>
__global__ void __launch_bounds__(256, 4) sage_fused(
    const u16* __restrict__ X, u16* __restrict__ out,   // out != X (ping-pong)
    const u16* __restrict__ S0, const int* __restrict__ of0, const int* __restrict__ ix0, int ns0,
    const u16* __restrict__ S1, const int* __restrict__ of1, const int* __restrict__ ix1, int ns1,
    const u16* __restrict__ S2, const int* __restrict__ of2, const int* __restrict__ ix2, int ns2,
    const u16* __restrict__ lin0, const u16* __restrict__ lin1, const u16* __restrict__ lin2,
    const u16* __restrict__ root, const float* __restrict__ bsum,
    float scale, int n) {
  constexpr int KC = 2 * (NM + 1);            // K-chunks of 32
  constexpr int AP = (NM + 1) * 64 + 8;       // padded A row pitch (u16)
  __shared__ __align__(16) u16 A_lds[32 * AP];
  __shared__ __align__(16) u16 D_lds[32 * 72];
  int t = threadIdx.x, wave = t >> 6, lane = t & 63;
  int m0 = blockIdx.x << 5;

  // ---- gather phase: lane (s,c); wave w fills rows w*8..w*8+7 ----
  {
    int s = lane >> 3, c = lane & 7;
    int rr = wave * 8 + s;
    int g = m0 + rr;
    int gc = (g < n) ? g : (n - 1);
    #pragma unroll
    for (int rel = 0; rel < NM; rel++) {
      const u16* S  = (rel == 0) ? S0 : (rel == 1) ? S1 : S2;
      const int* of = (rel == 0) ? of0 : (rel == 1) ? of1 : of2;
      const int* ix = (rel == 0) ? ix0 : (rel == 1) ? ix1 : ix2;
      u32 ns = (u32)((rel == 0) ? ns0 : (rel == 1) ? ns1 : ns2);
      int e0 = of[gc], e1 = of[gc + 1];
      int deg = e1 - e0;
      float a[8] = {0.f, 0.f, 0.f, 0.f, 0.f, 0.f, 0.f, 0.f};
      for (int base = e0; __any(base < e1); base += 8) {
        int id[8];
        #pragma unroll
        for (int j = 0; j < 8; j++) {        // 8 independent 4B id loads
          int e = base + j;
          id[j] = (e < e1) ? ix[e] : -1;     // exec-masked load
        }
        #pragma unroll
        for (int j = 0; j < 8; j++) {        // 8 independent 16B row loads
          bf16x8 v = {};
          if ((u32)id[j] < ns)               // exec-masked: no fetch if inactive
            v = *(const bf16x8*)(S + (size_t)(u32)id[j] * 64 + c * 8);
          #pragma unroll
          for (int k = 0; k < 8; k++) a[k] += bf2f((u16)v[k]);
        }
      }
      float inv = (deg > 0) ? 1.f / (float)deg : 0.f;
      bf16x8 m8;
      #pragma unroll
      for (int k = 0; k < 8; k++) m8[k] = (short)f2bf(a[k] * inv);
      *(bf16x8*)&A_lds[rr * AP + rel * 64 + c * 8] = m8;
    }
    // root X row (16B vector copy)
    bf16x8 xv = *(const bf16x8*)(X + (size_t)gc * 64 + c * 8);
    *(bf16x8*)&A_lds[rr * AP + NM * 64 + c * 8] = xv;
  }
  __syncthreads();

  // ---- MFMA phase: wave w -> rows (w&1)*16..+16, cols (w>>1)*32..+32 ----
  int col0 = lane & 15, kb = lane >> 4;
  int rt = (wave & 1) * 16;
  int ct = (wave >> 1) * 32;
  const u16* Wbase[KC];
  #pragma unroll
  for (int kc = 0; kc < KC; kc++) {
    int m = kc >> 1;
    const u16* basep = (m < NM) ? ((m == 0) ? lin0 : (m == 1) ? lin1 : lin2) : root;
    Wbase[kc] = basep + (kc & 1) * 32 + kb * 8;
  }
  f32x4 acc0 = {}, acc1 = {};
  #pragma unroll
  for (int kc = 0; kc < KC; kc++) {
    bf16x8 Af = *(const bf16x8*)&A_lds[(rt + col0) * AP + kc * 32 + kb * 8];
    bf16x8 B0 = *(const bf16x8*)(Wbase[kc] + (ct + col0) * 64);        // L1 hot
    acc0 = __builtin_amdgcn_mfma_f32_16x16x32_bf16(Af, B0, acc0, 0, 0, 0);
    bf16x8 B1 = *(const bf16x8*)(Wbase[kc] + (ct + 16 + col0) * 64);
    acc1 = __builtin_amdgcn_mfma_f32_16x16x32_bf16(Af, B1, acc1, 0, 0, 0);
  }

  // ---- epilogue: v = relu((acc+b)*s) + x, staged via LDS for coalesced IO ----
  float b0 = bsum[ct + col0];
  float b1 = bsum[ct + 16 + col0];
  #pragma unroll
  for (int j = 0; j < 4; j++) {
    int dr = rt + kb * 4 + j;                // D row within 32-row tile
    float xv0 = bf2f(A_lds[dr * AP + NM * 64 + ct + col0]);
    D_lds[dr * 72 + ct + col0] = f2bf(fmaxf((acc0[j] + b0) * scale, 0.f) + xv0);
    float xv1 = bf2f(A_lds[dr * AP + NM * 64 + ct + 16 + col0]);
    D_lds[dr * 72 + ct + 16 + col0] = f2bf(fmaxf((acc1[j] + b1) * scale, 0.f) + xv1);
  }
  __syncthreads();
  int row32 = t >> 3, cc = (t & 7) * 8;      // 256 threads = 32 rows x 8 chunks
  int row = m0 + row32;
  if (row < n) {
    bf16x8 o8;
    #pragma unroll
    for (int j = 0; j < 8; j++) o8[j] = (short)D_lds[row32 * 72 + cc + j];
    *(bf16x8*)(out + (size_t)row * 64 + cc) = o8;       // 16B coalesced store
  }
}

// ---------------------------------------------------------------------------
// Column sums over bf16 features (graph-mean readout), vectorized:
// thread = (row-slot = t>>3, col-chunk = (t&7)*8); ONE bf16x8 per row-visit
// (16B/lane, 1KB/wave-instr — v1 was a scalar u16/lane = 128B/wave-instr and
// only 512 waves: 100us at 32GB/s for an L3-resident scan). xor-shuffle
// reduce over row-slots, per-block LDS combine, 64 atomics/block.
__global__ void __launch_bounds__(256) colsum3(const u16* __restrict__ x, int n,
                                               float* __restrict__ gout) {
  __shared__ float part[64];
  int t = threadIdx.x;
  if (t < 64) part[t] = 0.f;
  __syncthreads();
  int lane = t & 63;
  int c = (lane & 7) * 8;
  int rs = blockIdx.x * 32 + (t >> 3);
  int stride = gridDim.x * 32;
  float a[8] = {0.f, 0.f, 0.f, 0.f, 0.f, 0.f, 0.f, 0.f};
  for (int r = rs; r < n; r += stride) {
    bf16x8 v = *(const bf16x8*)(x + (size_t)r * 64 + c);
    #pragma unroll
    for (int k = 0; k < 8; k++) a[k] += bf2f((u16)v[k]);
  }
  #pragma unroll
  for (int k = 0; k < 8; k++) {
    a[k] += __shfl_xor(a[k], 8);
    a[k] += __shfl_xor(a[k], 16);
    a[k] += __shfl_xor(a[k], 32);
  }
  if (lane < 8) {
    #pragma unroll
    for (int k = 0; k < 8; k++) atomicAdd(&part[lane * 8 + k], a[k]);
  }
  __syncthreads();
  if (t < 64) atomicAdd(&gout[t], part[t]);
}

// Crime head: out[0:20) as FP32
__global__ void __launch_bounds__(256) head2(const float* __restrict__ gsum,
    const float* __restrict__ Wc1, const float* __restrict__ bc1,
    const float* __restrict__ Wc2, const float* __restrict__ bc2,
    int NP, int NO, int NL, float* __restrict__ out) {
  __shared__ float g[192];
  __shared__ float h[64];
  int t = threadIdx.x;
  if (t < 192) {
    float d = (t < 64) ? (float)NP : (t < 128) ? (float)NO : (float)NL;
    g[t] = gsum[t] / d;
  }
  __syncthreads();
  if (t < 64) {
    float a = bc1[t];
    for (int k = 0; k < 192; k++) a += g[k] * Wc1[(size_t)t * 192 + k];
    h[t] = fmaxf(a, 0.f);
  }
  __syncthreads();
  if (t < 20) {
    float a = bc2[t];
    for (int k = 0; k < 64; k++) a += h[k] * Wc2[(size_t)t * 64 + k];
    out[t] = a;
  }
}

// Suspect head: out[i] as FP32 (out passed pre-offset by +20).
// Row loads vectorized: 8x bf16x8 instead of 64 scalar u16.
__global__ void __launch_bounds__(256) suspect2(const u16* __restrict__ p,
    const float* __restrict__ Ws1, const float* __restrict__ bs1,
    const float* __restrict__ Ws2, const float* __restrict__ bs2,
    float* __restrict__ out, int NP) {
  __shared__ float W1[2048];
  __shared__ float b1[32], w2[32];
  __shared__ float b2s;
  int t = threadIdx.x;
  #pragma unroll
  for (int i = 0; i < 8; i++) {
    int d = t + i * 256;
    W1[d] = Ws1[d];
  }
  if (t < 32) { b1[t] = bs1[t]; w2[t] = Ws2[t]; }
  if (t == 0) b2s = bs2[0];
  __syncthreads();
  int i = blockIdx.x * 256 + t;
  if (i >= NP) return;
  float x[64];
  #pragma unroll
  for (int q = 0; q < 8; q++) {
    bf16x8 v = *(const bf16x8*)(p + (size_t)i * 64 + q * 8);
    #pragma unroll
    for (int k = 0; k < 8; k++) x[q * 8 + k] = bf2f((u16)v[k]);
  }
  float sc = b2s;
  for (int j = 0; j < 32; j++) {
    float a = b1[j];
    const float* wr = &W1[j * 64];
    #pragma unroll
    for (int k = 0; k < 64; k++) a += x[k] * wr[k];
    sc += fmaxf(a, 0.f) * w2[j];
  }
  out[i] = sc;
}

// ---------------------------------------------------------------------------
extern "C" void kernel_launch(void* const* d_in, const int* in_sizes, int n_in,
                              void* d_out, int out_size, void* d_ws, size_t ws_size,
                              hipStream_t stream) {
  const int NP = in_sizes[0], NO = in_sizes[1], NL = in_sizes[2];
  const int Ea = in_sizes[3], Eu = in_sizes[5], Et = in_sizes[7];
  const int VP = in_sizes[9] / 64, VO = in_sizes[10] / 64, VL = in_sizes[11] / 64;

  const int* x_person   = (const int*)d_in[0];
  const int* x_object   = (const int*)d_in[1];
  const int* x_location = (const int*)d_in[2];
  const int* acts_src = (const int*)d_in[3];
  const int* acts_dst = (const int*)d_in[4];
  const int* uses_src = (const int*)d_in[5];
  const int* uses_dst = (const int*)d_in[6];
  const int* at_src   = (const int*)d_in[7];
  const int* at_dst   = (const int*)d_in[8];
  const float* person_emb   = (const float*)d_in[9];
  const float* object_emb   = (const float*)d_in[10];
  const float* location_emb = (const float*)d_in[11];
  const float* Wl  = (const float*)d_in[12];
  const float* bl  = (const float*)d_in[13];
  const float* Wr  = (const float*)d_in[14];
  const float* Wc1 = (const float*)d_in[15];
  const float* bc1 = (const float*)d_in[16];
  const float* Wc2 = (const float*)d_in[17];
  const float* bc2 = (const float*)d_in[18];
  const float* Ws1 = (const float*)d_in[19];
  const float* bs1 = (const float*)d_in[20];
  const float* Ws2 = (const float*)d_in[21];
  const float* bs2 = (const float*)d_in[22];
  float* out = (float*)d_out;

  // ---- bucket geometry (MAXBK guard: bench is 368) ----
  int B0 = (NP + BKW - 1) >> BKSH;
  int B1 = (NO + BKW - 1) >> BKSH;
  int B3 = (NL + BKW - 1) >> BKSH;
  int s1 = B0, s2 = s1 + B1, s3 = s2 + B0, s4 = s3 + B3, NBK = s4 + B0;
  if (NBK > MAXBK) return;   // out stays 0 -> visible failure signature

  // ---- workspace (16B aligned) ----
  char* w = (char*)d_ws;
  auto alloc = [&](size_t bytes) { char* r = w; w += (bytes + 15) & ~(size_t)15; return r; };
  u16* pA = (u16*)alloc((size_t)NP * 128);
  u16* pB = (u16*)alloc((size_t)NP * 128);
  u16* oA = (u16*)alloc((size_t)NO * 128);
  u16* oB = (u16*)alloc((size_t)NO * 128);
  u16* lA = (u16*)alloc((size_t)NL * 128);
  u16* lB = (u16*)alloc((size_t)NL * 128);
  float* gsum = (float*)alloc(192 * 4);
  const size_t CN = (size_t)3 * NP + NO + NL;
  int* off = (int*)alloc((CN + 8) * 4);
  int* bcnt  = (int*)alloc((MAXBK) * 4);
  int* bbase = (int*)alloc((MAXBK + 1) * 4);
  int* bcur  = (int*)alloc((MAXBK) * 4);
  const int E1 = Ea, E2 = E1 + Eu, E3 = E2 + Eu, E4 = E3 + Et, E5 = E4 + Et;
  u32* bdata = (u32*)alloc((size_t)E5 * 4);
  u16* WBlin  = (u16*)alloc((size_t)3 * 5 * 4096 * 2);
  u16* WBroot = (u16*)alloc((size_t)3 * 3 * 4096 * 2);
  float* bsums = (float*)alloc((size_t)3 * 3 * 64 * 4);
  int* csr = (int*)alloc((size_t)E5 * 4);
  size_t base_need = (size_t)(w - (char*)d_ws);
  (void)n_in; (void)out_size;
  // ws guard: if it fires, out stays 0 -> absmax == 0.118652 exactly (signature)
  if (base_need > ws_size) return;

  int o0 = 0, o1 = NP + 1, o2 = o1 + NO + 1, o3 = o2 + NP + 1, o4 = o3 + NL + 1;
  int g1 = Ea, g2 = Ea + Eu, g3 = Ea + 2 * Eu, g4 = Ea + 2 * Eu + Et;
  int* csr0 = csr;
  int* csr1 = csr + g1;
  int* csr2 = csr + g2;
  int* csr3 = csr + g3;
  int* csr4 = csr + g4;

  hipMemsetAsync(bcnt, 0, MAXBK * sizeof(int), stream);
  hipMemsetAsync(gsum, 0, 192 * sizeof(float), stream);

  prep_w<<<387, 256, 0, stream>>>(Wl, Wr, bl, WBlin, WBroot, bsums);

  gather_f2b<<<(NP * 16 + 255) / 256, 256, 0, stream>>>(person_emb, x_person, pA, NP, VP);
  gather_f2b<<<(NO * 16 + 255) / 256, 256, 0, stream>>>(object_emb, x_object, oA, NO, VO);
  gather_f2b<<<(NL * 16 + 255) / 256, 256, 0, stream>>>(location_emb, x_location, lA, NL, VL);

  // ---- CSR build: bucket-sort (dense writes) ----
  bkt_count<<<(E5 + 8191) / 8192, 256, 0, stream>>>(
      acts_dst, uses_dst, uses_src, at_dst, at_src, bcnt,
      E1, E2, E3, E4, E5, s1, s2, s3, s4, NP, NO, NP, NL, NP, NBK);
  bkt_scan<<<1, 512, 0, stream>>>(bcnt, bbase, bcur, off,
      s1, s2, s3, s4, NBK,
      o0 + NP, o1 + NO, o2 + NP, o3 + NL, o4 + NP);
  bkt_scatter<<<(E5 + 4095) / 4096, 256, 0, stream>>>(
      acts_src, uses_src, uses_dst, at_src, at_dst,
      acts_dst, uses_dst, uses_src, at_dst, at_src,
      bcur, bdata, E1, E2, E3, E4, E5, s1, s2, s3, s4, NP, NO, NP, NL, NP, NBK);
  bkt_sort<<<NBK, 1024, 0, stream>>>(bbase, bdata, off, csr,
      s1, s2, s3, s4, NBK, NP, NO, NP, NL, NP,
      o1, o2, o3, o4, g1, g2, g3, g4, Ea, Eu, Et);

  // ---- 3 layers: fused gather+GEMM, ping-pong buffers ----
  u16* pb[2] = {pA, pB};
  u16* ob[2] = {oA, oB};
  u16* lb[2] = {lA, lB};
  int cu = 0;
  for (int t = 0; t < 3; t++) {
    u16 *pi = pb[cu], *po = pb[1 - cu];
    u16 *oi = ob[cu], *oo = ob[1 - cu];
    u16 *li = lb[cu], *lo = lb[1 - cu];
    sage_fused<3><<<(NP + 31) / 32, 256, 0, stream>>>(pi, po,
        pi, off + o0, csr0, NP,
        oi, off + o2, csr2, NO,
        li, off + o4, csr4, NL,
        WBlin + ((size_t)t * 5 + 0) * 4096,
        WBlin + ((size_t)t * 5 + 2) * 4096,
        WBlin + ((size_t)t * 5 + 4) * 4096,
        WBroot + ((size_t)t * 3 + 0) * 4096,
        bsums + ((size_t)t * 3 + 0) * 64, 1.f / 3.f, NP);
    sage_fused<1><<<(NO + 31) / 32, 256, 0, stream>>>(oi, oo,
        pi, off + o1, csr1, NP,
        (const u16*)0, (const int*)0, (const int*)0, 0,
        (const u16*)0, (const int*)0, (const int*)0, 0,
        WBlin + ((size_t)t * 5 + 1) * 4096, (const u16*)0, (const u16*)0,
        WBroot + ((size_t)t * 3 + 1) * 4096,
        bsums + ((size_t)t * 3 + 1) * 64, 1.f, NO);
    sage_fused<1><<<(NL + 31) / 32, 256, 0, stream>>>(li, lo,
        pi, off + o3, csr3, NP,
        (const u16*)0, (const int*)0, (const int*)0, 0,
        (const u16*)0, (const int*)0, (const int*)0, 0,
        WBlin + ((size_t)t * 5 + 3) * 4096, (const u16*)0, (const u16*)0,
        WBroot + ((size_t)t * 3 + 2) * 4096,
        bsums + ((size_t)t * 3 + 2) * 64, 1.f, NL);
    cu = 1 - cu;
  }
  const u16* pF = pb[cu];
  const u16* oF = ob[cu];
  const u16* lF = lb[cu];

  // ---- readout (FP32 output) ----
  colsum3<<<256, 256, 0, stream>>>(pF, NP, gsum);
  colsum3<<<128, 256, 0, stream>>>(oF, NO, gsum + 64);
  colsum3<<<64, 256, 0, stream>>>(lF, NL, gsum + 128);
  head2<<<1, 256, 0, stream>>>(gsum, Wc1, bc1, Wc2, bc2, NP, NO, NL, out);
  suspect2<<<(NP + 255) / 256, 256, 0, stream>>>(pF, Ws1, bs1, Ws2, bs2, out + 20, NP);
}